// Round 11
// baseline (512.656 us; speedup 1.0000x reference)
//
#include <hip/hip_runtime.h>
#include <math.h>

constexpr int B_ = 4, S_ = 512, D_ = 768, H_ = 12, M_ = 4, DFF_ = 3072, HD_ = 64;
constexpr float EPS_ = 1e-6f;
constexpr float SCALE_ = 0.125f;  // HD^-0.5
constexpr int BS_ = B_ * S_;
constexpr int BH_ = B_ * H_;
constexpr long long BSD_ = (long long)BS_ * D_;
constexpr long long BS3D_ = (long long)BS_ * 3 * D_;
constexpr long long ATT_ = (long long)BH_ * S_ * S_;
constexpr long long BSF_ = (long long)BS_ * DFF_;

typedef __attribute__((ext_vector_type(8))) short bf16x8;
typedef __attribute__((ext_vector_type(4))) float f32x4;

__device__ __forceinline__ ushort f2bf(float f) {
    uint32_t u = __float_as_uint(f);
    u += 0x7FFF + ((u >> 16) & 1);
    return (ushort)(u >> 16);
}
__device__ __forceinline__ float bf2f(ushort u) {
    return __uint_as_float((uint32_t)u << 16);
}

__device__ __forceinline__ void gll16(const ushort* g, ushort* l) {
    __builtin_amdgcn_global_load_lds((const __attribute__((address_space(1))) void*)g,
                                     (__attribute__((address_space(3))) void*)l, 16, 0, 0);
}

// counted vmcnt wait (literal required in asm)
template <int N> __device__ __forceinline__ void waitcnt_vm() {
    if constexpr (N == 0) asm volatile("s_waitcnt vmcnt(0)" ::: "memory");
    else if constexpr (N == 4) asm volatile("s_waitcnt vmcnt(4)" ::: "memory");
    else if constexpr (N == 6) asm volatile("s_waitcnt vmcnt(6)" ::: "memory");
    else if constexpr (N == 8) asm volatile("s_waitcnt vmcnt(8)" ::: "memory");
    else static_assert(N == 0 || N == 4 || N == 6 || N == 8, "add literal");
}

// XCD-chunked bijective block remap (m204)
__device__ __forceinline__ int xcd_swz(int flat, int nwg) {
    int q = nwg >> 3, r = nwg & 7;
    int x = flat & 7, pos = flat >> 3;
    int base = (x < r) ? x * (q + 1) : r * (q + 1) + (x - r) * q;
    return base + pos;
}

// batched-row (rg in [0,8192)) -> [B,M,S,Nc] offset
__device__ __forceinline__ size_t stroff(int rg, int c, int Nc) {
    int m = rg >> 11;
    int b = (rg >> 9) & (B_ - 1);
    int s = rg & (S_ - 1);
    return ((size_t)((b * M_ + m) * S_ + s)) * Nc + c;
}

// ---------------- block reduction (256 threads = 4 waves) ----------------
__device__ __forceinline__ float block_sum(float v) {
    __shared__ float red[4];
    int tid = threadIdx.x;
#pragma unroll
    for (int off = 32; off > 0; off >>= 1) v += __shfl_down(v, off, 64);
    __syncthreads();
    if ((tid & 63) == 0) red[tid >> 6] = v;
    __syncthreads();
    return red[0] + red[1] + red[2] + red[3];
}

// ---------------- weight transpose+convert: W[K][N] f32 -> WT[N][K] bf16 ----------------
__global__ __launch_bounds__(256) void transpose_f2b(const float* __restrict__ W,
                                                     ushort* __restrict__ WT,
                                                     int K, int N) {
    __shared__ float t[32][33];
    int n0 = blockIdx.x * 32, k0 = blockIdx.y * 32;
    int tx = threadIdx.x & 31, ty = threadIdx.x >> 5;
#pragma unroll
    for (int i = 0; i < 4; i++)
        t[ty + i * 8][tx] = W[(size_t)(k0 + ty + i * 8) * N + n0 + tx];
    __syncthreads();
#pragma unroll
    for (int i = 0; i < 4; i++)
        WT[(size_t)(n0 + ty + i * 8) * K + k0 + tx] = f2bf(t[tx][ty + i * 8]);
}

// ---------------- V transpose: src[m][B,S,3D] bf16 -> dst[m][bh][HD][S] bf16 ----------------
__global__ __launch_bounds__(256) void transpose_v(const ushort* __restrict__ src0,
                                                   ushort* __restrict__ dst0) {
    int z = blockIdx.z;
    int m = z / BH_, bh = z % BH_;
    const ushort* qkvb = src0 + (size_t)m * BS3D_;
    ushort* Vt = dst0 + (size_t)m * BSD_;
    int b = bh / H_, hh = bh - b * H_;
    int s0 = blockIdx.x * 32, d0 = blockIdx.y * 32;
    __shared__ ushort t[32][33];
    int tx = threadIdx.x & 31, ty = threadIdx.x >> 5;
#pragma unroll
    for (int i = 0; i < 4; i++)
        t[ty + i * 8][tx] = qkvb[(size_t)(b * S_ + s0 + ty + i * 8) * 3 * D_ + 2 * D_ + hh * HD_ + d0 + tx];
    __syncthreads();
#pragma unroll
    for (int i = 0; i < 4; i++)
        Vt[(size_t)bh * HD_ * S_ + (size_t)(d0 + ty + i * 8) * S_ + s0 + tx] = t[tx][ty + i * 8];
}

// ---------------- LayerNorm forward: xhat bf16, h bf16 ----------------
__global__ __launch_bounds__(256) void ln_fwd(const float* __restrict__ x,
                                              const float* __restrict__ g,
                                              const float* __restrict__ bta,
                                              ushort* __restrict__ xhat,
                                              ushort* __restrict__ h,
                                              float* __restrict__ rstd) {
    int row = blockIdx.x;
    const float* xr = x + (size_t)row * D_;
    int tid = threadIdx.x;
    float v[3];
    float s = 0.f;
#pragma unroll
    for (int i = 0; i < 3; i++) { v[i] = xr[tid + i * 256]; s += v[i]; }
    s = block_sum(s);
    float mu = s * (1.0f / D_);
    float vs = 0.f;
#pragma unroll
    for (int i = 0; i < 3; i++) { float c = v[i] - mu; vs += c * c; }
    vs = block_sum(vs);
    float rs = rsqrtf(vs * (1.0f / D_) + EPS_);
#pragma unroll
    for (int i = 0; i < 3; i++) {
        int c = tid + i * 256;
        float xh = (v[i] - mu) * rs;
        xhat[(size_t)row * D_ + c] = f2bf(xh);
        h[(size_t)row * D_ + c] = f2bf(xh * g[c] + bta[c]);
    }
    if (tid == 0) rstd[row] = rs;
}

// ---------------- batched LayerNorm JVP: grid 4*BS_ rows ----------------
__global__ __launch_bounds__(256) void ln_jvp(const float* __restrict__ tf,
                                              const ushort* __restrict__ tb, int mode,
                                              const ushort* __restrict__ xhat,
                                              const float* __restrict__ rstd,
                                              const float* __restrict__ g,
                                              ushort* __restrict__ dh) {
    int rg = blockIdx.x;
    int r = rg & (BS_ - 1);
    size_t pbase = (size_t)r * D_;
    int tid = threadIdx.x;
    float tv[3], xh[3];
    float s1 = 0.f, s2 = 0.f;
    size_t tbase;
    if (mode == 0) {
        int m = rg >> 11;
        int b = r >> 9, s = r & (S_ - 1);
        tbase = ((size_t)((b * M_ + m) * S_ + s)) * D_;
    } else {
        tbase = (size_t)rg * D_;
    }
#pragma unroll
    for (int i = 0; i < 3; i++) {
        int c = tid + i * 256;
        tv[i] = (mode == 0) ? tf[tbase + c] : bf2f(tb[tbase + c]);
        xh[i] = bf2f(xhat[pbase + c]);
        s1 += tv[i];
        s2 += tv[i] * xh[i];
    }
    s1 = block_sum(s1);
    s2 = block_sum(s2);
    float mt = s1 * (1.0f / D_);
    float mx = s2 * (1.0f / D_);
    float rs = rstd[r];
#pragma unroll
    for (int i = 0; i < 3; i++) {
        int c = tid + i * 256;
        dh[(size_t)rg * D_ + c] = f2bf(g[c] * rs * (tv[i] - mt - xh[i] * mx));
    }
}

// ---------------- bf16 MFMA GEMM <BM,BN>, BK=64, 2-deep dbuf pipeline + setprio ----------------
template <int BM, int BN, int EPI, bool RS, bool OS>
__global__ __launch_bounds__(256) void gemm_mfma(const ushort* __restrict__ A,
                                                 const ushort* __restrict__ BT,
                                                 const float* __restrict__ bias,
                                                 const float* __restrict__ resf,
                                                 const ushort* __restrict__ resb,
                                                 float* __restrict__ Cf,
                                                 ushort* __restrict__ Cb,
                                                 ushort* __restrict__ aux,
                                                 int Nc, int Kd) {
    constexpr int FI = BM / 32, FJ = BN / 32;
    constexpr int LA = BM / 32, LB = BN / 32, L = LA + LB;
    __shared__ ushort As[2][BM * 64];
    __shared__ ushort Bs[2][BN * 64];
    int tid = threadIdx.x;
    int wave = tid >> 6, lane = tid & 63;
    int wr = wave >> 1, wc = wave & 1;
    int gx = gridDim.x, nwg = gx * gridDim.y;
    int work = xcd_swz(blockIdx.x + blockIdx.y * gx, nwg);
    int row0 = (work / gx) * BM, col0 = (work % gx) * BN;

    int srow = lane >> 3;
    int skel = ((lane & 7) ^ (lane >> 3)) * 8;
    const ushort* Ag0 = A + (size_t)(row0 + srow) * Kd + skel;
    const ushort* Bg0 = BT + (size_t)(col0 + srow) * Kd + skel;

    auto stage = [&](int bufi, int k0) {
#pragma unroll
        for (int cc = 0; cc < LA; cc++) {
            int c = wave * LA + cc;
            gll16(Ag0 + (size_t)(c * 8) * Kd + k0, As[bufi] + c * 512);
        }
#pragma unroll
        for (int cc = 0; cc < LB; cc++) {
            int c = wave * LB + cc;
            gll16(Bg0 + (size_t)(c * 8) * Kd + k0, Bs[bufi] + c * 512);
        }
    };

    int frow = lane & 15, fkb = (lane >> 4) * 8;
    int aoff[2][FI], boff[2][FJ];
#pragma unroll
    for (int ks = 0; ks < 2; ks++) {
        int sw = (fkb + ks * 32) ^ ((frow & 7) * 8);
#pragma unroll
        for (int i = 0; i < FI; i++) aoff[ks][i] = (wr * (BM / 2) + i * 16 + frow) * 64 + sw;
#pragma unroll
        for (int j = 0; j < FJ; j++) boff[ks][j] = (wc * (BN / 2) + j * 16 + frow) * 64 + sw;
    }

    f32x4 acc[FI][FJ] = {};

    int nt = Kd >> 6;
    stage(0, 0);
    if (nt > 1) { stage(1, 64); waitcnt_vm<L>(); }
    else        { waitcnt_vm<0>(); }
    __builtin_amdgcn_s_barrier();
    __builtin_amdgcn_sched_barrier(0);

    int cur = 0;
    for (int t = 0; t < nt; t++) {
        bf16x8 af[2][FI], bfv[2][FJ];
        const ushort* Ab = As[cur];
        const ushort* Bb = Bs[cur];
#pragma unroll
        for (int ks = 0; ks < 2; ks++) {
#pragma unroll
            for (int i = 0; i < FI; i++) af[ks][i] = *(const bf16x8*)(Ab + aoff[ks][i]);
#pragma unroll
            for (int j = 0; j < FJ; j++) bfv[ks][j] = *(const bf16x8*)(Bb + boff[ks][j]);
        }
        __builtin_amdgcn_s_setprio(1);
#pragma unroll
        for (int ks = 0; ks < 2; ks++)
#pragma unroll
            for (int i = 0; i < FI; i++)
#pragma unroll
                for (int j = 0; j < FJ; j++)
                    acc[i][j] = __builtin_amdgcn_mfma_f32_16x16x32_bf16(af[ks][i], bfv[ks][j], acc[i][j], 0, 0, 0);
        __builtin_amdgcn_s_setprio(0);
        __builtin_amdgcn_sched_barrier(0);
        __builtin_amdgcn_s_barrier();
        if (t + 2 < nt) {
            stage(cur, (t + 2) << 6);
            waitcnt_vm<L>();
        } else if (t + 1 < nt) {
            waitcnt_vm<0>();
        }
        __builtin_amdgcn_s_barrier();
        __builtin_amdgcn_sched_barrier(0);
        cur ^= 1;
    }

    // C/D layout: col = lane&15, row = (lane>>4)*4 + reg
#pragma unroll
    for (int i = 0; i < FI; i++) {
        int rbase = row0 + wr * (BM / 2) + i * 16 + (lane >> 4) * 4;
#pragma unroll
        for (int j = 0; j < FJ; j++) {
            int c = col0 + wc * (BN / 2) + j * 16 + (lane & 15);
#pragma unroll
            for (int r = 0; r < 4; r++) {
                int rg = rbase + r;
                size_t off = (size_t)rg * Nc + c;
                float v = acc[i][j][r];
                if (EPI == 0) {
                    if (bias) v += bias[c];
                    if (resf) v += resf[RS ? stroff(rg, c, Nc) : off];
                    if (resb) v += bf2f(resb[off]);
                    if (Cf) { if (OS) Cf[stroff(rg, c, Nc)] = v; else Cf[off] = v; }
                    if (Cb) Cb[off] = f2bf(v);
                } else if (EPI == 1) {
                    v += bias[c];
                    float cdf = 0.5f * (1.0f + erff(v * 0.70710678118654752f));
                    Cb[off] = f2bf(v * cdf);
                    aux[off] = f2bf(cdf + v * 0.39894228040143267f * expf(-0.5f * v * v));
                } else {
                    Cb[off] = f2bf(v * bf2f(aux[(size_t)(rg & (BS_ - 1)) * Nc + c]));
                }
            }
        }
    }
}

// ---------------- MFMA QK^T: single-shot BK=64 (K=HD), XOR-swizzled ----------------
template <bool TAN>
__global__ __launch_bounds__(256) void attn_qk_mfma(const ushort* __restrict__ qkvb,
                                                    const ushort* __restrict__ dqkvp,
                                                    ushort* __restrict__ sc) {
    int work = xcd_swz(blockIdx.x, gridDim.x);
    constexpr int NT = S_ / 128;  // 4
    int mz = work / (BH_ * NT * NT);
    int rem = work % (BH_ * NT * NT);
    int bh = rem / (NT * NT);
    int r2 = rem % (NT * NT);
    int q0 = (r2 / NT) * 128, kc0 = (r2 % NT) * 128;
    int b = bh / H_, hh = bh - b * H_;
    const size_t qoff = (size_t)b * S_ * 3 * D_ + hh * HD_;
    const int ld = 3 * D_;
    const ushort* dqkv = TAN ? dqkvp + (size_t)mz * BS3D_ : nullptr;
    __shared__ ushort As[128 * 64];
    __shared__ ushort Bs[128 * 64];
    __shared__ ushort dAs[TAN ? 128 * 64 : 1];
    __shared__ ushort dBs[TAN ? 128 * 64 : 1];
    int tid = threadIdx.x;
    int wave = tid >> 6, lane = tid & 63;
    int wr = wave >> 1, wc = wave & 1;

    int srow = lane >> 3;
    int skel = ((lane & 7) ^ (lane >> 3)) * 8;
    const ushort* Ag0 = qkvb + qoff + (size_t)(q0 + srow) * ld + skel;
    const ushort* Bg0 = qkvb + qoff + D_ + (size_t)(kc0 + srow) * ld + skel;

#pragma unroll
    for (int cc = 0; cc < 4; cc++) {
        int c = wave * 4 + cc;
        gll16(Ag0 + (size_t)(c * 8) * ld, As + c * 512);
        gll16(Bg0 + (size_t)(c * 8) * ld, Bs + c * 512);
        if (TAN) {
            gll16(dqkv + qoff + (size_t)(q0 + c * 8 + srow) * ld + skel, dAs + c * 512);
            gll16(dqkv + qoff + D_ + (size_t)(kc0 + c * 8 + srow) * ld + skel, dBs + c * 512);
        }
    }
    __syncthreads();

    int frow = lane & 15, fkb = (lane >> 4) * 8;
    f32x4 acc[4][4] = {};
#pragma unroll
    for (int ks = 0; ks < 2; ks++) {
        int sw = (fkb + ks * 32) ^ ((frow & 7) * 8);
        bf16x8 af[4], bfv[4];
#pragma unroll
        for (int i = 0; i < 4; i++) af[i] = *(const bf16x8*)(As + (wr * 64 + i * 16 + frow) * 64 + sw);
#pragma unroll
        for (int j = 0; j < 4; j++) bfv[j] = *(const bf16x8*)(Bs + (wc * 64 + j * 16 + frow) * 64 + sw);
        if (!TAN) {
            __builtin_amdgcn_s_setprio(1);
#pragma unroll
            for (int i = 0; i < 4; i++)
#pragma unroll
                for (int j = 0; j < 4; j++)
                    acc[i][j] = __builtin_amdgcn_mfma_f32_16x16x32_bf16(af[i], bfv[j], acc[i][j], 0, 0, 0);
            __builtin_amdgcn_s_setprio(0);
        } else {
            bf16x8 daf[4], dbf[4];
#pragma unroll
            for (int i = 0; i < 4; i++) daf[i] = *(const bf16x8*)(dAs + (wr * 64 + i * 16 + frow) * 64 + sw);
#pragma unroll
            for (int j = 0; j < 4; j++) dbf[j] = *(const bf16x8*)(dBs + (wc * 64 + j * 16 + frow) * 64 + sw);
            __builtin_amdgcn_s_setprio(1);
#pragma unroll
            for (int i = 0; i < 4; i++)
#pragma unroll
                for (int j = 0; j < 4; j++) {
                    acc[i][j] = __builtin_amdgcn_mfma_f32_16x16x32_bf16(daf[i], bfv[j], acc[i][j], 0, 0, 0);
                    acc[i][j] = __builtin_amdgcn_mfma_f32_16x16x32_bf16(af[i], dbf[j], acc[i][j], 0, 0, 0);
                }
            __builtin_amdgcn_s_setprio(0);
        }
    }

    ushort* scm = sc + (size_t)mz * ATT_;
#pragma unroll
    for (int i = 0; i < 4; i++) {
        int rbase = q0 + wr * 64 + i * 16 + (lane >> 4) * 4;
#pragma unroll
        for (int j = 0; j < 4; j++) {
            int c = kc0 + wc * 64 + j * 16 + (lane & 15);
#pragma unroll
            for (int r = 0; r < 4; r++)
                scm[((size_t)bh * S_ + rbase + r) * S_ + c] = f2bf(acc[i][j][r] * SCALE_);
        }
    }
}

// ---------------- FUSED primal softmax + P@V: BM=64, BK=64 ----------------
// pass A: online (m,s) per row from scores; pass B: probs in reg -> attnb store + MFMA with V
// 1D grid: work = bh*8 + qi
__global__ __launch_bounds__(256) void attn_sm_av(const ushort* __restrict__ scg,
                                                  const ushort* __restrict__ Vt,
                                                  ushort* __restrict__ attnb,
                                                  ushort* __restrict__ outp) {
    int work = xcd_swz(blockIdx.x, gridDim.x);
    int bh = work / 8;
    int q0 = (work % 8) * 64;
    int b = bh / H_, hh = bh - b * H_;
    const ushort* Sg = scg + (size_t)bh * S_ * S_;
    const ushort* Vg = Vt + (size_t)bh * HD_ * S_;
    __shared__ ushort Ss[64 * 64], Vs[64 * 64];
    int tid = threadIdx.x;
    int wave = tid >> 6, lane = tid & 63;
    int wr = wave >> 1, wc = wave & 1;
    int srow = lane >> 3;
    int skel = ((lane & 7) ^ (lane >> 3)) * 8;
    int frow = lane & 15, fkb = (lane >> 4) * 8;
    int aoff[2][2], boff[2][2];
#pragma unroll
    for (int ks = 0; ks < 2; ks++) {
        int sw = (fkb + ks * 32) ^ ((frow & 7) * 8);
#pragma unroll
        for (int i = 0; i < 2; i++) aoff[ks][i] = (wr * 32 + i * 16 + frow) * 64 + sw;
#pragma unroll
        for (int j = 0; j < 2; j++) boff[ks][j] = (wc * 32 + j * 16 + frow) * 64 + sw;
    }

    // ---- pass A: online max/sum per row (rows wr*32 + i*16 + frow) ----
    float m[2] = {-1e30f, -1e30f}, s[2] = {0.f, 0.f};
    for (int k0 = 0; k0 < S_; k0 += 64) {
#pragma unroll
        for (int cc = 0; cc < 2; cc++) {
            int c = wave * 2 + cc;
            gll16(Sg + (size_t)(q0 + c * 8 + srow) * S_ + k0 + skel, Ss + c * 512);
        }
        __syncthreads();
#pragma unroll
        for (int ks = 0; ks < 2; ks++)
#pragma unroll
            for (int i = 0; i < 2; i++) {
                bf16x8 s8 = *(const bf16x8*)(Ss + aoff[ks][i]);
                float cm = -1e30f, cs = 0.f;
#pragma unroll
                for (int e = 0; e < 8; e++) cm = fmaxf(cm, bf2f((ushort)s8[e]));
#pragma unroll
                for (int e = 0; e < 8; e++) cs += expf(bf2f((ushort)s8[e]) - cm);
                float mn = fmaxf(m[i], cm);
                s[i] = s[i] * expf(m[i] - mn) + cs * expf(cm - mn);
                m[i] = mn;
            }
        __syncthreads();
    }
#pragma unroll
    for (int i = 0; i < 2; i++) {
#pragma unroll
        for (int off = 16; off <= 32; off <<= 1) {
            float m2 = __shfl_xor(m[i], off);
            float s2 = __shfl_xor(s[i], off);
            float mn = fmaxf(m[i], m2);
            s[i] = s[i] * expf(m[i] - mn) + s2 * expf(m2 - mn);
            m[i] = mn;
        }
    }
    float inv[2] = {1.0f / s[0], 1.0f / s[1]};

    // ---- pass B: probs -> attnb + MFMA with V ----
    f32x4 acc[2][2] = {};
    for (int k0 = 0; k0 < S_; k0 += 64) {
#pragma unroll
        for (int cc = 0; cc < 2; cc++) {
            int c = wave * 2 + cc;
            gll16(Sg + (size_t)(q0 + c * 8 + srow) * S_ + k0 + skel, Ss + c * 512);
            gll16(Vg + (size_t)(c * 8 + srow) * S_ + k0 + skel, Vs + c * 512);
        }
        __syncthreads();
#pragma unroll
        for (int ks = 0; ks < 2; ks++) {
            bf16x8 p8[2], v8[2];
#pragma unroll
            for (int i = 0; i < 2; i++) {
                bf16x8 s8 = *(const bf16x8*)(Ss + aoff[ks][i]);
#pragma unroll
                for (int e = 0; e < 8; e++)
                    p8[i][e] = (short)f2bf(expf(bf2f((ushort)s8[e]) - m[i]) * inv[i]);
                // store probs (linear layout: reg elems = rows (q0+wr*32+i*16+frow), k = k0+fkb+ks*32..+7)
                int rw = q0 + wr * 32 + i * 16 + frow;
                *(bf16x8*)(attnb + ((size_t)bh * S_ + rw) * S_ + k0 + fkb + ks * 32) = p8[i];
            }
#pragma unroll
            for (int j = 0; j < 2; j++) v8[j] = *(const bf16x8*)(Vs + boff[ks][j]);
            __builtin_amdgcn_s_setprio(1);
#pragma unroll
            for (int i = 0; i < 2; i++)
#pragma unroll
                for (int j = 0; j < 2; j++)
                    acc[i][j] = __builtin_amdgcn_mfma_f32_16x16x32_bf16(p8[i], v8[j], acc[i][j], 0, 0, 0);
            __builtin_amdgcn_s_setprio(0);
        }
        __syncthreads();
    }

#pragma unroll
    for (int i = 0; i < 2; i++) {
        int rbase = q0 + wr * 32 + i * 16 + (lane >> 4) * 4;
#pragma unroll
        for (int j = 0; j < 2; j++) {
            int c = hh * HD_ + wc * 32 + j * 16 + (lane & 15);
#pragma unroll
            for (int r = 0; r < 4; r++)
                outp[(size_t)(b * S_ + rbase + r) * D_ + c] = f2bf(acc[i][j][r]);
        }
    }
}

// ---------------- FUSED tangent P@V: dattn + (dP@V + P@dV), BM=64, BK=64 ----------------
__global__ __launch_bounds__(256) void attn_av_tan(const ushort* __restrict__ Pb,
                                                   const ushort* __restrict__ dscp,
                                                   const ushort* __restrict__ Vt,
                                                   const ushort* __restrict__ dVtp,
                                                   ushort* __restrict__ outp) {
    int work = xcd_swz(blockIdx.x, gridDim.x);
    int mz = work / (BH_ * 8);
    int rem = work % (BH_ * 8);
    int bh = rem / 8;
    int q0 = (rem % 8) * 64;
    int b = bh / H_, hh = bh - b * H_;
    const ushort* Pg = Pb + (size_t)bh * S_ * S_;
    const ushort* Dg = dscp + (size_t)mz * ATT_ + (size_t)bh * S_ * S_;
    const ushort* Vg = Vt + (size_t)bh * HD_ * S_;
    const ushort* dVg = dVtp + (size_t)mz * BSD_ + (size_t)bh * HD_ * S_;
    ushort* outm = outp + (size_t)mz * BSD_;
    __shared__ ushort Ps[64 * 64], Ds[64 * 64], Vs[64 * 64], dVs[64 * 64];
    int tid = threadIdx.x;
    int wave = tid >> 6, lane = tid & 63;
    int wr = wave >> 1, wc = wave & 1;
    int srow = lane >> 3;
    int skel = ((lane & 7) ^ (lane >> 3)) * 8;
    int frow = lane & 15, fkb = (lane >> 4) * 8;
    int aoff[2][2], boff[2][2];
#pragma unroll
    for (int ks = 0; ks < 2; ks++) {
        int sw = (fkb + ks * 32) ^ ((frow & 7) * 8);
#pragma unroll
        for (int i = 0; i < 2; i++) aoff[ks][i] = (wr * 32 + i * 16 + frow) * 64 + sw;
#pragma unroll
        for (int j = 0; j < 2; j++) boff[ks][j] = (wc * 32 + j * 16 + frow) * 64 + sw;
    }

    // ---- pass 1: row sums s[i] ----
    float s[2] = {0.f, 0.f};
    for (int k0 = 0; k0 < S_; k0 += 64) {
#pragma unroll
        for (int cc = 0; cc < 2; cc++) {
            int c = wave * 2 + cc;
            gll16(Pg + (size_t)(q0 + c * 8 + srow) * S_ + k0 + skel, Ps + c * 512);
            gll16(Dg + (size_t)(q0 + c * 8 + srow) * S_ + k0 + skel, Ds + c * 512);
        }
        __syncthreads();
#pragma unroll
        for (int ks = 0; ks < 2; ks++)
#pragma unroll
            for (int i = 0; i < 2; i++) {
                bf16x8 p8 = *(const bf16x8*)(Ps + aoff[ks][i]);
                bf16x8 d8 = *(const bf16x8*)(Ds + aoff[ks][i]);
#pragma unroll
                for (int e = 0; e < 8; e++)
                    s[i] += bf2f((ushort)p8[e]) * bf2f((ushort)d8[e]);
            }
        __syncthreads();
    }
#pragma unroll
    for (int i = 0; i < 2; i++) {
        s[i] += __shfl_xor(s[i], 16);
        s[i] += __shfl_xor(s[i], 32);
    }

    // ---- pass 2: acc = dP@V + P@dV ----
    f32x4 acc[2][2] = {};
    for (int k0 = 0; k0 < S_; k0 += 64) {
#pragma unroll
        for (int cc = 0; cc < 2; cc++) {
            int c = wave * 2 + cc;
            gll16(Pg + (size_t)(q0 + c * 8 + srow) * S_ + k0 + skel, Ps + c * 512);
            gll16(Dg + (size_t)(q0 + c * 8 + srow) * S_ + k0 + skel, Ds + c * 512);
            gll16(Vg + (size_t)(c * 8 + srow) * S_ + k0 + skel, Vs + c * 512);
            gll16(dVg + (size_t)(c * 8 + srow) * S_ + k0 + skel, dVs + c * 512);
        }
        __syncthreads();
#pragma unroll
        for (int ks = 0; ks < 2; ks++) {
            bf16x8 p8[2], dp8[2], v8[2], dv8[2];
#pragma unroll
            for (int i = 0; i < 2; i++) {
                p8[i] = *(const bf16x8*)(Ps + aoff[ks][i]);
                bf16x8 d8 = *(const bf16x8*)(Ds + aoff[ks][i]);
#pragma unroll
                for (int e = 0; e < 8; e++)
                    dp8[i][e] = (short)f2bf(bf2f((ushort)p8[i][e]) * (bf2f((ushort)d8[e]) - s[i]));
            }
#pragma unroll
            for (int j = 0; j < 2; j++) {
                v8[j] = *(const bf16x8*)(Vs + boff[ks][j]);
                dv8[j] = *(const bf16x8*)(dVs + boff[ks][j]);
            }
            __builtin_amdgcn_s_setprio(1);
#pragma unroll
            for (int i = 0; i < 2; i++)
#pragma unroll
                for (int j = 0; j < 2; j++) {
                    acc[i][j] = __builtin_amdgcn_mfma_f32_16x16x32_bf16(dp8[i], v8[j], acc[i][j], 0, 0, 0);
                    acc[i][j] = __builtin_amdgcn_mfma_f32_16x16x32_bf16(p8[i], dv8[j], acc[i][j], 0, 0, 0);
                }
            __builtin_amdgcn_s_setprio(0);
        }
        __syncthreads();
    }

#pragma unroll
    for (int i = 0; i < 2; i++) {
        int rbase = q0 + wr * 32 + i * 16 + (lane >> 4) * 4;
#pragma unroll
        for (int j = 0; j < 2; j++) {
            int c = hh * HD_ + wc * 32 + j * 16 + (lane & 15);
#pragma unroll
            for (int r = 0; r < 4; r++)
                outm[(size_t)(b * S_ + rbase + r) * D_ + c] = f2bf(acc[i][j][r]);
        }
    }
}

// ---------------- host ----------------
extern "C" void kernel_launch(void* const* d_in, const int* in_sizes, int n_in,
                              void* d_out, int out_size, void* d_ws, size_t ws_size,
                              hipStream_t stream) {
    const float* x = (const float*)d_in[0];
    const float* xt = (const float*)d_in[1];
    const float* g1 = (const float*)d_in[2];
    const float* b1 = (const float*)d_in[3];
    const float* Wqkv = (const float*)d_in[4];
    const float* Wproj = (const float*)d_in[5];
    const float* bproj = (const float*)d_in[6];
    const float* g2 = (const float*)d_in[7];
    const float* b2 = (const float*)d_in[8];
    const float* W1 = (const float*)d_in[9];
    const float* bf1 = (const float*)d_in[10];
    const float* W2 = (const float*)d_in[11];
    const float* bf2 = (const float*)d_in[12];
    float* out = (float*)d_out;
    float* out_t = out + BSD_;   // [B,M,S,D]

    char* wp = (char*)d_ws;
    auto alloc = [&](size_t bytes) { void* p = wp; wp += (bytes + 255) & ~(size_t)255; return p; };
    ushort* xhat1 = (ushort*)alloc(BSD_ * 2);
    ushort* hb = (ushort*)alloc(BSD_ * 2);
    ushort* obb = (ushort*)alloc(BSD_ * 2);
    float* x2 = (float*)alloc(BSD_ * 4);
    ushort* xhat2 = (ushort*)alloc(BSD_ * 2);
    ushort* h2b = (ushort*)alloc(BSD_ * 2);
    ushort* dx2b = (ushort*)alloc(4 * BSD_ * 2);   // [4*BS][D] bf16
    ushort* qkvb = (ushort*)alloc(BS3D_ * 2);
    ushort* Vt = (ushort*)alloc(BSD_ * 2);
    ushort* dscb2 = (ushort*)alloc(2 * ATT_ * 2);  // [2][BH,S,S]: primal scores / tangent-pair dsc
    ushort* attnb = (ushort*)alloc(ATT_ * 2);      // primal probs bf16
    ushort* gpb = (ushort*)alloc(BSF_ * 2);        // gelu'(u) bf16
    float* rstd1 = (float*)alloc(BS_ * 4);
    float* rstd2 = (float*)alloc(BS_ * 4);
    ushort* WqkvT = (ushort*)alloc((size_t)D_ * 3 * D_ * 2);
    ushort* WprojT = (ushort*)alloc((size_t)D_ * D_ * 2);
    ushort* W1T = (ushort*)alloc((size_t)DFF_ * D_ * 2);
    ushort* W2T = (ushort*)alloc((size_t)D_ * DFF_ * 2);
    // Region A (50.3 MB): phase1 {dqkvb4 + dVt4}, phase2 {da4}
    char* regA = (char*)alloc(4 * BSF_ * 2);
    ushort* dqkvb4 = (ushort*)regA;
    ushort* dVt4 = (ushort*)(regA + 4 * BS3D_ * 2);
    ushort* da4 = (ushort*)regA;
    // Region B (12.6 MB): {ab} -> {dh4} -> {dob4} -> {dh2_4}
    char* regB = (char*)alloc(4 * BSD_ * 2);
    ushort* ab = (ushort*)regB;
    ushort* dh4 = (ushort*)regB;
    ushort* dob4 = (ushort*)regB;
    ushort* dh2_4 = (ushort*)regB;

    // ---- weights -> bf16 transposed [N][K] ----
    transpose_f2b<<<dim3(3 * D_ / 32, D_ / 32), 256, 0, stream>>>(Wqkv, WqkvT, D_, 3 * D_);
    transpose_f2b<<<dim3(D_ / 32, D_ / 32), 256, 0, stream>>>(Wproj, WprojT, D_, D_);
    transpose_f2b<<<dim3(DFF_ / 32, D_ / 32), 256, 0, stream>>>(W1, W1T, D_, DFF_);
    transpose_f2b<<<dim3(D_ / 32, DFF_ / 32), 256, 0, stream>>>(W2, W2T, DFF_, D_);

    // ---- primal ----
    ln_fwd<<<BS_, 256, 0, stream>>>(x, g1, b1, xhat1, hb, rstd1);
    gemm_mfma<64, 128, 0, false, false><<<dim3(3 * D_ / 128, BS_ / 64), 256, 0, stream>>>(
        hb, WqkvT, nullptr, nullptr, nullptr, nullptr, qkvb, nullptr, 3 * D_, D_);
    transpose_v<<<dim3(S_ / 32, HD_ / 32, BH_), 256, 0, stream>>>(qkvb, Vt);
    attn_qk_mfma<false><<<(S_ / 128) * (S_ / 128) * BH_, 256, 0, stream>>>(qkvb, nullptr, dscb2);
    attn_sm_av<<<8 * BH_, 256, 0, stream>>>(dscb2, Vt, attnb, obb);
    gemm_mfma<64, 64, 0, false, false><<<dim3(D_ / 64, BS_ / 64), 256, 0, stream>>>(
        obb, WprojT, bproj, x, nullptr, x2, nullptr, nullptr, D_, D_);
    ln_fwd<<<BS_, 256, 0, stream>>>(x2, g2, b2, xhat2, h2b, rstd2);
    gemm_mfma<128, 128, 1, false, false><<<dim3(DFF_ / 128, BS_ / 128), 256, 0, stream>>>(
        h2b, W1T, bf1, nullptr, nullptr, nullptr, ab, gpb, DFF_, D_);
    gemm_mfma<64, 64, 0, false, false><<<dim3(D_ / 64, BS_ / 64), 256, 0, stream>>>(
        ab, W2T, bf2, x2, nullptr, out, nullptr, nullptr, D_, DFF_);

    // ---- tangents: batched linear stages (M = 8192), pair-batched fused attention ----
    ln_jvp<<<4 * BS_, 256, 0, stream>>>(xt, nullptr, 0, xhat1, rstd1, g1, dh4);
    gemm_mfma<128, 128, 0, false, false><<<dim3(3 * D_ / 128, 4 * BS_ / 128), 256, 0, stream>>>(
        dh4, WqkvT, nullptr, nullptr, nullptr, nullptr, dqkvb4, nullptr, 3 * D_, D_);
    transpose_v<<<dim3(S_ / 32, HD_ / 32, 4 * BH_), 256, 0, stream>>>(dqkvb4, dVt4);
    for (int p = 0; p < 2; p++) {
        attn_qk_mfma<true><<<2 * (S_ / 128) * (S_ / 128) * BH_, 256, 0, stream>>>(
            qkvb, dqkvb4 + (size_t)p * 2 * BS3D_, dscb2);
        attn_av_tan<<<2 * 8 * BH_, 256, 0, stream>>>(
            attnb, dscb2, Vt, dVt4 + (size_t)p * 2 * BSD_, dob4 + (size_t)p * 2 * BSD_);
    }
    gemm_mfma<128, 64, 0, true, false><<<dim3(D_ / 64, 4 * BS_ / 128), 256, 0, stream>>>(
        dob4, WprojT, nullptr, xt, nullptr, nullptr, dx2b, nullptr, D_, D_);
    ln_jvp<<<4 * BS_, 256, 0, stream>>>(nullptr, dx2b, 1, xhat2, rstd2, g2, dh2_4);
    gemm_mfma<128, 128, 2, false, false><<<dim3(DFF_ / 128, 4 * BS_ / 128), 256, 0, stream>>>(
        dh2_4, W1T, nullptr, nullptr, nullptr, nullptr, da4, gpb, DFF_, D_);
    gemm_mfma<128, 64, 0, false, true><<<dim3(D_ / 64, 4 * BS_ / 128), 256, 0, stream>>>(
        da4, W2T, nullptr, nullptr, dx2b, out_t, nullptr, nullptr, D_, DFF_);
}

// Round 12
// 485.570 us; speedup vs baseline: 1.0558x; 1.0558x over previous
//
#include <hip/hip_runtime.h>
#include <math.h>

constexpr int B_ = 4, S_ = 512, D_ = 768, H_ = 12, M_ = 4, DFF_ = 3072, HD_ = 64;
constexpr float EPS_ = 1e-6f;
constexpr float SCALE_ = 0.125f;  // HD^-0.5
constexpr int BS_ = B_ * S_;
constexpr int BH_ = B_ * H_;
constexpr long long BSD_ = (long long)BS_ * D_;
constexpr long long BS3D_ = (long long)BS_ * 3 * D_;
constexpr long long ATT_ = (long long)BH_ * S_ * S_;
constexpr long long BSF_ = (long long)BS_ * DFF_;

typedef __attribute__((ext_vector_type(8))) short bf16x8;
typedef __attribute__((ext_vector_type(4))) float f32x4;

__device__ __forceinline__ ushort f2bf(float f) {
    uint32_t u = __float_as_uint(f);
    u += 0x7FFF + ((u >> 16) & 1);
    return (ushort)(u >> 16);
}
__device__ __forceinline__ float bf2f(ushort u) {
    return __uint_as_float((uint32_t)u << 16);
}

__device__ __forceinline__ void gll16(const ushort* g, ushort* l) {
    __builtin_amdgcn_global_load_lds((const __attribute__((address_space(1))) void*)g,
                                     (__attribute__((address_space(3))) void*)l, 16, 0, 0);
}

// counted vmcnt wait (literal required in asm)
template <int N> __device__ __forceinline__ void waitcnt_vm() {
    if constexpr (N == 0) asm volatile("s_waitcnt vmcnt(0)" ::: "memory");
    else if constexpr (N == 4) asm volatile("s_waitcnt vmcnt(4)" ::: "memory");
    else if constexpr (N == 6) asm volatile("s_waitcnt vmcnt(6)" ::: "memory");
    else if constexpr (N == 8) asm volatile("s_waitcnt vmcnt(8)" ::: "memory");
    else static_assert(N == 0 || N == 4 || N == 6 || N == 8, "add literal");
}

// XCD-chunked bijective block remap (m204)
__device__ __forceinline__ int xcd_swz(int flat, int nwg) {
    int q = nwg >> 3, r = nwg & 7;
    int x = flat & 7, pos = flat >> 3;
    int base = (x < r) ? x * (q + 1) : r * (q + 1) + (x - r) * q;
    return base + pos;
}

// batched-row (rg in [0,8192)) -> [B,M,S,Nc] offset
__device__ __forceinline__ size_t stroff(int rg, int c, int Nc) {
    int m = rg >> 11;
    int b = (rg >> 9) & (B_ - 1);
    int s = rg & (S_ - 1);
    return ((size_t)((b * M_ + m) * S_ + s)) * Nc + c;
}

// ---------------- block reductions (256 threads = 4 waves) ----------------
__device__ __forceinline__ float block_sum(float v) {
    __shared__ float red[4];
    int tid = threadIdx.x;
#pragma unroll
    for (int off = 32; off > 0; off >>= 1) v += __shfl_down(v, off, 64);
    __syncthreads();
    if ((tid & 63) == 0) red[tid >> 6] = v;
    __syncthreads();
    return red[0] + red[1] + red[2] + red[3];
}

__device__ __forceinline__ float block_max(float v) {
    __shared__ float red[4];
    int tid = threadIdx.x;
#pragma unroll
    for (int off = 32; off > 0; off >>= 1) v = fmaxf(v, __shfl_down(v, off, 64));
    __syncthreads();
    if ((tid & 63) == 0) red[tid >> 6] = v;
    __syncthreads();
    return fmaxf(fmaxf(red[0], red[1]), fmaxf(red[2], red[3]));
}

// ---------------- weight transpose+convert: W[K][N] f32 -> WT[N][K] bf16 ----------------
__global__ __launch_bounds__(256) void transpose_f2b(const float* __restrict__ W,
                                                     ushort* __restrict__ WT,
                                                     int K, int N) {
    __shared__ float t[32][33];
    int n0 = blockIdx.x * 32, k0 = blockIdx.y * 32;
    int tx = threadIdx.x & 31, ty = threadIdx.x >> 5;
#pragma unroll
    for (int i = 0; i < 4; i++)
        t[ty + i * 8][tx] = W[(size_t)(k0 + ty + i * 8) * N + n0 + tx];
    __syncthreads();
#pragma unroll
    for (int i = 0; i < 4; i++)
        WT[(size_t)(n0 + ty + i * 8) * K + k0 + tx] = f2bf(t[tx][ty + i * 8]);
}

// ---------------- V transpose: src[m][B,S,3D] bf16 -> dst[m][bh][HD][S] bf16 ----------------
__global__ __launch_bounds__(256) void transpose_v(const ushort* __restrict__ src0,
                                                   ushort* __restrict__ dst0) {
    int z = blockIdx.z;
    int m = z / BH_, bh = z % BH_;
    const ushort* qkvb = src0 + (size_t)m * BS3D_;
    ushort* Vt = dst0 + (size_t)m * BSD_;
    int b = bh / H_, hh = bh - b * H_;
    int s0 = blockIdx.x * 32, d0 = blockIdx.y * 32;
    __shared__ ushort t[32][33];
    int tx = threadIdx.x & 31, ty = threadIdx.x >> 5;
#pragma unroll
    for (int i = 0; i < 4; i++)
        t[ty + i * 8][tx] = qkvb[(size_t)(b * S_ + s0 + ty + i * 8) * 3 * D_ + 2 * D_ + hh * HD_ + d0 + tx];
    __syncthreads();
#pragma unroll
    for (int i = 0; i < 4; i++)
        Vt[(size_t)bh * HD_ * S_ + (size_t)(d0 + ty + i * 8) * S_ + s0 + tx] = t[tx][ty + i * 8];
}

// ---------------- LayerNorm forward: xhat bf16, h bf16 ----------------
__global__ __launch_bounds__(256) void ln_fwd(const float* __restrict__ x,
                                              const float* __restrict__ g,
                                              const float* __restrict__ bta,
                                              ushort* __restrict__ xhat,
                                              ushort* __restrict__ h,
                                              float* __restrict__ rstd) {
    int row = blockIdx.x;
    const float* xr = x + (size_t)row * D_;
    int tid = threadIdx.x;
    float v[3];
    float s = 0.f;
#pragma unroll
    for (int i = 0; i < 3; i++) { v[i] = xr[tid + i * 256]; s += v[i]; }
    s = block_sum(s);
    float mu = s * (1.0f / D_);
    float vs = 0.f;
#pragma unroll
    for (int i = 0; i < 3; i++) { float c = v[i] - mu; vs += c * c; }
    vs = block_sum(vs);
    float rs = rsqrtf(vs * (1.0f / D_) + EPS_);
#pragma unroll
    for (int i = 0; i < 3; i++) {
        int c = tid + i * 256;
        float xh = (v[i] - mu) * rs;
        xhat[(size_t)row * D_ + c] = f2bf(xh);
        h[(size_t)row * D_ + c] = f2bf(xh * g[c] + bta[c]);
    }
    if (tid == 0) rstd[row] = rs;
}

// ---------------- batched LayerNorm JVP: grid 4*BS_ rows ----------------
__global__ __launch_bounds__(256) void ln_jvp(const float* __restrict__ tf,
                                              const ushort* __restrict__ tb, int mode,
                                              const ushort* __restrict__ xhat,
                                              const float* __restrict__ rstd,
                                              const float* __restrict__ g,
                                              ushort* __restrict__ dh) {
    int rg = blockIdx.x;
    int r = rg & (BS_ - 1);
    size_t pbase = (size_t)r * D_;
    int tid = threadIdx.x;
    float tv[3], xh[3];
    float s1 = 0.f, s2 = 0.f;
    size_t tbase;
    if (mode == 0) {
        int m = rg >> 11;
        int b = r >> 9, s = r & (S_ - 1);
        tbase = ((size_t)((b * M_ + m) * S_ + s)) * D_;
    } else {
        tbase = (size_t)rg * D_;
    }
#pragma unroll
    for (int i = 0; i < 3; i++) {
        int c = tid + i * 256;
        tv[i] = (mode == 0) ? tf[tbase + c] : bf2f(tb[tbase + c]);
        xh[i] = bf2f(xhat[pbase + c]);
        s1 += tv[i];
        s2 += tv[i] * xh[i];
    }
    s1 = block_sum(s1);
    s2 = block_sum(s2);
    float mt = s1 * (1.0f / D_);
    float mx = s2 * (1.0f / D_);
    float rs = rstd[r];
#pragma unroll
    for (int i = 0; i < 3; i++) {
        int c = tid + i * 256;
        dh[(size_t)rg * D_ + c] = f2bf(g[c] * rs * (tv[i] - mt - xh[i] * mx));
    }
}

// ---------------- bf16 MFMA GEMM <BM,BN>, BK=64, 2-deep dbuf pipeline (T3/T4) ----------------
template <int BM, int BN, int EPI, bool RS, bool OS>
__global__ __launch_bounds__(256) void gemm_mfma(const ushort* __restrict__ A,
                                                 const ushort* __restrict__ BT,
                                                 const float* __restrict__ bias,
                                                 const float* __restrict__ resf,
                                                 const ushort* __restrict__ resb,
                                                 float* __restrict__ Cf,
                                                 ushort* __restrict__ Cb,
                                                 ushort* __restrict__ aux,
                                                 int Nc, int Kd) {
    constexpr int FI = BM / 32, FJ = BN / 32;
    constexpr int LA = BM / 32, LB = BN / 32, L = LA + LB;
    __shared__ ushort As[2][BM * 64];
    __shared__ ushort Bs[2][BN * 64];
    int tid = threadIdx.x;
    int wave = tid >> 6, lane = tid & 63;
    int wr = wave >> 1, wc = wave & 1;
    int gx = gridDim.x, nwg = gx * gridDim.y;
    int work = xcd_swz(blockIdx.x + blockIdx.y * gx, nwg);
    int row0 = (work / gx) * BM, col0 = (work % gx) * BN;

    int srow = lane >> 3;
    int skel = ((lane & 7) ^ (lane >> 3)) * 8;
    const ushort* Ag0 = A + (size_t)(row0 + srow) * Kd + skel;
    const ushort* Bg0 = BT + (size_t)(col0 + srow) * Kd + skel;

    auto stage = [&](int bufi, int k0) {
#pragma unroll
        for (int cc = 0; cc < LA; cc++) {
            int c = wave * LA + cc;
            gll16(Ag0 + (size_t)(c * 8) * Kd + k0, As[bufi] + c * 512);
        }
#pragma unroll
        for (int cc = 0; cc < LB; cc++) {
            int c = wave * LB + cc;
            gll16(Bg0 + (size_t)(c * 8) * Kd + k0, Bs[bufi] + c * 512);
        }
    };

    int frow = lane & 15, fkb = (lane >> 4) * 8;
    int aoff[2][FI], boff[2][FJ];
#pragma unroll
    for (int ks = 0; ks < 2; ks++) {
        int sw = (fkb + ks * 32) ^ ((frow & 7) * 8);
#pragma unroll
        for (int i = 0; i < FI; i++) aoff[ks][i] = (wr * (BM / 2) + i * 16 + frow) * 64 + sw;
#pragma unroll
        for (int j = 0; j < FJ; j++) boff[ks][j] = (wc * (BN / 2) + j * 16 + frow) * 64 + sw;
    }

    f32x4 acc[FI][FJ] = {};

    int nt = Kd >> 6;
    stage(0, 0);
    if (nt > 1) { stage(1, 64); waitcnt_vm<L>(); }
    else        { waitcnt_vm<0>(); }
    __builtin_amdgcn_s_barrier();
    __builtin_amdgcn_sched_barrier(0);

    int cur = 0;
    for (int t = 0; t < nt; t++) {
        bf16x8 af[2][FI], bfv[2][FJ];
        const ushort* Ab = As[cur];
        const ushort* Bb = Bs[cur];
#pragma unroll
        for (int ks = 0; ks < 2; ks++) {
#pragma unroll
            for (int i = 0; i < FI; i++) af[ks][i] = *(const bf16x8*)(Ab + aoff[ks][i]);
#pragma unroll
            for (int j = 0; j < FJ; j++) bfv[ks][j] = *(const bf16x8*)(Bb + boff[ks][j]);
        }
#pragma unroll
        for (int ks = 0; ks < 2; ks++)
#pragma unroll
            for (int i = 0; i < FI; i++)
#pragma unroll
                for (int j = 0; j < FJ; j++)
                    acc[i][j] = __builtin_amdgcn_mfma_f32_16x16x32_bf16(af[ks][i], bfv[ks][j], acc[i][j], 0, 0, 0);
        __builtin_amdgcn_sched_barrier(0);
        __builtin_amdgcn_s_barrier();
        if (t + 2 < nt) {
            stage(cur, (t + 2) << 6);
            waitcnt_vm<L>();
        } else if (t + 1 < nt) {
            waitcnt_vm<0>();
        }
        __builtin_amdgcn_s_barrier();
        __builtin_amdgcn_sched_barrier(0);
        cur ^= 1;
    }

    // C/D layout: col = lane&15, row = (lane>>4)*4 + reg
#pragma unroll
    for (int i = 0; i < FI; i++) {
        int rbase = row0 + wr * (BM / 2) + i * 16 + (lane >> 4) * 4;
#pragma unroll
        for (int j = 0; j < FJ; j++) {
            int c = col0 + wc * (BN / 2) + j * 16 + (lane & 15);
#pragma unroll
            for (int r = 0; r < 4; r++) {
                int rg = rbase + r;
                size_t off = (size_t)rg * Nc + c;
                float v = acc[i][j][r];
                if (EPI == 0) {
                    if (bias) v += bias[c];
                    if (resf) v += resf[RS ? stroff(rg, c, Nc) : off];
                    if (resb) v += bf2f(resb[off]);
                    if (Cf) { if (OS) Cf[stroff(rg, c, Nc)] = v; else Cf[off] = v; }
                    if (Cb) Cb[off] = f2bf(v);
                } else if (EPI == 1) {
                    v += bias[c];
                    float cdf = 0.5f * (1.0f + erff(v * 0.70710678118654752f));
                    Cb[off] = f2bf(v * cdf);
                    aux[off] = f2bf(cdf + v * 0.39894228040143267f * expf(-0.5f * v * v));
                } else {
                    Cb[off] = f2bf(v * bf2f(aux[(size_t)(rg & (BS_ - 1)) * Nc + c]));
                }
            }
        }
    }
}

// ---------------- MFMA QK^T: single-shot BK=64 (K=HD), XOR-swizzled ----------------
template <bool TAN>
__global__ __launch_bounds__(256) void attn_qk_mfma(const ushort* __restrict__ qkvb,
                                                    const ushort* __restrict__ dqkvp,
                                                    ushort* __restrict__ sc) {
    int work = xcd_swz(blockIdx.x, gridDim.x);
    constexpr int NT = S_ / 128;  // 4
    int mz = work / (BH_ * NT * NT);
    int rem = work % (BH_ * NT * NT);
    int bh = rem / (NT * NT);
    int r2 = rem % (NT * NT);
    int q0 = (r2 / NT) * 128, kc0 = (r2 % NT) * 128;
    int b = bh / H_, hh = bh - b * H_;
    const size_t qoff = (size_t)b * S_ * 3 * D_ + hh * HD_;
    const int ld = 3 * D_;
    const ushort* dqkv = TAN ? dqkvp + (size_t)mz * BS3D_ : nullptr;
    __shared__ ushort As[128 * 64];
    __shared__ ushort Bs[128 * 64];
    __shared__ ushort dAs[TAN ? 128 * 64 : 1];
    __shared__ ushort dBs[TAN ? 128 * 64 : 1];
    int tid = threadIdx.x;
    int wave = tid >> 6, lane = tid & 63;
    int wr = wave >> 1, wc = wave & 1;

    int srow = lane >> 3;
    int skel = ((lane & 7) ^ (lane >> 3)) * 8;
    const ushort* Ag0 = qkvb + qoff + (size_t)(q0 + srow) * ld + skel;
    const ushort* Bg0 = qkvb + qoff + D_ + (size_t)(kc0 + srow) * ld + skel;

#pragma unroll
    for (int cc = 0; cc < 4; cc++) {
        int c = wave * 4 + cc;
        gll16(Ag0 + (size_t)(c * 8) * ld, As + c * 512);
        gll16(Bg0 + (size_t)(c * 8) * ld, Bs + c * 512);
        if (TAN) {
            gll16(dqkv + qoff + (size_t)(q0 + c * 8 + srow) * ld + skel, dAs + c * 512);
            gll16(dqkv + qoff + D_ + (size_t)(kc0 + c * 8 + srow) * ld + skel, dBs + c * 512);
        }
    }
    __syncthreads();

    int frow = lane & 15, fkb = (lane >> 4) * 8;
    f32x4 acc[4][4] = {};
#pragma unroll
    for (int ks = 0; ks < 2; ks++) {
        int sw = (fkb + ks * 32) ^ ((frow & 7) * 8);
        bf16x8 af[4], bfv[4];
#pragma unroll
        for (int i = 0; i < 4; i++) af[i] = *(const bf16x8*)(As + (wr * 64 + i * 16 + frow) * 64 + sw);
#pragma unroll
        for (int j = 0; j < 4; j++) bfv[j] = *(const bf16x8*)(Bs + (wc * 64 + j * 16 + frow) * 64 + sw);
        if (!TAN) {
#pragma unroll
            for (int i = 0; i < 4; i++)
#pragma unroll
                for (int j = 0; j < 4; j++)
                    acc[i][j] = __builtin_amdgcn_mfma_f32_16x16x32_bf16(af[i], bfv[j], acc[i][j], 0, 0, 0);
        } else {
            bf16x8 daf[4], dbf[4];
#pragma unroll
            for (int i = 0; i < 4; i++) daf[i] = *(const bf16x8*)(dAs + (wr * 64 + i * 16 + frow) * 64 + sw);
#pragma unroll
            for (int j = 0; j < 4; j++) dbf[j] = *(const bf16x8*)(dBs + (wc * 64 + j * 16 + frow) * 64 + sw);
#pragma unroll
            for (int i = 0; i < 4; i++)
#pragma unroll
                for (int j = 0; j < 4; j++) {
                    acc[i][j] = __builtin_amdgcn_mfma_f32_16x16x32_bf16(daf[i], bfv[j], acc[i][j], 0, 0, 0);
                    acc[i][j] = __builtin_amdgcn_mfma_f32_16x16x32_bf16(af[i], dbf[j], acc[i][j], 0, 0, 0);
                }
        }
    }

    ushort* scm = sc + (size_t)mz * ATT_;
#pragma unroll
    for (int i = 0; i < 4; i++) {
        int rbase = q0 + wr * 64 + i * 16 + (lane >> 4) * 4;
#pragma unroll
        for (int j = 0; j < 4; j++) {
            int c = kc0 + wc * 64 + j * 16 + (lane & 15);
#pragma unroll
            for (int r = 0; r < 4; r++)
                scm[((size_t)bh * S_ + rbase + r) * S_ + c] = f2bf(acc[i][j][r] * SCALE_);
        }
    }
}

// ---------------- primal P@V: BK=64, XOR-swizzled ----------------
__global__ __launch_bounds__(256) void attn_av_p(const ushort* __restrict__ Pb,
                                                 const ushort* __restrict__ Vt,
                                                 ushort* __restrict__ outp) {
    int work = xcd_swz(blockIdx.x, gridDim.x);
    constexpr int NT = S_ / 128;  // 4
    int bh = work / NT;
    int q0 = (work % NT) * 128;
    int b = bh / H_, hh = bh - b * H_;
    const ushort* Pg = Pb + (size_t)bh * S_ * S_;
    const ushort* Vg = Vt + (size_t)bh * HD_ * S_;
    __shared__ ushort As[128 * 64];
    __shared__ ushort Bs[64 * 64];
    int tid = threadIdx.x;
    int wave = tid >> 6, lane = tid & 63;
    int wr = wave >> 1, wc = wave & 1;
    int srow = lane >> 3;
    int skel = ((lane & 7) ^ (lane >> 3)) * 8;
    int frow = lane & 15, fkb = (lane >> 4) * 8;

    f32x4 acc[4][2] = {};
    for (int k0 = 0; k0 < S_; k0 += 64) {
#pragma unroll
        for (int cc = 0; cc < 4; cc++) {
            int c = wave * 4 + cc;
            gll16(Pg + (size_t)(q0 + c * 8 + srow) * S_ + k0 + skel, As + c * 512);
        }
#pragma unroll
        for (int cc = 0; cc < 2; cc++) {
            int c = wave * 2 + cc;
            gll16(Vg + (size_t)(c * 8 + srow) * S_ + k0 + skel, Bs + c * 512);
        }
        __syncthreads();
#pragma unroll
        for (int ks = 0; ks < 2; ks++) {
            int sw = (fkb + ks * 32) ^ ((frow & 7) * 8);
            bf16x8 af[4], bfv[2];
#pragma unroll
            for (int i = 0; i < 4; i++) af[i] = *(const bf16x8*)(As + (wr * 64 + i * 16 + frow) * 64 + sw);
#pragma unroll
            for (int j = 0; j < 2; j++) bfv[j] = *(const bf16x8*)(Bs + (wc * 32 + j * 16 + frow) * 64 + sw);
#pragma unroll
            for (int i = 0; i < 4; i++)
#pragma unroll
                for (int j = 0; j < 2; j++)
                    acc[i][j] = __builtin_amdgcn_mfma_f32_16x16x32_bf16(af[i], bfv[j], acc[i][j], 0, 0, 0);
        }
        __syncthreads();
    }

#pragma unroll
    for (int i = 0; i < 4; i++) {
        int rbase = q0 + wr * 64 + i * 16 + (lane >> 4) * 4;
#pragma unroll
        for (int j = 0; j < 2; j++) {
            int c = hh * HD_ + wc * 32 + j * 16 + (lane & 15);
#pragma unroll
            for (int r = 0; r < 4; r++)
                outp[(size_t)(b * S_ + rbase + r) * D_ + c] = f2bf(acc[i][j][r]);
        }
    }
}

// ---------------- FUSED tangent P@V (single pass): dO = (P.D)@V + P@dV - s*O ----------------
// s = rowsum(P.D) accumulated alongside the MFMAs; epilogue subtracts s*O (O = primal out).
// 1D grid: work = mz*(BH*8) + bh*8 + qi
__global__ __launch_bounds__(256) void attn_av_tan(const ushort* __restrict__ Pb,
                                                   const ushort* __restrict__ dscp,
                                                   const ushort* __restrict__ Vt,
                                                   const ushort* __restrict__ dVtp,
                                                   const ushort* __restrict__ Ob,
                                                   ushort* __restrict__ outp) {
    int work = xcd_swz(blockIdx.x, gridDim.x);
    int mz = work / (BH_ * 8);
    int rem = work % (BH_ * 8);
    int bh = rem / 8;
    int q0 = (rem % 8) * 64;
    int b = bh / H_, hh = bh - b * H_;
    const ushort* Pg = Pb + (size_t)bh * S_ * S_;
    const ushort* Dg = dscp + (size_t)mz * ATT_ + (size_t)bh * S_ * S_;
    const ushort* Vg = Vt + (size_t)bh * HD_ * S_;
    const ushort* dVg = dVtp + (size_t)mz * BSD_ + (size_t)bh * HD_ * S_;
    ushort* outm = outp + (size_t)mz * BSD_;
    __shared__ ushort Ps[64 * 64], Ds[64 * 64], Vs[64 * 64], dVs[64 * 64];  // 32 KB
    int tid = threadIdx.x;
    int wave = tid >> 6, lane = tid & 63;
    int wr = wave >> 1, wc = wave & 1;
    int srow = lane >> 3;
    int skel = ((lane & 7) ^ (lane >> 3)) * 8;
    int frow = lane & 15, fkb = (lane >> 4) * 8;
    int aoff[2][2], boff[2][2];
#pragma unroll
    for (int ks = 0; ks < 2; ks++) {
        int sw = (fkb + ks * 32) ^ ((frow & 7) * 8);
#pragma unroll
        for (int i = 0; i < 2; i++) aoff[ks][i] = (wr * 32 + i * 16 + frow) * 64 + sw;
#pragma unroll
        for (int j = 0; j < 2; j++) boff[ks][j] = (wc * 32 + j * 16 + frow) * 64 + sw;
    }

    float s[2] = {0.f, 0.f};   // rowsum(P.D) for rows q0 + wr*32 + i*16 + frow (partial: this lane's k-slices)
    f32x4 acc[2][2] = {};

    for (int k0 = 0; k0 < S_; k0 += 64) {
#pragma unroll
        for (int cc = 0; cc < 2; cc++) {
            int c = wave * 2 + cc;
            gll16(Pg + (size_t)(q0 + c * 8 + srow) * S_ + k0 + skel, Ps + c * 512);
            gll16(Dg + (size_t)(q0 + c * 8 + srow) * S_ + k0 + skel, Ds + c * 512);
            gll16(Vg + (size_t)(c * 8 + srow) * S_ + k0 + skel, Vs + c * 512);
            gll16(dVg + (size_t)(c * 8 + srow) * S_ + k0 + skel, dVs + c * 512);
        }
        __syncthreads();
#pragma unroll
        for (int ks = 0; ks < 2; ks++) {
            bf16x8 p8[2], pq8[2], v8[2], dv8[2];
#pragma unroll
            for (int i = 0; i < 2; i++) {
                p8[i] = *(const bf16x8*)(Ps + aoff[ks][i]);
                bf16x8 d8 = *(const bf16x8*)(Ds + aoff[ks][i]);
#pragma unroll
                for (int e = 0; e < 8; e++) {
                    float pd = bf2f((ushort)p8[i][e]) * bf2f((ushort)d8[e]);
                    s[i] += pd;
                    pq8[i][e] = (short)f2bf(pd);
                }
            }
#pragma unroll
            for (int j = 0; j < 2; j++) {
                v8[j] = *(const bf16x8*)(Vs + boff[ks][j]);
                dv8[j] = *(const bf16x8*)(dVs + boff[ks][j]);
            }
#pragma unroll
            for (int i = 0; i < 2; i++)
#pragma unroll
                for (int j = 0; j < 2; j++) {
                    acc[i][j] = __builtin_amdgcn_mfma_f32_16x16x32_bf16(pq8[i], v8[j], acc[i][j], 0, 0, 0);
                    acc[i][j] = __builtin_amdgcn_mfma_f32_16x16x32_bf16(p8[i], dv8[j], acc[i][j], 0, 0, 0);
                }
        }
        __syncthreads();
    }

    // complete rowsums: lanes {l, l^16, l^32, l^48} hold the 4 k-slices of row (.. + frow)
#pragma unroll
    for (int i = 0; i < 2; i++) {
        s[i] += __shfl_xor(s[i], 16);
        s[i] += __shfl_xor(s[i], 32);
    }

    // epilogue: out = acc - s[row]*O[row][col]; s redistributed from frow-domain to C-domain rows
#pragma unroll
    for (int i = 0; i < 2; i++) {
        int rbase = q0 + wr * 32 + i * 16 + (lane >> 4) * 4;
#pragma unroll
        for (int r = 0; r < 4; r++) {
            float sc = __shfl(s[i], ((lane >> 4) << 2) + r);  // lane with frow = (lane>>4)*4+r
#pragma unroll
            for (int j = 0; j < 2; j++) {
                int c = hh * HD_ + wc * 32 + j * 16 + (lane & 15);
                float o = bf2f(Ob[(size_t)(b * S_ + rbase + r) * D_ + c]);
                outm[(size_t)(b * S_ + rbase + r) * D_ + c] = f2bf(acc[i][j][r] - sc * o);
            }
        }
    }
}

// ---------------- softmax: bf16 scores -> bf16 probs ----------------
__global__ __launch_bounds__(256) void softmax_rows(const ushort* __restrict__ sc,
                                                    ushort* __restrict__ scb) {
    size_t row = blockIdx.x;
    const ushort* p = sc + row * S_;
    int tid = threadIdx.x;
    ushort2 vu = *(const ushort2*)&p[tid * 2];
    float v0 = bf2f(vu.x), v1 = bf2f(vu.y);
    float mx = block_max(fmaxf(v0, v1));
    float e0 = expf(v0 - mx), e1 = expf(v1 - mx);
    float s = block_sum(e0 + e1);
    float inv = 1.0f / s;
    ushort2 ob; ob.x = f2bf(e0 * inv); ob.y = f2bf(e1 * inv);
    *(ushort2*)&scb[row * S_ + tid * 2] = ob;
}

// ---------------- host ----------------
extern "C" void kernel_launch(void* const* d_in, const int* in_sizes, int n_in,
                              void* d_out, int out_size, void* d_ws, size_t ws_size,
                              hipStream_t stream) {
    const float* x = (const float*)d_in[0];
    const float* xt = (const float*)d_in[1];
    const float* g1 = (const float*)d_in[2];
    const float* b1 = (const float*)d_in[3];
    const float* Wqkv = (const float*)d_in[4];
    const float* Wproj = (const float*)d_in[5];
    const float* bproj = (const float*)d_in[6];
    const float* g2 = (const float*)d_in[7];
    const float* b2 = (const float*)d_in[8];
    const float* W1 = (const float*)d_in[9];
    const float* bf1 = (const float*)d_in[10];
    const float* W2 = (const float*)d_in[11];
    const float* bf2 = (const float*)d_in[12];
    float* out = (float*)d_out;
    float* out_t = out + BSD_;   // [B,M,S,D]

    char* wp = (char*)d_ws;
    auto alloc = [&](size_t bytes) { void* p = wp; wp += (bytes + 255) & ~(size_t)255; return p; };
    ushort* xhat1 = (ushort*)alloc(BSD_ * 2);
    ushort* hb = (ushort*)alloc(BSD_ * 2);
    ushort* obb = (ushort*)alloc(BSD_ * 2);
    float* x2 = (float*)alloc(BSD_ * 4);
    ushort* xhat2 = (ushort*)alloc(BSD_ * 2);
    ushort* h2b = (ushort*)alloc(BSD_ * 2);
    ushort* dx2b = (ushort*)alloc(4 * BSD_ * 2);   // [4*BS][D] bf16
    ushort* qkvb = (ushort*)alloc(BS3D_ * 2);
    ushort* Vt = (ushort*)alloc(BSD_ * 2);
    ushort* dscb2 = (ushort*)alloc(2 * ATT_ * 2);  // [2][BH,S,S]: primal scores / tangent-pair dsc
    ushort* attnb = (ushort*)alloc(ATT_ * 2);      // primal probs bf16
    ushort* gpb = (ushort*)alloc(BSF_ * 2);        // gelu'(u) bf16
    float* rstd1 = (float*)alloc(BS_ * 4);
    float* rstd2 = (float*)alloc(BS_ * 4);
    ushort* WqkvT = (ushort*)alloc((size_t)D_ * 3 * D_ * 2);
    ushort* WprojT = (ushort*)alloc((size_t)D_ * D_ * 2);
    ushort* W1T = (ushort*)alloc((size_t)DFF_ * D_ * 2);
    ushort* W2T = (ushort*)alloc((size_t)D_ * DFF_ * 2);
    // Region A (50.3 MB): phase1 {dqkvb4 + dVt4}, phase2 {da4}
    char* regA = (char*)alloc(4 * BSF_ * 2);
    ushort* dqkvb4 = (ushort*)regA;
    ushort* dVt4 = (ushort*)(regA + 4 * BS3D_ * 2);
    ushort* da4 = (ushort*)regA;
    // Region B (12.6 MB): {ab} -> {dh4} -> {dob4} -> {dh2_4}
    char* regB = (char*)alloc(4 * BSD_ * 2);
    ushort* ab = (ushort*)regB;
    ushort* dh4 = (ushort*)regB;
    ushort* dob4 = (ushort*)regB;
    ushort* dh2_4 = (ushort*)regB;

    // ---- weights -> bf16 transposed [N][K] ----
    transpose_f2b<<<dim3(3 * D_ / 32, D_ / 32), 256, 0, stream>>>(Wqkv, WqkvT, D_, 3 * D_);
    transpose_f2b<<<dim3(D_ / 32, D_ / 32), 256, 0, stream>>>(Wproj, WprojT, D_, D_);
    transpose_f2b<<<dim3(DFF_ / 32, D_ / 32), 256, 0, stream>>>(W1, W1T, D_, DFF_);
    transpose_f2b<<<dim3(D_ / 32, DFF_ / 32), 256, 0, stream>>>(W2, W2T, DFF_, D_);

    // ---- primal ----
    ln_fwd<<<BS_, 256, 0, stream>>>(x, g1, b1, xhat1, hb, rstd1);
    gemm_mfma<64, 128, 0, false, false><<<dim3(3 * D_ / 128, BS_ / 64), 256, 0, stream>>>(
        hb, WqkvT, nullptr, nullptr, nullptr, nullptr, qkvb, nullptr, 3 * D_, D_);
    transpose_v<<<dim3(S_ / 32, HD_ / 32, BH_), 256, 0, stream>>>(qkvb, Vt);
    attn_qk_mfma<false><<<(S_ / 128) * (S_ / 128) * BH_, 256, 0, stream>>>(qkvb, nullptr, dscb2);
    softmax_rows<<<BH_ * S_, 256, 0, stream>>>(dscb2, attnb);
    attn_av_p<<<(S_ / 128) * BH_, 256, 0, stream>>>(attnb, Vt, obb);
    gemm_mfma<64, 64, 0, false, false><<<dim3(D_ / 64, BS_ / 64), 256, 0, stream>>>(
        obb, WprojT, bproj, x, nullptr, x2, nullptr, nullptr, D_, D_);
    ln_fwd<<<BS_, 256, 0, stream>>>(x2, g2, b2, xhat2, h2b, rstd2);
    gemm_mfma<128, 128, 1, false, false><<<dim3(DFF_ / 128, BS_ / 128), 256, 0, stream>>>(
        h2b, W1T, bf1, nullptr, nullptr, nullptr, ab, gpb, DFF_, D_);
    gemm_mfma<64, 64, 0, false, false><<<dim3(D_ / 64, BS_ / 64), 256, 0, stream>>>(
        ab, W2T, bf2, x2, nullptr, out, nullptr, nullptr, D_, DFF_);

    // ---- tangents: batched linear stages (M = 8192), pair-batched fused attention ----
    ln_jvp<<<4 * BS_, 256, 0, stream>>>(xt, nullptr, 0, xhat1, rstd1, g1, dh4);
    gemm_mfma<128, 128, 0, false, false><<<dim3(3 * D_ / 128, 4 * BS_ / 128), 256, 0, stream>>>(
        dh4, WqkvT, nullptr, nullptr, nullptr, nullptr, dqkvb4, nullptr, 3 * D_, D_);
    transpose_v<<<dim3(S_ / 32, HD_ / 32, 4 * BH_), 256, 0, stream>>>(dqkvb4, dVt4);
    for (int p = 0; p < 2; p++) {
        attn_qk_mfma<true><<<2 * (S_ / 128) * (S_ / 128) * BH_, 256, 0, stream>>>(
            qkvb, dqkvb4 + (size_t)p * 2 * BS3D_, dscb2);
        attn_av_tan<<<2 * 8 * BH_, 256, 0, stream>>>(
            attnb, dscb2, Vt, dVt4 + (size_t)p * 2 * BSD_, obb, dob4 + (size_t)p * 2 * BSD_);
    }
    gemm_mfma<128, 64, 0, true, false><<<dim3(D_ / 64, 4 * BS_ / 128), 256, 0, stream>>>(
        dob4, WprojT, nullptr, xt, nullptr, nullptr, dx2b, nullptr, D_, D_);
    ln_jvp<<<4 * BS_, 256, 0, stream>>>(nullptr, dx2b, 1, xhat2, rstd2, g2, dh2_4);
    gemm_mfma<128, 128, 2, false, false><<<dim3(DFF_ / 128, 4 * BS_ / 128), 256, 0, stream>>>(
        dh2_4, W1T, nullptr, nullptr, nullptr, nullptr, da4, gpb, DFF_, D_);
    gemm_mfma<128, 64, 0, false, true><<<dim3(D_ / 64, 4 * BS_ / 128), 256, 0, stream>>>(
        da4, W2T, nullptr, nullptr, dx2b, out_t, nullptr, nullptr, D_, DFF_);
}

// Round 13
// 478.991 us; speedup vs baseline: 1.0703x; 1.0137x over previous
//
#include <hip/hip_runtime.h>
#include <math.h>

constexpr int B_ = 4, S_ = 512, D_ = 768, H_ = 12, M_ = 4, DFF_ = 3072, HD_ = 64;
constexpr float EPS_ = 1e-6f;
constexpr float SCALE_ = 0.125f;  // HD^-0.5
constexpr int BS_ = B_ * S_;
constexpr int BH_ = B_ * H_;
constexpr long long BSD_ = (long long)BS_ * D_;
constexpr long long BS3D_ = (long long)BS_ * 3 * D_;
constexpr long long ATT_ = (long long)BH_ * S_ * S_;
constexpr long long BSF_ = (long long)BS_ * DFF_;

typedef __attribute__((ext_vector_type(8))) short bf16x8;
typedef __attribute__((ext_vector_type(4))) float f32x4;

__device__ __forceinline__ ushort f2bf(float f) {
    uint32_t u = __float_as_uint(f);
    u += 0x7FFF + ((u >> 16) & 1);
    return (ushort)(u >> 16);
}
__device__ __forceinline__ float bf2f(ushort u) {
    return __uint_as_float((uint32_t)u << 16);
}

__device__ __forceinline__ void gll16(const ushort* g, ushort* l) {
    __builtin_amdgcn_global_load_lds((const __attribute__((address_space(1))) void*)g,
                                     (__attribute__((address_space(3))) void*)l, 16, 0, 0);
}

// counted vmcnt wait (literal required in asm)
template <int N> __device__ __forceinline__ void waitcnt_vm() {
    if constexpr (N == 0) asm volatile("s_waitcnt vmcnt(0)" ::: "memory");
    else if constexpr (N == 4) asm volatile("s_waitcnt vmcnt(4)" ::: "memory");
    else if constexpr (N == 6) asm volatile("s_waitcnt vmcnt(6)" ::: "memory");
    else if constexpr (N == 8) asm volatile("s_waitcnt vmcnt(8)" ::: "memory");
    else static_assert(N == 0 || N == 4 || N == 6 || N == 8, "add literal");
}

// XCD-chunked bijective block remap (m204)
__device__ __forceinline__ int xcd_swz(int flat, int nwg) {
    int q = nwg >> 3, r = nwg & 7;
    int x = flat & 7, pos = flat >> 3;
    int base = (x < r) ? x * (q + 1) : r * (q + 1) + (x - r) * q;
    return base + pos;
}

// batched-row (rg in [0,8192)) -> [B,M,S,Nc] offset
__device__ __forceinline__ size_t stroff(int rg, int c, int Nc) {
    int m = rg >> 11;
    int b = (rg >> 9) & (B_ - 1);
    int s = rg & (S_ - 1);
    return ((size_t)((b * M_ + m) * S_ + s)) * Nc + c;
}

// ---------------- block reductions (256 threads = 4 waves) ----------------
__device__ __forceinline__ float block_sum(float v) {
    __shared__ float red[4];
    int tid = threadIdx.x;
#pragma unroll
    for (int off = 32; off > 0; off >>= 1) v += __shfl_down(v, off, 64);
    __syncthreads();
    if ((tid & 63) == 0) red[tid >> 6] = v;
    __syncthreads();
    return red[0] + red[1] + red[2] + red[3];
}

__device__ __forceinline__ float block_max(float v) {
    __shared__ float red[4];
    int tid = threadIdx.x;
#pragma unroll
    for (int off = 32; off > 0; off >>= 1) v = fmaxf(v, __shfl_down(v, off, 64));
    __syncthreads();
    if ((tid & 63) == 0) red[tid >> 6] = v;
    __syncthreads();
    return fmaxf(fmaxf(red[0], red[1]), fmaxf(red[2], red[3]));
}

// ---------------- weight transpose+convert: W[K][N] f32 -> WT[N][K] bf16 ----------------
__global__ __launch_bounds__(256) void transpose_f2b(const float* __restrict__ W,
                                                     ushort* __restrict__ WT,
                                                     int K, int N) {
    __shared__ float t[32][33];
    int n0 = blockIdx.x * 32, k0 = blockIdx.y * 32;
    int tx = threadIdx.x & 31, ty = threadIdx.x >> 5;
#pragma unroll
    for (int i = 0; i < 4; i++)
        t[ty + i * 8][tx] = W[(size_t)(k0 + ty + i * 8) * N + n0 + tx];
    __syncthreads();
#pragma unroll
    for (int i = 0; i < 4; i++)
        WT[(size_t)(n0 + ty + i * 8) * K + k0 + tx] = f2bf(t[tx][ty + i * 8]);
}

// ---------------- V transpose: src[m][B,S,3D] bf16 -> dst[m][bh][HD][S] bf16 ----------------
__global__ __launch_bounds__(256) void transpose_v(const ushort* __restrict__ src0,
                                                   ushort* __restrict__ dst0) {
    int z = blockIdx.z;
    int m = z / BH_, bh = z % BH_;
    const ushort* qkvb = src0 + (size_t)m * BS3D_;
    ushort* Vt = dst0 + (size_t)m * BSD_;
    int b = bh / H_, hh = bh - b * H_;
    int s0 = blockIdx.x * 32, d0 = blockIdx.y * 32;
    __shared__ ushort t[32][33];
    int tx = threadIdx.x & 31, ty = threadIdx.x >> 5;
#pragma unroll
    for (int i = 0; i < 4; i++)
        t[ty + i * 8][tx] = qkvb[(size_t)(b * S_ + s0 + ty + i * 8) * 3 * D_ + 2 * D_ + hh * HD_ + d0 + tx];
    __syncthreads();
#pragma unroll
    for (int i = 0; i < 4; i++)
        Vt[(size_t)bh * HD_ * S_ + (size_t)(d0 + ty + i * 8) * S_ + s0 + tx] = t[tx][ty + i * 8];
}

// ---------------- LayerNorm forward: xhat bf16, h bf16 ----------------
__global__ __launch_bounds__(256) void ln_fwd(const float* __restrict__ x,
                                              const float* __restrict__ g,
                                              const float* __restrict__ bta,
                                              ushort* __restrict__ xhat,
                                              ushort* __restrict__ h,
                                              float* __restrict__ rstd) {
    int row = blockIdx.x;
    const float* xr = x + (size_t)row * D_;
    int tid = threadIdx.x;
    float v[3];
    float s = 0.f;
#pragma unroll
    for (int i = 0; i < 3; i++) { v[i] = xr[tid + i * 256]; s += v[i]; }
    s = block_sum(s);
    float mu = s * (1.0f / D_);
    float vs = 0.f;
#pragma unroll
    for (int i = 0; i < 3; i++) { float c = v[i] - mu; vs += c * c; }
    vs = block_sum(vs);
    float rs = rsqrtf(vs * (1.0f / D_) + EPS_);
#pragma unroll
    for (int i = 0; i < 3; i++) {
        int c = tid + i * 256;
        float xh = (v[i] - mu) * rs;
        xhat[(size_t)row * D_ + c] = f2bf(xh);
        h[(size_t)row * D_ + c] = f2bf(xh * g[c] + bta[c]);
    }
    if (tid == 0) rstd[row] = rs;
}

// ---------------- batched LayerNorm JVP: grid 4*BS_ rows ----------------
__global__ __launch_bounds__(256) void ln_jvp(const float* __restrict__ tf,
                                              const ushort* __restrict__ tb, int mode,
                                              const ushort* __restrict__ xhat,
                                              const float* __restrict__ rstd,
                                              const float* __restrict__ g,
                                              ushort* __restrict__ dh) {
    int rg = blockIdx.x;
    int r = rg & (BS_ - 1);
    size_t pbase = (size_t)r * D_;
    int tid = threadIdx.x;
    float tv[3], xh[3];
    float s1 = 0.f, s2 = 0.f;
    size_t tbase;
    if (mode == 0) {
        int m = rg >> 11;
        int b = r >> 9, s = r & (S_ - 1);
        tbase = ((size_t)((b * M_ + m) * S_ + s)) * D_;
    } else {
        tbase = (size_t)rg * D_;
    }
#pragma unroll
    for (int i = 0; i < 3; i++) {
        int c = tid + i * 256;
        tv[i] = (mode == 0) ? tf[tbase + c] : bf2f(tb[tbase + c]);
        xh[i] = bf2f(xhat[pbase + c]);
        s1 += tv[i];
        s2 += tv[i] * xh[i];
    }
    s1 = block_sum(s1);
    s2 = block_sum(s2);
    float mt = s1 * (1.0f / D_);
    float mx = s2 * (1.0f / D_);
    float rs = rstd[r];
#pragma unroll
    for (int i = 0; i < 3; i++) {
        int c = tid + i * 256;
        dh[(size_t)rg * D_ + c] = f2bf(g[c] * rs * (tv[i] - mt - xh[i] * mx));
    }
}

// ---------------- bf16 MFMA GEMM <BM,BN>, BK=64, 2-deep dbuf pipeline (T3/T4) ----------------
// Work mapping: XCD-chunked (m204) + 8-row-panel bands, col-major within band:
// concurrent set per XCD = 8 A-panels + 8 B-panels < 4 MB L2 (anti-thrash).
// Requires gridDim.y % 8 == 0 (all launches satisfy).
template <int BM, int BN, int EPI, bool RS, bool OS>
__global__ __launch_bounds__(256) void gemm_mfma(const ushort* __restrict__ A,
                                                 const ushort* __restrict__ BT,
                                                 const float* __restrict__ bias,
                                                 const float* __restrict__ resf,
                                                 const ushort* __restrict__ resb,
                                                 float* __restrict__ Cf,
                                                 ushort* __restrict__ Cb,
                                                 ushort* __restrict__ aux,
                                                 int Nc, int Kd) {
    constexpr int FI = BM / 32, FJ = BN / 32;
    constexpr int LA = BM / 32, LB = BN / 32, L = LA + LB;
    __shared__ ushort As[2][BM * 64];
    __shared__ ushort Bs[2][BN * 64];
    int tid = threadIdx.x;
    int wave = tid >> 6, lane = tid & 63;
    int wr = wave >> 1, wc = wave & 1;
    int gx = gridDim.x, nwg = gx * gridDim.y;
    int work = xcd_swz(blockIdx.x + blockIdx.y * gx, nwg);
    // band remap: 8 row-panels per band, col-major inside the band
    int band = work / (8 * gx);
    int wi = work - band * (8 * gx);
    int row0 = (band * 8 + (wi & 7)) * BM;
    int col0 = (wi >> 3) * BN;

    int srow = lane >> 3;
    int skel = ((lane & 7) ^ (lane >> 3)) * 8;
    const ushort* Ag0 = A + (size_t)(row0 + srow) * Kd + skel;
    const ushort* Bg0 = BT + (size_t)(col0 + srow) * Kd + skel;

    auto stage = [&](int bufi, int k0) {
#pragma unroll
        for (int cc = 0; cc < LA; cc++) {
            int c = wave * LA + cc;
            gll16(Ag0 + (size_t)(c * 8) * Kd + k0, As[bufi] + c * 512);
        }
#pragma unroll
        for (int cc = 0; cc < LB; cc++) {
            int c = wave * LB + cc;
            gll16(Bg0 + (size_t)(c * 8) * Kd + k0, Bs[bufi] + c * 512);
        }
    };

    int frow = lane & 15, fkb = (lane >> 4) * 8;
    int aoff[2][FI], boff[2][FJ];
#pragma unroll
    for (int ks = 0; ks < 2; ks++) {
        int sw = (fkb + ks * 32) ^ ((frow & 7) * 8);
#pragma unroll
        for (int i = 0; i < FI; i++) aoff[ks][i] = (wr * (BM / 2) + i * 16 + frow) * 64 + sw;
#pragma unroll
        for (int j = 0; j < FJ; j++) boff[ks][j] = (wc * (BN / 2) + j * 16 + frow) * 64 + sw;
    }

    f32x4 acc[FI][FJ] = {};

    int nt = Kd >> 6;
    stage(0, 0);
    if (nt > 1) { stage(1, 64); waitcnt_vm<L>(); }
    else        { waitcnt_vm<0>(); }
    __builtin_amdgcn_s_barrier();
    __builtin_amdgcn_sched_barrier(0);

    int cur = 0;
    for (int t = 0; t < nt; t++) {
        bf16x8 af[2][FI], bfv[2][FJ];
        const ushort* Ab = As[cur];
        const ushort* Bb = Bs[cur];
#pragma unroll
        for (int ks = 0; ks < 2; ks++) {
#pragma unroll
            for (int i = 0; i < FI; i++) af[ks][i] = *(const bf16x8*)(Ab + aoff[ks][i]);
#pragma unroll
            for (int j = 0; j < FJ; j++) bfv[ks][j] = *(const bf16x8*)(Bb + boff[ks][j]);
        }
#pragma unroll
        for (int ks = 0; ks < 2; ks++)
#pragma unroll
            for (int i = 0; i < FI; i++)
#pragma unroll
                for (int j = 0; j < FJ; j++)
                    acc[i][j] = __builtin_amdgcn_mfma_f32_16x16x32_bf16(af[ks][i], bfv[ks][j], acc[i][j], 0, 0, 0);
        __builtin_amdgcn_sched_barrier(0);
        __builtin_amdgcn_s_barrier();
        if (t + 2 < nt) {
            stage(cur, (t + 2) << 6);
            waitcnt_vm<L>();
        } else if (t + 1 < nt) {
            waitcnt_vm<0>();
        }
        __builtin_amdgcn_s_barrier();
        __builtin_amdgcn_sched_barrier(0);
        cur ^= 1;
    }

    // C/D layout: col = lane&15, row = (lane>>4)*4 + reg
#pragma unroll
    for (int i = 0; i < FI; i++) {
        int rbase = row0 + wr * (BM / 2) + i * 16 + (lane >> 4) * 4;
#pragma unroll
        for (int j = 0; j < FJ; j++) {
            int c = col0 + wc * (BN / 2) + j * 16 + (lane & 15);
#pragma unroll
            for (int r = 0; r < 4; r++) {
                int rg = rbase + r;
                size_t off = (size_t)rg * Nc + c;
                float v = acc[i][j][r];
                if (EPI == 0) {
                    if (bias) v += bias[c];
                    if (resf) v += resf[RS ? stroff(rg, c, Nc) : off];
                    if (resb) v += bf2f(resb[off]);
                    if (Cf) { if (OS) Cf[stroff(rg, c, Nc)] = v; else Cf[off] = v; }
                    if (Cb) Cb[off] = f2bf(v);
                } else if (EPI == 1) {
                    v += bias[c];
                    float cdf = 0.5f * (1.0f + erff(v * 0.70710678118654752f));
                    Cb[off] = f2bf(v * cdf);
                    aux[off] = f2bf(cdf + v * 0.39894228040143267f * expf(-0.5f * v * v));
                } else {
                    Cb[off] = f2bf(v * bf2f(aux[(size_t)(rg & (BS_ - 1)) * Nc + c]));
                }
            }
        }
    }
}

// ---------------- MFMA QK^T: single-shot BK=64 (K=HD), XOR-swizzled ----------------
template <bool TAN>
__global__ __launch_bounds__(256) void attn_qk_mfma(const ushort* __restrict__ qkvb,
                                                    const ushort* __restrict__ dqkvp,
                                                    ushort* __restrict__ sc) {
    int work = xcd_swz(blockIdx.x, gridDim.x);
    constexpr int NT = S_ / 128;  // 4
    int mz = work / (BH_ * NT * NT);
    int rem = work % (BH_ * NT * NT);
    int bh = rem / (NT * NT);
    int r2 = rem % (NT * NT);
    int q0 = (r2 / NT) * 128, kc0 = (r2 % NT) * 128;
    int b = bh / H_, hh = bh - b * H_;
    const size_t qoff = (size_t)b * S_ * 3 * D_ + hh * HD_;
    const int ld = 3 * D_;
    const ushort* dqkv = TAN ? dqkvp + (size_t)mz * BS3D_ : nullptr;
    __shared__ ushort As[128 * 64];
    __shared__ ushort Bs[128 * 64];
    __shared__ ushort dAs[TAN ? 128 * 64 : 1];
    __shared__ ushort dBs[TAN ? 128 * 64 : 1];
    int tid = threadIdx.x;
    int wave = tid >> 6, lane = tid & 63;
    int wr = wave >> 1, wc = wave & 1;

    int srow = lane >> 3;
    int skel = ((lane & 7) ^ (lane >> 3)) * 8;
    const ushort* Ag0 = qkvb + qoff + (size_t)(q0 + srow) * ld + skel;
    const ushort* Bg0 = qkvb + qoff + D_ + (size_t)(kc0 + srow) * ld + skel;

#pragma unroll
    for (int cc = 0; cc < 4; cc++) {
        int c = wave * 4 + cc;
        gll16(Ag0 + (size_t)(c * 8) * ld, As + c * 512);
        gll16(Bg0 + (size_t)(c * 8) * ld, Bs + c * 512);
        if (TAN) {
            gll16(dqkv + qoff + (size_t)(q0 + c * 8 + srow) * ld + skel, dAs + c * 512);
            gll16(dqkv + qoff + D_ + (size_t)(kc0 + c * 8 + srow) * ld + skel, dBs + c * 512);
        }
    }
    __syncthreads();

    int frow = lane & 15, fkb = (lane >> 4) * 8;
    f32x4 acc[4][4] = {};
#pragma unroll
    for (int ks = 0; ks < 2; ks++) {
        int sw = (fkb + ks * 32) ^ ((frow & 7) * 8);
        bf16x8 af[4], bfv[4];
#pragma unroll
        for (int i = 0; i < 4; i++) af[i] = *(const bf16x8*)(As + (wr * 64 + i * 16 + frow) * 64 + sw);
#pragma unroll
        for (int j = 0; j < 4; j++) bfv[j] = *(const bf16x8*)(Bs + (wc * 64 + j * 16 + frow) * 64 + sw);
        if (!TAN) {
#pragma unroll
            for (int i = 0; i < 4; i++)
#pragma unroll
                for (int j = 0; j < 4; j++)
                    acc[i][j] = __builtin_amdgcn_mfma_f32_16x16x32_bf16(af[i], bfv[j], acc[i][j], 0, 0, 0);
        } else {
            bf16x8 daf[4], dbf[4];
#pragma unroll
            for (int i = 0; i < 4; i++) daf[i] = *(const bf16x8*)(dAs + (wr * 64 + i * 16 + frow) * 64 + sw);
#pragma unroll
            for (int j = 0; j < 4; j++) dbf[j] = *(const bf16x8*)(dBs + (wc * 64 + j * 16 + frow) * 64 + sw);
#pragma unroll
            for (int i = 0; i < 4; i++)
#pragma unroll
                for (int j = 0; j < 4; j++) {
                    acc[i][j] = __builtin_amdgcn_mfma_f32_16x16x32_bf16(daf[i], bfv[j], acc[i][j], 0, 0, 0);
                    acc[i][j] = __builtin_amdgcn_mfma_f32_16x16x32_bf16(af[i], dbf[j], acc[i][j], 0, 0, 0);
                }
        }
    }

    ushort* scm = sc + (size_t)mz * ATT_;
#pragma unroll
    for (int i = 0; i < 4; i++) {
        int rbase = q0 + wr * 64 + i * 16 + (lane >> 4) * 4;
#pragma unroll
        for (int j = 0; j < 4; j++) {
            int c = kc0 + wc * 64 + j * 16 + (lane & 15);
#pragma unroll
            for (int r = 0; r < 4; r++)
                scm[((size_t)bh * S_ + rbase + r) * S_ + c] = f2bf(acc[i][j][r] * SCALE_);
        }
    }
}

// ---------------- primal P@V: BK=64, XOR-swizzled ----------------
__global__ __launch_bounds__(256) void attn_av_p(const ushort* __restrict__ Pb,
                                                 const ushort* __restrict__ Vt,
                                                 ushort* __restrict__ outp) {
    int work = xcd_swz(blockIdx.x, gridDim.x);
    constexpr int NT = S_ / 128;  // 4
    int bh = work / NT;
    int q0 = (work % NT) * 128;
    int b = bh / H_, hh = bh - b * H_;
    const ushort* Pg = Pb + (size_t)bh * S_ * S_;
    const ushort* Vg = Vt + (size_t)bh * HD_ * S_;
    __shared__ ushort As[128 * 64];
    __shared__ ushort Bs[64 * 64];
    int tid = threadIdx.x;
    int wave = tid >> 6, lane = tid & 63;
    int wr = wave >> 1, wc = wave & 1;
    int srow = lane >> 3;
    int skel = ((lane & 7) ^ (lane >> 3)) * 8;
    int frow = lane & 15, fkb = (lane >> 4) * 8;

    f32x4 acc[4][2] = {};
    for (int k0 = 0; k0 < S_; k0 += 64) {
#pragma unroll
        for (int cc = 0; cc < 4; cc++) {
            int c = wave * 4 + cc;
            gll16(Pg + (size_t)(q0 + c * 8 + srow) * S_ + k0 + skel, As + c * 512);
        }
#pragma unroll
        for (int cc = 0; cc < 2; cc++) {
            int c = wave * 2 + cc;
            gll16(Vg + (size_t)(c * 8 + srow) * S_ + k0 + skel, Bs + c * 512);
        }
        __syncthreads();
#pragma unroll
        for (int ks = 0; ks < 2; ks++) {
            int sw = (fkb + ks * 32) ^ ((frow & 7) * 8);
            bf16x8 af[4], bfv[2];
#pragma unroll
            for (int i = 0; i < 4; i++) af[i] = *(const bf16x8*)(As + (wr * 64 + i * 16 + frow) * 64 + sw);
#pragma unroll
            for (int j = 0; j < 2; j++) bfv[j] = *(const bf16x8*)(Bs + (wc * 32 + j * 16 + frow) * 64 + sw);
#pragma unroll
            for (int i = 0; i < 4; i++)
#pragma unroll
                for (int j = 0; j < 2; j++)
                    acc[i][j] = __builtin_amdgcn_mfma_f32_16x16x32_bf16(af[i], bfv[j], acc[i][j], 0, 0, 0);
        }
        __syncthreads();
    }

#pragma unroll
    for (int i = 0; i < 4; i++) {
        int rbase = q0 + wr * 64 + i * 16 + (lane >> 4) * 4;
#pragma unroll
        for (int j = 0; j < 2; j++) {
            int c = hh * HD_ + wc * 32 + j * 16 + (lane & 15);
#pragma unroll
            for (int r = 0; r < 4; r++)
                outp[(size_t)(b * S_ + rbase + r) * D_ + c] = f2bf(acc[i][j][r]);
        }
    }
}

// ---------------- FUSED tangent P@V (single pass): dO = (P.D)@V + P@dV - s*O ----------------
__global__ __launch_bounds__(256) void attn_av_tan(const ushort* __restrict__ Pb,
                                                   const ushort* __restrict__ dscp,
                                                   const ushort* __restrict__ Vt,
                                                   const ushort* __restrict__ dVtp,
                                                   const ushort* __restrict__ Ob,
                                                   ushort* __restrict__ outp) {
    int work = xcd_swz(blockIdx.x, gridDim.x);
    int mz = work / (BH_ * 8);
    int rem = work % (BH_ * 8);
    int bh = rem / 8;
    int q0 = (rem % 8) * 64;
    int b = bh / H_, hh = bh - b * H_;
    const ushort* Pg = Pb + (size_t)bh * S_ * S_;
    const ushort* Dg = dscp + (size_t)mz * ATT_ + (size_t)bh * S_ * S_;
    const ushort* Vg = Vt + (size_t)bh * HD_ * S_;
    const ushort* dVg = dVtp + (size_t)mz * BSD_ + (size_t)bh * HD_ * S_;
    ushort* outm = outp + (size_t)mz * BSD_;
    __shared__ ushort Ps[64 * 64], Ds[64 * 64], Vs[64 * 64], dVs[64 * 64];
    int tid = threadIdx.x;
    int wave = tid >> 6, lane = tid & 63;
    int wr = wave >> 1, wc = wave & 1;
    int srow = lane >> 3;
    int skel = ((lane & 7) ^ (lane >> 3)) * 8;
    int frow = lane & 15, fkb = (lane >> 4) * 8;
    int aoff[2][2], boff[2][2];
#pragma unroll
    for (int ks = 0; ks < 2; ks++) {
        int sw = (fkb + ks * 32) ^ ((frow & 7) * 8);
#pragma unroll
        for (int i = 0; i < 2; i++) aoff[ks][i] = (wr * 32 + i * 16 + frow) * 64 + sw;
#pragma unroll
        for (int j = 0; j < 2; j++) boff[ks][j] = (wc * 32 + j * 16 + frow) * 64 + sw;
    }

    float s[2] = {0.f, 0.f};
    f32x4 acc[2][2] = {};

    for (int k0 = 0; k0 < S_; k0 += 64) {
#pragma unroll
        for (int cc = 0; cc < 2; cc++) {
            int c = wave * 2 + cc;
            gll16(Pg + (size_t)(q0 + c * 8 + srow) * S_ + k0 + skel, Ps + c * 512);
            gll16(Dg + (size_t)(q0 + c * 8 + srow) * S_ + k0 + skel, Ds + c * 512);
            gll16(Vg + (size_t)(c * 8 + srow) * S_ + k0 + skel, Vs + c * 512);
            gll16(dVg + (size_t)(c * 8 + srow) * S_ + k0 + skel, dVs + c * 512);
        }
        __syncthreads();
#pragma unroll
        for (int ks = 0; ks < 2; ks++) {
            bf16x8 p8[2], pq8[2], v8[2], dv8[2];
#pragma unroll
            for (int i = 0; i < 2; i++) {
                p8[i] = *(const bf16x8*)(Ps + aoff[ks][i]);
                bf16x8 d8 = *(const bf16x8*)(Ds + aoff[ks][i]);
#pragma unroll
                for (int e = 0; e < 8; e++) {
                    float pd = bf2f((ushort)p8[i][e]) * bf2f((ushort)d8[e]);
                    s[i] += pd;
                    pq8[i][e] = (short)f2bf(pd);
                }
            }
#pragma unroll
            for (int j = 0; j < 2; j++) {
                v8[j] = *(const bf16x8*)(Vs + boff[ks][j]);
                dv8[j] = *(const bf16x8*)(dVs + boff[ks][j]);
            }
#pragma unroll
            for (int i = 0; i < 2; i++)
#pragma unroll
                for (int j = 0; j < 2; j++) {
                    acc[i][j] = __builtin_amdgcn_mfma_f32_16x16x32_bf16(pq8[i], v8[j], acc[i][j], 0, 0, 0);
                    acc[i][j] = __builtin_amdgcn_mfma_f32_16x16x32_bf16(p8[i], dv8[j], acc[i][j], 0, 0, 0);
                }
        }
        __syncthreads();
    }

#pragma unroll
    for (int i = 0; i < 2; i++) {
        s[i] += __shfl_xor(s[i], 16);
        s[i] += __shfl_xor(s[i], 32);
    }

#pragma unroll
    for (int i = 0; i < 2; i++) {
        int rbase = q0 + wr * 32 + i * 16 + (lane >> 4) * 4;
#pragma unroll
        for (int r = 0; r < 4; r++) {
            float sc = __shfl(s[i], ((lane >> 4) << 2) + r);
#pragma unroll
            for (int j = 0; j < 2; j++) {
                int c = hh * HD_ + wc * 32 + j * 16 + (lane & 15);
                float o = bf2f(Ob[(size_t)(b * S_ + rbase + r) * D_ + c]);
                outm[(size_t)(b * S_ + rbase + r) * D_ + c] = f2bf(acc[i][j][r] - sc * o);
            }
        }
    }
}

// ---------------- softmax: bf16 scores -> bf16 probs ----------------
__global__ __launch_bounds__(256) void softmax_rows(const ushort* __restrict__ sc,
                                                    ushort* __restrict__ scb) {
    size_t row = blockIdx.x;
    const ushort* p = sc + row * S_;
    int tid = threadIdx.x;
    ushort2 vu = *(const ushort2*)&p[tid * 2];
    float v0 = bf2f(vu.x), v1 = bf2f(vu.y);
    float mx = block_max(fmaxf(v0, v1));
    float e0 = expf(v0 - mx), e1 = expf(v1 - mx);
    float s = block_sum(e0 + e1);
    float inv = 1.0f / s;
    ushort2 ob; ob.x = f2bf(e0 * inv); ob.y = f2bf(e1 * inv);
    *(ushort2*)&scb[row * S_ + tid * 2] = ob;
}

// ---------------- host ----------------
extern "C" void kernel_launch(void* const* d_in, const int* in_sizes, int n_in,
                              void* d_out, int out_size, void* d_ws, size_t ws_size,
                              hipStream_t stream) {
    const float* x = (const float*)d_in[0];
    const float* xt = (const float*)d_in[1];
    const float* g1 = (const float*)d_in[2];
    const float* b1 = (const float*)d_in[3];
    const float* Wqkv = (const float*)d_in[4];
    const float* Wproj = (const float*)d_in[5];
    const float* bproj = (const float*)d_in[6];
    const float* g2 = (const float*)d_in[7];
    const float* b2 = (const float*)d_in[8];
    const float* W1 = (const float*)d_in[9];
    const float* bf1 = (const float*)d_in[10];
    const float* W2 = (const float*)d_in[11];
    const float* bf2 = (const float*)d_in[12];
    float* out = (float*)d_out;
    float* out_t = out + BSD_;   // [B,M,S,D]

    char* wp = (char*)d_ws;
    auto alloc = [&](size_t bytes) { void* p = wp; wp += (bytes + 255) & ~(size_t)255; return p; };
    ushort* xhat1 = (ushort*)alloc(BSD_ * 2);
    ushort* hb = (ushort*)alloc(BSD_ * 2);
    ushort* obb = (ushort*)alloc(BSD_ * 2);
    float* x2 = (float*)alloc(BSD_ * 4);
    ushort* xhat2 = (ushort*)alloc(BSD_ * 2);
    ushort* h2b = (ushort*)alloc(BSD_ * 2);
    ushort* dx2b = (ushort*)alloc(4 * BSD_ * 2);   // [4*BS][D] bf16
    ushort* qkvb = (ushort*)alloc(BS3D_ * 2);
    ushort* Vt = (ushort*)alloc(BSD_ * 2);
    ushort* dscb2 = (ushort*)alloc(2 * ATT_ * 2);  // [2][BH,S,S]
    ushort* attnb = (ushort*)alloc(ATT_ * 2);      // primal probs bf16
    ushort* gpb = (ushort*)alloc(BSF_ * 2);        // gelu'(u) bf16
    float* rstd1 = (float*)alloc(BS_ * 4);
    float* rstd2 = (float*)alloc(BS_ * 4);
    ushort* WqkvT = (ushort*)alloc((size_t)D_ * 3 * D_ * 2);
    ushort* WprojT = (ushort*)alloc((size_t)D_ * D_ * 2);
    ushort* W1T = (ushort*)alloc((size_t)DFF_ * D_ * 2);
    ushort* W2T = (ushort*)alloc((size_t)D_ * DFF_ * 2);
    // Region A (50.3 MB): phase1 {dqkvb4 + dVt4}, phase2 {da4}
    char* regA = (char*)alloc(4 * BSF_ * 2);
    ushort* dqkvb4 = (ushort*)regA;
    ushort* dVt4 = (ushort*)(regA + 4 * BS3D_ * 2);
    ushort* da4 = (ushort*)regA;
    // Region B (12.6 MB): {ab} -> {dh4} -> {dob4} -> {dh2_4}
    char* regB = (char*)alloc(4 * BSD_ * 2);
    ushort* ab = (ushort*)regB;
    ushort* dh4 = (ushort*)regB;
    ushort* dob4 = (ushort*)regB;
    ushort* dh2_4 = (ushort*)regB;

    // ---- weights -> bf16 transposed [N][K] ----
    transpose_f2b<<<dim3(3 * D_ / 32, D_ / 32), 256, 0, stream>>>(Wqkv, WqkvT, D_, 3 * D_);
    transpose_f2b<<<dim3(D_ / 32, D_ / 32), 256, 0, stream>>>(Wproj, WprojT, D_, D_);
    transpose_f2b<<<dim3(DFF_ / 32, D_ / 32), 256, 0, stream>>>(W1, W1T, D_, DFF_);
    transpose_f2b<<<dim3(D_ / 32, DFF_ / 32), 256, 0, stream>>>(W2, W2T, DFF_, D_);

    // ---- primal ----
    ln_fwd<<<BS_, 256, 0, stream>>>(x, g1, b1, xhat1, hb, rstd1);
    gemm_mfma<64, 128, 0, false, false><<<dim3(3 * D_ / 128, BS_ / 64), 256, 0, stream>>>(
        hb, WqkvT, nullptr, nullptr, nullptr, nullptr, qkvb, nullptr, 3 * D_, D_);
    transpose_v<<<dim3(S_ / 32, HD_ / 32, BH_), 256, 0, stream>>>(qkvb, Vt);
    attn_qk_mfma<false><<<(S_ / 128) * (S_ / 128) * BH_, 256, 0, stream>>>(qkvb, nullptr, dscb2);
    softmax_rows<<<BH_ * S_, 256, 0, stream>>>(dscb2, attnb);
    attn_av_p<<<(S_ / 128) * BH_, 256, 0, stream>>>(attnb, Vt, obb);
    gemm_mfma<64, 64, 0, false, false><<<dim3(D_ / 64, BS_ / 64), 256, 0, stream>>>(
        obb, WprojT, bproj, x, nullptr, x2, nullptr, nullptr, D_, D_);
    ln_fwd<<<BS_, 256, 0, stream>>>(x2, g2, b2, xhat2, h2b, rstd2);
    gemm_mfma<128, 128, 1, false, false><<<dim3(DFF_ / 128, BS_ / 128), 256, 0, stream>>>(
        h2b, W1T, bf1, nullptr, nullptr, nullptr, ab, gpb, DFF_, D_);
    gemm_mfma<64, 64, 0, false, false><<<dim3(D_ / 64, BS_ / 64), 256, 0, stream>>>(
        ab, W2T, bf2, x2, nullptr, out, nullptr, nullptr, D_, DFF_);

    // ---- tangents: batched linear stages (M = 8192), pair-batched fused attention ----
    ln_jvp<<<4 * BS_, 256, 0, stream>>>(xt, nullptr, 0, xhat1, rstd1, g1, dh4);
    gemm_mfma<128, 128, 0, false, false><<<dim3(3 * D_ / 128, 4 * BS_ / 128), 256, 0, stream>>>(
        dh4, WqkvT, nullptr, nullptr, nullptr, nullptr, dqkvb4, nullptr, 3 * D_, D_);
    transpose_v<<<dim3(S_ / 32, HD_ / 32, 4 * BH_), 256, 0, stream>>>(dqkvb4, dVt4);
    for (int p = 0; p < 2; p++) {
        attn_qk_mfma<true><<<2 * (S_ / 128) * (S_ / 128) * BH_, 256, 0, stream>>>(
            qkvb, dqkvb4 + (size_t)p * 2 * BS3D_, dscb2);
        attn_av_tan<<<2 * 8 * BH_, 256, 0, stream>>>(
            attnb, dscb2, Vt, dVt4 + (size_t)p * 2 * BSD_, obb, dob4 + (size_t)p * 2 * BSD_);
    }
    gemm_mfma<128, 64, 0, true, false><<<dim3(D_ / 64, 4 * BS_ / 128), 256, 0, stream>>>(
        dob4, WprojT, nullptr, xt, nullptr, nullptr, dx2b, nullptr, D_, D_);
    ln_jvp<<<4 * BS_, 256, 0, stream>>>(nullptr, dx2b, 1, xhat2, rstd2, g2, dh2_4);
    gemm_mfma<128, 128, 2, false, false><<<dim3(DFF_ / 128, 4 * BS_ / 128), 256, 0, stream>>>(
        dh2_4, W1T, nullptr, nullptr, nullptr, nullptr, da4, gpb, DFF_, D_);
    gemm_mfma<128, 64, 0, false, true><<<dim3(D_ / 64, 4 * BS_ / 128), 256, 0, stream>>>(
        da4, W2T, nullptr, nullptr, dx2b, out_t, nullptr, nullptr, D_, DFF_);
}

// Round 14
// 452.103 us; speedup vs baseline: 1.1339x; 1.0595x over previous
//
#include <hip/hip_runtime.h>
#include <math.h>

constexpr int B_ = 4, S_ = 512, D_ = 768, H_ = 12, M_ = 4, DFF_ = 3072, HD_ = 64;
constexpr float EPS_ = 1e-6f;
constexpr float SCALE_ = 0.125f;  // HD^-0.5
constexpr int BS_ = B_ * S_;
constexpr int BH_ = B_ * H_;
constexpr long long BSD_ = (long long)BS_ * D_;
constexpr long long BS3D_ = (long long)BS_ * 3 * D_;
constexpr long long ATT_ = (long long)BH_ * S_ * S_;
constexpr long long BSF_ = (long long)BS_ * DFF_;

typedef __attribute__((ext_vector_type(8))) short bf16x8;
typedef __attribute__((ext_vector_type(4))) float f32x4;

__device__ __forceinline__ ushort f2bf(float f) {
    uint32_t u = __float_as_uint(f);
    u += 0x7FFF + ((u >> 16) & 1);
    return (ushort)(u >> 16);
}
__device__ __forceinline__ float bf2f(ushort u) {
    return __uint_as_float((uint32_t)u << 16);
}

__device__ __forceinline__ void gll16(const ushort* g, ushort* l) {
    __builtin_amdgcn_global_load_lds((const __attribute__((address_space(1))) void*)g,
                                     (__attribute__((address_space(3))) void*)l, 16, 0, 0);
}

// counted vmcnt wait (literal required in asm)
template <int N> __device__ __forceinline__ void waitcnt_vm() {
    if constexpr (N == 0) asm volatile("s_waitcnt vmcnt(0)" ::: "memory");
    else if constexpr (N == 4) asm volatile("s_waitcnt vmcnt(4)" ::: "memory");
    else if constexpr (N == 6) asm volatile("s_waitcnt vmcnt(6)" ::: "memory");
    else if constexpr (N == 8) asm volatile("s_waitcnt vmcnt(8)" ::: "memory");
    else static_assert(N == 0 || N == 4 || N == 6 || N == 8, "add literal");
}

__device__ __forceinline__ void waitcnt_lgkm0() {
    asm volatile("s_waitcnt lgkmcnt(0)" ::: "memory");
    __builtin_amdgcn_sched_barrier(0);  // rule 18: fence MFMA/reg-op hoisting
}

// XCD-chunked bijective block remap (m204)
__device__ __forceinline__ int xcd_swz(int flat, int nwg) {
    int q = nwg >> 3, r = nwg & 7;
    int x = flat & 7, pos = flat >> 3;
    int base = (x < r) ? x * (q + 1) : r * (q + 1) + (x - r) * q;
    return base + pos;
}

// batched-row (rg in [0,8192)) -> [B,M,S,Nc] offset
__device__ __forceinline__ size_t stroff(int rg, int c, int Nc) {
    int m = rg >> 11;
    int b = (rg >> 9) & (B_ - 1);
    int s = rg & (S_ - 1);
    return ((size_t)((b * M_ + m) * S_ + s)) * Nc + c;
}

// ---------------- block reductions (256 threads = 4 waves) ----------------
__device__ __forceinline__ float block_sum(float v) {
    __shared__ float red[4];
    int tid = threadIdx.x;
#pragma unroll
    for (int off = 32; off > 0; off >>= 1) v += __shfl_down(v, off, 64);
    __syncthreads();
    if ((tid & 63) == 0) red[tid >> 6] = v;
    __syncthreads();
    return red[0] + red[1] + red[2] + red[3];
}

__device__ __forceinline__ float block_max(float v) {
    __shared__ float red[4];
    int tid = threadIdx.x;
#pragma unroll
    for (int off = 32; off > 0; off >>= 1) v = fmaxf(v, __shfl_down(v, off, 64));
    __syncthreads();
    if ((tid & 63) == 0) red[tid >> 6] = v;
    __syncthreads();
    return fmaxf(fmaxf(red[0], red[1]), fmaxf(red[2], red[3]));
}

// ---------------- weight transpose+convert: W[K][N] f32 -> WT[N][K] bf16 ----------------
__global__ __launch_bounds__(256) void transpose_f2b(const float* __restrict__ W,
                                                     ushort* __restrict__ WT,
                                                     int K, int N) {
    __shared__ float t[32][33];
    int n0 = blockIdx.x * 32, k0 = blockIdx.y * 32;
    int tx = threadIdx.x & 31, ty = threadIdx.x >> 5;
#pragma unroll
    for (int i = 0; i < 4; i++)
        t[ty + i * 8][tx] = W[(size_t)(k0 + ty + i * 8) * N + n0 + tx];
    __syncthreads();
#pragma unroll
    for (int i = 0; i < 4; i++)
        WT[(size_t)(n0 + ty + i * 8) * K + k0 + tx] = f2bf(t[tx][ty + i * 8]);
}

// ---------------- V transpose: src[m][B,S,3D] bf16 -> dst[m][bh][HD][S] bf16 ----------------
__global__ __launch_bounds__(256) void transpose_v(const ushort* __restrict__ src0,
                                                   ushort* __restrict__ dst0) {
    int z = blockIdx.z;
    int m = z / BH_, bh = z % BH_;
    const ushort* qkvb = src0 + (size_t)m * BS3D_;
    ushort* Vt = dst0 + (size_t)m * BSD_;
    int b = bh / H_, hh = bh - b * H_;
    int s0 = blockIdx.x * 32, d0 = blockIdx.y * 32;
    __shared__ ushort t[32][33];
    int tx = threadIdx.x & 31, ty = threadIdx.x >> 5;
#pragma unroll
    for (int i = 0; i < 4; i++)
        t[ty + i * 8][tx] = qkvb[(size_t)(b * S_ + s0 + ty + i * 8) * 3 * D_ + 2 * D_ + hh * HD_ + d0 + tx];
    __syncthreads();
#pragma unroll
    for (int i = 0; i < 4; i++)
        Vt[(size_t)bh * HD_ * S_ + (size_t)(d0 + ty + i * 8) * S_ + s0 + tx] = t[tx][ty + i * 8];
}

// ---------------- LayerNorm forward: xhat bf16, h bf16 ----------------
__global__ __launch_bounds__(256) void ln_fwd(const float* __restrict__ x,
                                              const float* __restrict__ g,
                                              const float* __restrict__ bta,
                                              ushort* __restrict__ xhat,
                                              ushort* __restrict__ h,
                                              float* __restrict__ rstd) {
    int row = blockIdx.x;
    const float* xr = x + (size_t)row * D_;
    int tid = threadIdx.x;
    float v[3];
    float s = 0.f;
#pragma unroll
    for (int i = 0; i < 3; i++) { v[i] = xr[tid + i * 256]; s += v[i]; }
    s = block_sum(s);
    float mu = s * (1.0f / D_);
    float vs = 0.f;
#pragma unroll
    for (int i = 0; i < 3; i++) { float c = v[i] - mu; vs += c * c; }
    vs = block_sum(vs);
    float rs = rsqrtf(vs * (1.0f / D_) + EPS_);
#pragma unroll
    for (int i = 0; i < 3; i++) {
        int c = tid + i * 256;
        float xh = (v[i] - mu) * rs;
        xhat[(size_t)row * D_ + c] = f2bf(xh);
        h[(size_t)row * D_ + c] = f2bf(xh * g[c] + bta[c]);
    }
    if (tid == 0) rstd[row] = rs;
}

// ---------------- batched LayerNorm JVP: grid 4*BS_ rows ----------------
__global__ __launch_bounds__(256) void ln_jvp(const float* __restrict__ tf,
                                              const ushort* __restrict__ tb, int mode,
                                              const ushort* __restrict__ xhat,
                                              const float* __restrict__ rstd,
                                              const float* __restrict__ g,
                                              ushort* __restrict__ dh) {
    int rg = blockIdx.x;
    int r = rg & (BS_ - 1);
    size_t pbase = (size_t)r * D_;
    int tid = threadIdx.x;
    float tv[3], xh[3];
    float s1 = 0.f, s2 = 0.f;
    size_t tbase;
    if (mode == 0) {
        int m = rg >> 11;
        int b = r >> 9, s = r & (S_ - 1);
        tbase = ((size_t)((b * M_ + m) * S_ + s)) * D_;
    } else {
        tbase = (size_t)rg * D_;
    }
#pragma unroll
    for (int i = 0; i < 3; i++) {
        int c = tid + i * 256;
        tv[i] = (mode == 0) ? tf[tbase + c] : bf2f(tb[tbase + c]);
        xh[i] = bf2f(xhat[pbase + c]);
        s1 += tv[i];
        s2 += tv[i] * xh[i];
    }
    s1 = block_sum(s1);
    s2 = block_sum(s2);
    float mt = s1 * (1.0f / D_);
    float mx = s2 * (1.0f / D_);
    float rs = rstd[r];
#pragma unroll
    for (int i = 0; i < 3; i++) {
        int c = tid + i * 256;
        dh[(size_t)rg * D_ + c] = f2bf(g[c] * rs * (tv[i] - mt - xh[i] * mx));
    }
}

// ---------------- bf16 MFMA GEMM <BM,BN>, BK=64, 2-deep pipeline, stage-early ----------------
// Per iter: read frags -> lgkmcnt(0) -> barrier (buf fully read) -> stage(t+2) into freed buf
// -> MFMA (overlaps stage flight) -> vmcnt(L) (t+1 landed, t+2 in flight) -> barrier.
template <int BM, int BN, int EPI, bool RS, bool OS>
__global__ __launch_bounds__(256) void gemm_mfma(const ushort* __restrict__ A,
                                                 const ushort* __restrict__ BT,
                                                 const float* __restrict__ bias,
                                                 const float* __restrict__ resf,
                                                 const ushort* __restrict__ resb,
                                                 float* __restrict__ Cf,
                                                 ushort* __restrict__ Cb,
                                                 ushort* __restrict__ aux,
                                                 int Nc, int Kd) {
    constexpr int FI = BM / 32, FJ = BN / 32;
    constexpr int LA = BM / 32, LB = BN / 32, L = LA + LB;
    __shared__ ushort As[2][BM * 64];
    __shared__ ushort Bs[2][BN * 64];
    int tid = threadIdx.x;
    int wave = tid >> 6, lane = tid & 63;
    int wr = wave >> 1, wc = wave & 1;
    int gx = gridDim.x, nwg = gx * gridDim.y;
    int work = xcd_swz(blockIdx.x + blockIdx.y * gx, nwg);
    // band remap: 8 row-panels per band, col-major inside (L2 anti-thrash); gy%8==0 required
    int band = work / (8 * gx);
    int wi = work - band * (8 * gx);
    int row0 = (band * 8 + (wi & 7)) * BM;
    int col0 = (wi >> 3) * BN;

    int srow = lane >> 3;
    int skel = ((lane & 7) ^ (lane >> 3)) * 8;
    const ushort* Ag0 = A + (size_t)(row0 + srow) * Kd + skel;
    const ushort* Bg0 = BT + (size_t)(col0 + srow) * Kd + skel;

    auto stage = [&](int bufi, int k0) {
#pragma unroll
        for (int cc = 0; cc < LA; cc++) {
            int c = wave * LA + cc;
            gll16(Ag0 + (size_t)(c * 8) * Kd + k0, As[bufi] + c * 512);
        }
#pragma unroll
        for (int cc = 0; cc < LB; cc++) {
            int c = wave * LB + cc;
            gll16(Bg0 + (size_t)(c * 8) * Kd + k0, Bs[bufi] + c * 512);
        }
    };

    int frow = lane & 15, fkb = (lane >> 4) * 8;
    int aoff[2][FI], boff[2][FJ];
#pragma unroll
    for (int ks = 0; ks < 2; ks++) {
        int sw = (fkb + ks * 32) ^ ((frow & 7) * 8);
#pragma unroll
        for (int i = 0; i < FI; i++) aoff[ks][i] = (wr * (BM / 2) + i * 16 + frow) * 64 + sw;
#pragma unroll
        for (int j = 0; j < FJ; j++) boff[ks][j] = (wc * (BN / 2) + j * 16 + frow) * 64 + sw;
    }

    f32x4 acc[FI][FJ] = {};

    int nt = Kd >> 6;
    stage(0, 0);
    if (nt > 1) { stage(1, 64); waitcnt_vm<L>(); }
    else        { waitcnt_vm<0>(); }
    __builtin_amdgcn_s_barrier();
    __builtin_amdgcn_sched_barrier(0);

    int cur = 0;
    for (int t = 0; t < nt; t++) {
        bf16x8 af[2][FI], bfv[2][FJ];
        const ushort* Ab = As[cur];
        const ushort* Bb = Bs[cur];
#pragma unroll
        for (int ks = 0; ks < 2; ks++) {
#pragma unroll
            for (int i = 0; i < FI; i++) af[ks][i] = *(const bf16x8*)(Ab + aoff[ks][i]);
#pragma unroll
            for (int j = 0; j < FJ; j++) bfv[ks][j] = *(const bf16x8*)(Bb + boff[ks][j]);
        }
        waitcnt_lgkm0();                 // reads retired before others' stages can overwrite
        __builtin_amdgcn_s_barrier();    // all waves done reading buf[cur]
        if (t + 2 < nt) {
            stage(cur, (t + 2) << 6);    // issue early: overlaps with MFMA below
            __builtin_amdgcn_sched_barrier(0);
        }
#pragma unroll
        for (int ks = 0; ks < 2; ks++)
#pragma unroll
            for (int i = 0; i < FI; i++)
#pragma unroll
                for (int j = 0; j < FJ; j++)
                    acc[i][j] = __builtin_amdgcn_mfma_f32_16x16x32_bf16(af[ks][i], bfv[ks][j], acc[i][j], 0, 0, 0);
        __builtin_amdgcn_sched_barrier(0);
        if (t + 2 < nt) waitcnt_vm<L>();        // t+1 complete, t+2 in flight
        else if (t + 1 < nt) waitcnt_vm<0>();   // last prefetched tile complete
        __builtin_amdgcn_s_barrier();
        __builtin_amdgcn_sched_barrier(0);
        cur ^= 1;
    }

    // C/D layout: col = lane&15, row = (lane>>4)*4 + reg
#pragma unroll
    for (int i = 0; i < FI; i++) {
        int rbase = row0 + wr * (BM / 2) + i * 16 + (lane >> 4) * 4;
#pragma unroll
        for (int j = 0; j < FJ; j++) {
            int c = col0 + wc * (BN / 2) + j * 16 + (lane & 15);
#pragma unroll
            for (int r = 0; r < 4; r++) {
                int rg = rbase + r;
                size_t off = (size_t)rg * Nc + c;
                float v = acc[i][j][r];
                if (EPI == 0) {
                    if (bias) v += bias[c];
                    if (resf) v += resf[RS ? stroff(rg, c, Nc) : off];
                    if (resb) v += bf2f(resb[off]);
                    if (Cf) { if (OS) Cf[stroff(rg, c, Nc)] = v; else Cf[off] = v; }
                    if (Cb) Cb[off] = f2bf(v);
                } else if (EPI == 1) {
                    v += bias[c];
                    float cdf = 0.5f * (1.0f + erff(v * 0.70710678118654752f));
                    Cb[off] = f2bf(v * cdf);
                    aux[off] = f2bf(cdf + v * 0.39894228040143267f * expf(-0.5f * v * v));
                } else {
                    Cb[off] = f2bf(v * bf2f(aux[(size_t)(rg & (BS_ - 1)) * Nc + c]));
                }
            }
        }
    }
}

// ---------------- MFMA QK^T: single-shot BK=64 (K=HD), XOR-swizzled ----------------
template <bool TAN>
__global__ __launch_bounds__(256) void attn_qk_mfma(const ushort* __restrict__ qkvb,
                                                    const ushort* __restrict__ dqkvp,
                                                    ushort* __restrict__ sc) {
    int work = xcd_swz(blockIdx.x, gridDim.x);
    constexpr int NT = S_ / 128;  // 4
    int mz = work / (BH_ * NT * NT);
    int rem = work % (BH_ * NT * NT);
    int bh = rem / (NT * NT);
    int r2 = rem % (NT * NT);
    int q0 = (r2 / NT) * 128, kc0 = (r2 % NT) * 128;
    int b = bh / H_, hh = bh - b * H_;
    const size_t qoff = (size_t)b * S_ * 3 * D_ + hh * HD_;
    const int ld = 3 * D_;
    const ushort* dqkv = TAN ? dqkvp + (size_t)mz * BS3D_ : nullptr;
    __shared__ ushort As[128 * 64];
    __shared__ ushort Bs[128 * 64];
    __shared__ ushort dAs[TAN ? 128 * 64 : 1];
    __shared__ ushort dBs[TAN ? 128 * 64 : 1];
    int tid = threadIdx.x;
    int wave = tid >> 6, lane = tid & 63;
    int wr = wave >> 1, wc = wave & 1;

    int srow = lane >> 3;
    int skel = ((lane & 7) ^ (lane >> 3)) * 8;
    const ushort* Ag0 = qkvb + qoff + (size_t)(q0 + srow) * ld + skel;
    const ushort* Bg0 = qkvb + qoff + D_ + (size_t)(kc0 + srow) * ld + skel;

#pragma unroll
    for (int cc = 0; cc < 4; cc++) {
        int c = wave * 4 + cc;
        gll16(Ag0 + (size_t)(c * 8) * ld, As + c * 512);
        gll16(Bg0 + (size_t)(c * 8) * ld, Bs + c * 512);
        if (TAN) {
            gll16(dqkv + qoff + (size_t)(q0 + c * 8 + srow) * ld + skel, dAs + c * 512);
            gll16(dqkv + qoff + D_ + (size_t)(kc0 + c * 8 + srow) * ld + skel, dBs + c * 512);
        }
    }
    __syncthreads();

    int frow = lane & 15, fkb = (lane >> 4) * 8;
    f32x4 acc[4][4] = {};
#pragma unroll
    for (int ks = 0; ks < 2; ks++) {
        int sw = (fkb + ks * 32) ^ ((frow & 7) * 8);
        bf16x8 af[4], bfv[4];
#pragma unroll
        for (int i = 0; i < 4; i++) af[i] = *(const bf16x8*)(As + (wr * 64 + i * 16 + frow) * 64 + sw);
#pragma unroll
        for (int j = 0; j < 4; j++) bfv[j] = *(const bf16x8*)(Bs + (wc * 64 + j * 16 + frow) * 64 + sw);
        if (!TAN) {
#pragma unroll
            for (int i = 0; i < 4; i++)
#pragma unroll
                for (int j = 0; j < 4; j++)
                    acc[i][j] = __builtin_amdgcn_mfma_f32_16x16x32_bf16(af[i], bfv[j], acc[i][j], 0, 0, 0);
        } else {
            bf16x8 daf[4], dbf[4];
#pragma unroll
            for (int i = 0; i < 4; i++) daf[i] = *(const bf16x8*)(dAs + (wr * 64 + i * 16 + frow) * 64 + sw);
#pragma unroll
            for (int j = 0; j < 4; j++) dbf[j] = *(const bf16x8*)(dBs + (wc * 64 + j * 16 + frow) * 64 + sw);
#pragma unroll
            for (int i = 0; i < 4; i++)
#pragma unroll
                for (int j = 0; j < 4; j++) {
                    acc[i][j] = __builtin_amdgcn_mfma_f32_16x16x32_bf16(daf[i], bfv[j], acc[i][j], 0, 0, 0);
                    acc[i][j] = __builtin_amdgcn_mfma_f32_16x16x32_bf16(af[i], dbf[j], acc[i][j], 0, 0, 0);
                }
        }
    }

    ushort* scm = sc + (size_t)mz * ATT_;
#pragma unroll
    for (int i = 0; i < 4; i++) {
        int rbase = q0 + wr * 64 + i * 16 + (lane >> 4) * 4;
#pragma unroll
        for (int j = 0; j < 4; j++) {
            int c = kc0 + wc * 64 + j * 16 + (lane & 15);
#pragma unroll
            for (int r = 0; r < 4; r++)
                scm[((size_t)bh * S_ + rbase + r) * S_ + c] = f2bf(acc[i][j][r] * SCALE_);
        }
    }
}

// ---------------- primal P@V: BK=64, XOR-swizzled ----------------
__global__ __launch_bounds__(256) void attn_av_p(const ushort* __restrict__ Pb,
                                                 const ushort* __restrict__ Vt,
                                                 ushort* __restrict__ outp) {
    int work = xcd_swz(blockIdx.x, gridDim.x);
    constexpr int NT = S_ / 128;  // 4
    int bh = work / NT;
    int q0 = (work % NT) * 128;
    int b = bh / H_, hh = bh - b * H_;
    const ushort* Pg = Pb + (size_t)bh * S_ * S_;
    const ushort* Vg = Vt + (size_t)bh * HD_ * S_;
    __shared__ ushort As[128 * 64];
    __shared__ ushort Bs[64 * 64];
    int tid = threadIdx.x;
    int wave = tid >> 6, lane = tid & 63;
    int wr = wave >> 1, wc = wave & 1;
    int srow = lane >> 3;
    int skel = ((lane & 7) ^ (lane >> 3)) * 8;
    int frow = lane & 15, fkb = (lane >> 4) * 8;

    f32x4 acc[4][2] = {};
    for (int k0 = 0; k0 < S_; k0 += 64) {
#pragma unroll
        for (int cc = 0; cc < 4; cc++) {
            int c = wave * 4 + cc;
            gll16(Pg + (size_t)(q0 + c * 8 + srow) * S_ + k0 + skel, As + c * 512);
        }
#pragma unroll
        for (int cc = 0; cc < 2; cc++) {
            int c = wave * 2 + cc;
            gll16(Vg + (size_t)(c * 8 + srow) * S_ + k0 + skel, Bs + c * 512);
        }
        __syncthreads();
#pragma unroll
        for (int ks = 0; ks < 2; ks++) {
            int sw = (fkb + ks * 32) ^ ((frow & 7) * 8);
            bf16x8 af[4], bfv[2];
#pragma unroll
            for (int i = 0; i < 4; i++) af[i] = *(const bf16x8*)(As + (wr * 64 + i * 16 + frow) * 64 + sw);
#pragma unroll
            for (int j = 0; j < 2; j++) bfv[j] = *(const bf16x8*)(Bs + (wc * 32 + j * 16 + frow) * 64 + sw);
#pragma unroll
            for (int i = 0; i < 4; i++)
#pragma unroll
                for (int j = 0; j < 2; j++)
                    acc[i][j] = __builtin_amdgcn_mfma_f32_16x16x32_bf16(af[i], bfv[j], acc[i][j], 0, 0, 0);
        }
        __syncthreads();
    }

#pragma unroll
    for (int i = 0; i < 4; i++) {
        int rbase = q0 + wr * 64 + i * 16 + (lane >> 4) * 4;
#pragma unroll
        for (int j = 0; j < 2; j++) {
            int c = hh * HD_ + wc * 32 + j * 16 + (lane & 15);
#pragma unroll
            for (int r = 0; r < 4; r++)
                outp[(size_t)(b * S_ + rbase + r) * D_ + c] = f2bf(acc[i][j][r]);
        }
    }
}

// ---------------- FUSED tangent P@V (single pass, 128 q-rows): dO = (P.D)@V + P@dV - s*O ----
// 1D grid: work = mz*(BH*4) + bh*4 + qi
__global__ __launch_bounds__(256) void attn_av_tan(const ushort* __restrict__ Pb,
                                                   const ushort* __restrict__ dscp,
                                                   const ushort* __restrict__ Vt,
                                                   const ushort* __restrict__ dVtp,
                                                   const ushort* __restrict__ Ob,
                                                   ushort* __restrict__ outp) {
    int work = xcd_swz(blockIdx.x, gridDim.x);
    int mz = work / (BH_ * 4);
    int rem = work % (BH_ * 4);
    int bh = rem / 4;
    int q0 = (rem % 4) * 128;
    int b = bh / H_, hh = bh - b * H_;
    const ushort* Pg = Pb + (size_t)bh * S_ * S_;
    const ushort* Dg = dscp + (size_t)mz * ATT_ + (size_t)bh * S_ * S_;
    const ushort* Vg = Vt + (size_t)bh * HD_ * S_;
    const ushort* dVg = dVtp + (size_t)mz * BSD_ + (size_t)bh * HD_ * S_;
    ushort* outm = outp + (size_t)mz * BSD_;
    __shared__ ushort Ps[128 * 64], Ds[128 * 64], Vs[64 * 64], dVs[64 * 64];  // 48 KB
    int tid = threadIdx.x;
    int wave = tid >> 6, lane = tid & 63;
    int wr = wave >> 1, wc = wave & 1;
    int srow = lane >> 3;
    int skel = ((lane & 7) ^ (lane >> 3)) * 8;
    int frow = lane & 15, fkb = (lane >> 4) * 8;
    int aoff[2][4], boff[2][2];
#pragma unroll
    for (int ks = 0; ks < 2; ks++) {
        int sw = (fkb + ks * 32) ^ ((frow & 7) * 8);
#pragma unroll
        for (int i = 0; i < 4; i++) aoff[ks][i] = (wr * 64 + i * 16 + frow) * 64 + sw;
#pragma unroll
        for (int j = 0; j < 2; j++) boff[ks][j] = (wc * 32 + j * 16 + frow) * 64 + sw;
    }

    float s[4] = {0.f, 0.f, 0.f, 0.f};
    f32x4 acc[4][2] = {};

    for (int k0 = 0; k0 < S_; k0 += 64) {
#pragma unroll
        for (int cc = 0; cc < 4; cc++) {
            int c = wave * 4 + cc;
            gll16(Pg + (size_t)(q0 + c * 8 + srow) * S_ + k0 + skel, Ps + c * 512);
            gll16(Dg + (size_t)(q0 + c * 8 + srow) * S_ + k0 + skel, Ds + c * 512);
        }
#pragma unroll
        for (int cc = 0; cc < 2; cc++) {
            int c = wave * 2 + cc;
            gll16(Vg + (size_t)(c * 8 + srow) * S_ + k0 + skel, Vs + c * 512);
            gll16(dVg + (size_t)(c * 8 + srow) * S_ + k0 + skel, dVs + c * 512);
        }
        __syncthreads();
#pragma unroll
        for (int ks = 0; ks < 2; ks++) {
            bf16x8 p8[4], pq8[4], v8[2], dv8[2];
#pragma unroll
            for (int i = 0; i < 4; i++) {
                p8[i] = *(const bf16x8*)(Ps + aoff[ks][i]);
                bf16x8 d8 = *(const bf16x8*)(Ds + aoff[ks][i]);
#pragma unroll
                for (int e = 0; e < 8; e++) {
                    float pd = bf2f((ushort)p8[i][e]) * bf2f((ushort)d8[e]);
                    s[i] += pd;
                    pq8[i][e] = (short)f2bf(pd);
                }
            }
#pragma unroll
            for (int j = 0; j < 2; j++) {
                v8[j] = *(const bf16x8*)(Vs + boff[ks][j]);
                dv8[j] = *(const bf16x8*)(dVs + boff[ks][j]);
            }
#pragma unroll
            for (int i = 0; i < 4; i++)
#pragma unroll
                for (int j = 0; j < 2; j++) {
                    acc[i][j] = __builtin_amdgcn_mfma_f32_16x16x32_bf16(pq8[i], v8[j], acc[i][j], 0, 0, 0);
                    acc[i][j] = __builtin_amdgcn_mfma_f32_16x16x32_bf16(p8[i], dv8[j], acc[i][j], 0, 0, 0);
                }
        }
        __syncthreads();
    }

    // complete rowsums: lanes {l, l^16, l^32, l^48} hold the 4 k-slices of row (.. + frow)
#pragma unroll
    for (int i = 0; i < 4; i++) {
        s[i] += __shfl_xor(s[i], 16);
        s[i] += __shfl_xor(s[i], 32);
    }

    // epilogue: out = acc - s[row]*O[row][col]
#pragma unroll
    for (int i = 0; i < 4; i++) {
        int rbase = q0 + wr * 64 + i * 16 + (lane >> 4) * 4;
#pragma unroll
        for (int r = 0; r < 4; r++) {
            float sc = __shfl(s[i], ((lane >> 4) << 2) + r);
#pragma unroll
            for (int j = 0; j < 2; j++) {
                int c = hh * HD_ + wc * 32 + j * 16 + (lane & 15);
                float o = bf2f(Ob[(size_t)(b * S_ + rbase + r) * D_ + c]);
                outm[(size_t)(b * S_ + rbase + r) * D_ + c] = f2bf(acc[i][j][r] - sc * o);
            }
        }
    }
}

// ---------------- softmax: bf16 scores -> bf16 probs ----------------
__global__ __launch_bounds__(256) void softmax_rows(const ushort* __restrict__ sc,
                                                    ushort* __restrict__ scb) {
    size_t row = blockIdx.x;
    const ushort* p = sc + row * S_;
    int tid = threadIdx.x;
    ushort2 vu = *(const ushort2*)&p[tid * 2];
    float v0 = bf2f(vu.x), v1 = bf2f(vu.y);
    float mx = block_max(fmaxf(v0, v1));
    float e0 = expf(v0 - mx), e1 = expf(v1 - mx);
    float s = block_sum(e0 + e1);
    float inv = 1.0f / s;
    ushort2 ob; ob.x = f2bf(e0 * inv); ob.y = f2bf(e1 * inv);
    *(ushort2*)&scb[row * S_ + tid * 2] = ob;
}

// ---------------- host ----------------
extern "C" void kernel_launch(void* const* d_in, const int* in_sizes, int n_in,
                              void* d_out, int out_size, void* d_ws, size_t ws_size,
                              hipStream_t stream) {
    const float* x = (const float*)d_in[0];
    const float* xt = (const float*)d_in[1];
    const float* g1 = (const float*)d_in[2];
    const float* b1 = (const float*)d_in[3];
    const float* Wqkv = (const float*)d_in[4];
    const float* Wproj = (const float*)d_in[5];
    const float* bproj = (const float*)d_in[6];
    const float* g2 = (const float*)d_in[7];
    const float* b2 = (const float*)d_in[8];
    const float* W1 = (const float*)d_in[9];
    const float* bf1 = (const float*)d_in[10];
    const float* W2 = (const float*)d_in[11];
    const float* bf2 = (const float*)d_in[12];
    float* out = (float*)d_out;
    float* out_t = out + BSD_;   // [B,M,S,D]

    char* wp = (char*)d_ws;
    auto alloc = [&](size_t bytes) { void* p = wp; wp += (bytes + 255) & ~(size_t)255; return p; };
    ushort* xhat1 = (ushort*)alloc(BSD_ * 2);
    ushort* hb = (ushort*)alloc(BSD_ * 2);
    ushort* obb = (ushort*)alloc(BSD_ * 2);
    float* x2 = (float*)alloc(BSD_ * 4);
    ushort* xhat2 = (ushort*)alloc(BSD_ * 2);
    ushort* h2b = (ushort*)alloc(BSD_ * 2);
    ushort* dx2b = (ushort*)alloc(4 * BSD_ * 2);   // [4*BS][D] bf16
    ushort* qkvb = (ushort*)alloc(BS3D_ * 2);
    ushort* Vt = (ushort*)alloc(BSD_ * 2);
    ushort* dscb2 = (ushort*)alloc(2 * ATT_ * 2);  // [2][BH,S,S]
    ushort* attnb = (ushort*)alloc(ATT_ * 2);      // primal probs bf16
    ushort* gpb = (ushort*)alloc(BSF_ * 2);        // gelu'(u) bf16
    float* rstd1 = (float*)alloc(BS_ * 4);
    float* rstd2 = (float*)alloc(BS_ * 4);
    ushort* WqkvT = (ushort*)alloc((size_t)D_ * 3 * D_ * 2);
    ushort* WprojT = (ushort*)alloc((size_t)D_ * D_ * 2);
    ushort* W1T = (ushort*)alloc((size_t)DFF_ * D_ * 2);
    ushort* W2T = (ushort*)alloc((size_t)D_ * DFF_ * 2);
    // Region A (50.3 MB): phase1 {dqkvb4 + dVt4}, phase2 {da4}
    char* regA = (char*)alloc(4 * BSF_ * 2);
    ushort* dqkvb4 = (ushort*)regA;
    ushort* dVt4 = (ushort*)(regA + 4 * BS3D_ * 2);
    ushort* da4 = (ushort*)regA;
    // Region B (12.6 MB): {ab} -> {dh4} -> {dob4} -> {dh2_4}
    char* regB = (char*)alloc(4 * BSD_ * 2);
    ushort* ab = (ushort*)regB;
    ushort* dh4 = (ushort*)regB;
    ushort* dob4 = (ushort*)regB;
    ushort* dh2_4 = (ushort*)regB;

    // ---- weights -> bf16 transposed [N][K] ----
    transpose_f2b<<<dim3(3 * D_ / 32, D_ / 32), 256, 0, stream>>>(Wqkv, WqkvT, D_, 3 * D_);
    transpose_f2b<<<dim3(D_ / 32, D_ / 32), 256, 0, stream>>>(Wproj, WprojT, D_, D_);
    transpose_f2b<<<dim3(DFF_ / 32, D_ / 32), 256, 0, stream>>>(W1, W1T, D_, DFF_);
    transpose_f2b<<<dim3(D_ / 32, DFF_ / 32), 256, 0, stream>>>(W2, W2T, DFF_, D_);

    // ---- primal ----
    ln_fwd<<<BS_, 256, 0, stream>>>(x, g1, b1, xhat1, hb, rstd1);
    gemm_mfma<64, 128, 0, false, false><<<dim3(3 * D_ / 128, BS_ / 64), 256, 0, stream>>>(
        hb, WqkvT, nullptr, nullptr, nullptr, nullptr, qkvb, nullptr, 3 * D_, D_);
    transpose_v<<<dim3(S_ / 32, HD_ / 32, BH_), 256, 0, stream>>>(qkvb, Vt);
    attn_qk_mfma<false><<<(S_ / 128) * (S_ / 128) * BH_, 256, 0, stream>>>(qkvb, nullptr, dscb2);
    softmax_rows<<<BH_ * S_, 256, 0, stream>>>(dscb2, attnb);
    attn_av_p<<<(S_ / 128) * BH_, 256, 0, stream>>>(attnb, Vt, obb);
    gemm_mfma<64, 64, 0, false, false><<<dim3(D_ / 64, BS_ / 64), 256, 0, stream>>>(
        obb, WprojT, bproj, x, nullptr, x2, nullptr, nullptr, D_, D_);
    ln_fwd<<<BS_, 256, 0, stream>>>(x2, g2, b2, xhat2, h2b, rstd2);
    gemm_mfma<128, 128, 1, false, false><<<dim3(DFF_ / 128, BS_ / 128), 256, 0, stream>>>(
        h2b, W1T, bf1, nullptr, nullptr, nullptr, ab, gpb, DFF_, D_);
    gemm_mfma<64, 64, 0, false, false><<<dim3(D_ / 64, BS_ / 64), 256, 0, stream>>>(
        ab, W2T, bf2, x2, nullptr, out, nullptr, nullptr, D_, DFF_);

    // ---- tangents: batched linear stages (M = 8192), pair-batched fused attention ----
    ln_jvp<<<4 * BS_, 256, 0, stream>>>(xt, nullptr, 0, xhat1, rstd1, g1, dh4);
    gemm_mfma<128, 128, 0, false, false><<<dim3(3 * D_ / 128, 4 * BS_ / 128), 256, 0, stream>>>(
        dh4, WqkvT, nullptr, nullptr, nullptr, nullptr, dqkvb4, nullptr, 3 * D_, D_);
    transpose_v<<<dim3(S_ / 32, HD_ / 32, 4 * BH_), 256, 0, stream>>>(dqkvb4, dVt4);
    for (int p = 0; p < 2; p++) {
        attn_qk_mfma<true><<<2 * (S_ / 128) * (S_ / 128) * BH_, 256, 0, stream>>>(
            qkvb, dqkvb4 + (size_t)p * 2 * BS3D_, dscb2);
        attn_av_tan<<<2 * 4 * BH_, 256, 0, stream>>>(
            attnb, dscb2, Vt, dVt4 + (size_t)p * 2 * BSD_, obb, dob4 + (size_t)p * 2 * BSD_);
    }
    gemm_mfma<128, 64, 0, true, false><<<dim3(D_ / 64, 4 * BS_ / 128), 256, 0, stream>>>(
        dob4, WprojT, nullptr, xt, nullptr, nullptr, dx2b, nullptr, D_, D_);
    ln_jvp<<<4 * BS_, 256, 0, stream>>>(nullptr, dx2b, 1, xhat2, rstd2, g2, dh2_4);
    gemm_mfma<128, 128, 2, false, false><<<dim3(DFF_ / 128, 4 * BS_ / 128), 256, 0, stream>>>(
        dh2_4, W1T, nullptr, nullptr, nullptr, nullptr, da4, gpb, DFF_, D_);
    gemm_mfma<128, 64, 0, false, true><<<dim3(D_ / 64, 4 * BS_ / 128), 256, 0, stream>>>(
        da4, W2T, nullptr, nullptr, dx2b, out_t, nullptr, nullptr, D_, DFF_);
}

// Round 15
// 452.043 us; speedup vs baseline: 1.1341x; 1.0001x over previous
//
#include <hip/hip_runtime.h>
#include <math.h>

constexpr int B_ = 4, S_ = 512, D_ = 768, H_ = 12, M_ = 4, DFF_ = 3072, HD_ = 64;
constexpr float EPS_ = 1e-6f;
constexpr float SCALE_ = 0.125f;  // HD^-0.5
constexpr int BS_ = B_ * S_;
constexpr int BH_ = B_ * H_;
constexpr long long BSD_ = (long long)BS_ * D_;
constexpr long long BS3D_ = (long long)BS_ * 3 * D_;
constexpr long long ATT_ = (long long)BH_ * S_ * S_;
constexpr long long BSF_ = (long long)BS_ * DFF_;

typedef __attribute__((ext_vector_type(8))) short bf16x8;
typedef __attribute__((ext_vector_type(4))) float f32x4;

__device__ __forceinline__ ushort f2bf(float f) {
    uint32_t u = __float_as_uint(f);
    u += 0x7FFF + ((u >> 16) & 1);
    return (ushort)(u >> 16);
}
__device__ __forceinline__ float bf2f(ushort u) {
    return __uint_as_float((uint32_t)u << 16);
}

__device__ __forceinline__ void gll16(const ushort* g, ushort* l) {
    __builtin_amdgcn_global_load_lds((const __attribute__((address_space(1))) void*)g,
                                     (__attribute__((address_space(3))) void*)l, 16, 0, 0);
}

// counted vmcnt wait (literal required in asm)
template <int N> __device__ __forceinline__ void waitcnt_vm() {
    if constexpr (N == 0) asm volatile("s_waitcnt vmcnt(0)" ::: "memory");
    else if constexpr (N == 4) asm volatile("s_waitcnt vmcnt(4)" ::: "memory");
    else if constexpr (N == 6) asm volatile("s_waitcnt vmcnt(6)" ::: "memory");
    else if constexpr (N == 8) asm volatile("s_waitcnt vmcnt(8)" ::: "memory");
    else static_assert(N == 0 || N == 4 || N == 6 || N == 8, "add literal");
}

__device__ __forceinline__ void waitcnt_lgkm0() {
    asm volatile("s_waitcnt lgkmcnt(0)" ::: "memory");
    __builtin_amdgcn_sched_barrier(0);  // rule 18: fence MFMA/reg-op hoisting
}

// XCD-chunked bijective block remap (m204)
__device__ __forceinline__ int xcd_swz(int flat, int nwg) {
    int q = nwg >> 3, r = nwg & 7;
    int x = flat & 7, pos = flat >> 3;
    int base = (x < r) ? x * (q + 1) : r * (q + 1) + (x - r) * q;
    return base + pos;
}

// batched-row (rg in [0,8192)) -> [B,M,S,Nc] offset
__device__ __forceinline__ size_t stroff(int rg, int c, int Nc) {
    int m = rg >> 11;
    int b = (rg >> 9) & (B_ - 1);
    int s = rg & (S_ - 1);
    return ((size_t)((b * M_ + m) * S_ + s)) * Nc + c;
}

// ---------------- block reductions (256 threads = 4 waves) ----------------
__device__ __forceinline__ float block_sum(float v) {
    __shared__ float red[4];
    int tid = threadIdx.x;
#pragma unroll
    for (int off = 32; off > 0; off >>= 1) v += __shfl_down(v, off, 64);
    __syncthreads();
    if ((tid & 63) == 0) red[tid >> 6] = v;
    __syncthreads();
    return red[0] + red[1] + red[2] + red[3];
}

__device__ __forceinline__ float block_max(float v) {
    __shared__ float red[4];
    int tid = threadIdx.x;
#pragma unroll
    for (int off = 32; off > 0; off >>= 1) v = fmaxf(v, __shfl_down(v, off, 64));
    __syncthreads();
    if ((tid & 63) == 0) red[tid >> 6] = v;
    __syncthreads();
    return fmaxf(fmaxf(red[0], red[1]), fmaxf(red[2], red[3]));
}

// ---------------- weight transpose+convert: W[K][N] f32 -> WT[N][K] bf16 ----------------
__global__ __launch_bounds__(256) void transpose_f2b(const float* __restrict__ W,
                                                     ushort* __restrict__ WT,
                                                     int K, int N) {
    __shared__ float t[32][33];
    int n0 = blockIdx.x * 32, k0 = blockIdx.y * 32;
    int tx = threadIdx.x & 31, ty = threadIdx.x >> 5;
#pragma unroll
    for (int i = 0; i < 4; i++)
        t[ty + i * 8][tx] = W[(size_t)(k0 + ty + i * 8) * N + n0 + tx];
    __syncthreads();
#pragma unroll
    for (int i = 0; i < 4; i++)
        WT[(size_t)(n0 + ty + i * 8) * K + k0 + tx] = f2bf(t[tx][ty + i * 8]);
}

// ---------------- V transpose: src[m][B,S,3D] bf16 -> dst[m][bh][HD][S] bf16 ----------------
__global__ __launch_bounds__(256) void transpose_v(const ushort* __restrict__ src0,
                                                   ushort* __restrict__ dst0) {
    int z = blockIdx.z;
    int m = z / BH_, bh = z % BH_;
    const ushort* qkvb = src0 + (size_t)m * BS3D_;
    ushort* Vt = dst0 + (size_t)m * BSD_;
    int b = bh / H_, hh = bh - b * H_;
    int s0 = blockIdx.x * 32, d0 = blockIdx.y * 32;
    __shared__ ushort t[32][33];
    int tx = threadIdx.x & 31, ty = threadIdx.x >> 5;
#pragma unroll
    for (int i = 0; i < 4; i++)
        t[ty + i * 8][tx] = qkvb[(size_t)(b * S_ + s0 + ty + i * 8) * 3 * D_ + 2 * D_ + hh * HD_ + d0 + tx];
    __syncthreads();
#pragma unroll
    for (int i = 0; i < 4; i++)
        Vt[(size_t)bh * HD_ * S_ + (size_t)(d0 + ty + i * 8) * S_ + s0 + tx] = t[tx][ty + i * 8];
}

// ---------------- LayerNorm forward: xhat bf16, h bf16 ----------------
__global__ __launch_bounds__(256) void ln_fwd(const float* __restrict__ x,
                                              const float* __restrict__ g,
                                              const float* __restrict__ bta,
                                              ushort* __restrict__ xhat,
                                              ushort* __restrict__ h,
                                              float* __restrict__ rstd) {
    int row = blockIdx.x;
    const float* xr = x + (size_t)row * D_;
    int tid = threadIdx.x;
    float v[3];
    float s = 0.f;
#pragma unroll
    for (int i = 0; i < 3; i++) { v[i] = xr[tid + i * 256]; s += v[i]; }
    s = block_sum(s);
    float mu = s * (1.0f / D_);
    float vs = 0.f;
#pragma unroll
    for (int i = 0; i < 3; i++) { float c = v[i] - mu; vs += c * c; }
    vs = block_sum(vs);
    float rs = rsqrtf(vs * (1.0f / D_) + EPS_);
#pragma unroll
    for (int i = 0; i < 3; i++) {
        int c = tid + i * 256;
        float xh = (v[i] - mu) * rs;
        xhat[(size_t)row * D_ + c] = f2bf(xh);
        h[(size_t)row * D_ + c] = f2bf(xh * g[c] + bta[c]);
    }
    if (tid == 0) rstd[row] = rs;
}

// ---------------- batched LayerNorm JVP: grid 4*BS_ rows ----------------
__global__ __launch_bounds__(256) void ln_jvp(const float* __restrict__ tf,
                                              const ushort* __restrict__ tb, int mode,
                                              const ushort* __restrict__ xhat,
                                              const float* __restrict__ rstd,
                                              const float* __restrict__ g,
                                              ushort* __restrict__ dh) {
    int rg = blockIdx.x;
    int r = rg & (BS_ - 1);
    size_t pbase = (size_t)r * D_;
    int tid = threadIdx.x;
    float tv[3], xh[3];
    float s1 = 0.f, s2 = 0.f;
    size_t tbase;
    if (mode == 0) {
        int m = rg >> 11;
        int b = r >> 9, s = r & (S_ - 1);
        tbase = ((size_t)((b * M_ + m) * S_ + s)) * D_;
    } else {
        tbase = (size_t)rg * D_;
    }
#pragma unroll
    for (int i = 0; i < 3; i++) {
        int c = tid + i * 256;
        tv[i] = (mode == 0) ? tf[tbase + c] : bf2f(tb[tbase + c]);
        xh[i] = bf2f(xhat[pbase + c]);
        s1 += tv[i];
        s2 += tv[i] * xh[i];
    }
    s1 = block_sum(s1);
    s2 = block_sum(s2);
    float mt = s1 * (1.0f / D_);
    float mx = s2 * (1.0f / D_);
    float rs = rstd[r];
#pragma unroll
    for (int i = 0; i < 3; i++) {
        int c = tid + i * 256;
        dh[(size_t)rg * D_ + c] = f2bf(g[c] * rs * (tv[i] - mt - xh[i] * mx));
    }
}

// ---------------- bf16 MFMA GEMM <BM,BN>, BK=64, 2-deep pipeline, stage-early ----------------
// Per iter: read frags -> lgkmcnt(0) -> barrier (buf fully read) -> stage(t+2) into freed buf
// -> MFMA (overlaps stage flight) -> vmcnt(L) (t+1 landed, t+2 in flight) -> barrier.
template <int BM, int BN, int EPI, bool RS, bool OS>
__global__ __launch_bounds__(256) void gemm_mfma(const ushort* __restrict__ A,
                                                 const ushort* __restrict__ BT,
                                                 const float* __restrict__ bias,
                                                 const float* __restrict__ resf,
                                                 const ushort* __restrict__ resb,
                                                 float* __restrict__ Cf,
                                                 ushort* __restrict__ Cb,
                                                 ushort* __restrict__ aux,
                                                 int Nc, int Kd) {
    constexpr int FI = BM / 32, FJ = BN / 32;
    constexpr int LA = BM / 32, LB = BN / 32, L = LA + LB;
    __shared__ ushort As[2][BM * 64];
    __shared__ ushort Bs[2][BN * 64];
    int tid = threadIdx.x;
    int wave = tid >> 6, lane = tid & 63;
    int wr = wave >> 1, wc = wave & 1;
    int gx = gridDim.x, nwg = gx * gridDim.y;
    int work = xcd_swz(blockIdx.x + blockIdx.y * gx, nwg);
    // band remap: 8 row-panels per band, col-major inside (L2 anti-thrash); gy%8==0 required
    int band = work / (8 * gx);
    int wi = work - band * (8 * gx);
    int row0 = (band * 8 + (wi & 7)) * BM;
    int col0 = (wi >> 3) * BN;

    int srow = lane >> 3;
    int skel = ((lane & 7) ^ (lane >> 3)) * 8;
    const ushort* Ag0 = A + (size_t)(row0 + srow) * Kd + skel;
    const ushort* Bg0 = BT + (size_t)(col0 + srow) * Kd + skel;

    auto stage = [&](int bufi, int k0) {
#pragma unroll
        for (int cc = 0; cc < LA; cc++) {
            int c = wave * LA + cc;
            gll16(Ag0 + (size_t)(c * 8) * Kd + k0, As[bufi] + c * 512);
        }
#pragma unroll
        for (int cc = 0; cc < LB; cc++) {
            int c = wave * LB + cc;
            gll16(Bg0 + (size_t)(c * 8) * Kd + k0, Bs[bufi] + c * 512);
        }
    };

    int frow = lane & 15, fkb = (lane >> 4) * 8;
    int aoff[2][FI], boff[2][FJ];
#pragma unroll
    for (int ks = 0; ks < 2; ks++) {
        int sw = (fkb + ks * 32) ^ ((frow & 7) * 8);
#pragma unroll
        for (int i = 0; i < FI; i++) aoff[ks][i] = (wr * (BM / 2) + i * 16 + frow) * 64 + sw;
#pragma unroll
        for (int j = 0; j < FJ; j++) boff[ks][j] = (wc * (BN / 2) + j * 16 + frow) * 64 + sw;
    }

    f32x4 acc[FI][FJ] = {};

    int nt = Kd >> 6;
    stage(0, 0);
    if (nt > 1) { stage(1, 64); waitcnt_vm<L>(); }
    else        { waitcnt_vm<0>(); }
    __builtin_amdgcn_s_barrier();
    __builtin_amdgcn_sched_barrier(0);

    int cur = 0;
    for (int t = 0; t < nt; t++) {
        bf16x8 af[2][FI], bfv[2][FJ];
        const ushort* Ab = As[cur];
        const ushort* Bb = Bs[cur];
#pragma unroll
        for (int ks = 0; ks < 2; ks++) {
#pragma unroll
            for (int i = 0; i < FI; i++) af[ks][i] = *(const bf16x8*)(Ab + aoff[ks][i]);
#pragma unroll
            for (int j = 0; j < FJ; j++) bfv[ks][j] = *(const bf16x8*)(Bb + boff[ks][j]);
        }
        waitcnt_lgkm0();                 // reads retired before others' stages can overwrite
        __builtin_amdgcn_s_barrier();    // all waves done reading buf[cur]
        if (t + 2 < nt) {
            stage(cur, (t + 2) << 6);    // issue early: overlaps with MFMA below
            __builtin_amdgcn_sched_barrier(0);
        }
#pragma unroll
        for (int ks = 0; ks < 2; ks++)
#pragma unroll
            for (int i = 0; i < FI; i++)
#pragma unroll
                for (int j = 0; j < FJ; j++)
                    acc[i][j] = __builtin_amdgcn_mfma_f32_16x16x32_bf16(af[ks][i], bfv[ks][j], acc[i][j], 0, 0, 0);
        __builtin_amdgcn_sched_barrier(0);
        if (t + 2 < nt) waitcnt_vm<L>();        // t+1 complete, t+2 in flight
        else if (t + 1 < nt) waitcnt_vm<0>();   // last prefetched tile complete
        __builtin_amdgcn_s_barrier();
        __builtin_amdgcn_sched_barrier(0);
        cur ^= 1;
    }

    // C/D layout: col = lane&15, row = (lane>>4)*4 + reg
#pragma unroll
    for (int i = 0; i < FI; i++) {
        int rbase = row0 + wr * (BM / 2) + i * 16 + (lane >> 4) * 4;
#pragma unroll
        for (int j = 0; j < FJ; j++) {
            int c = col0 + wc * (BN / 2) + j * 16 + (lane & 15);
#pragma unroll
            for (int r = 0; r < 4; r++) {
                int rg = rbase + r;
                size_t off = (size_t)rg * Nc + c;
                float v = acc[i][j][r];
                if (EPI == 0) {
                    if (bias) v += bias[c];
                    if (resf) v += resf[RS ? stroff(rg, c, Nc) : off];
                    if (resb) v += bf2f(resb[off]);
                    if (Cf) { if (OS) Cf[stroff(rg, c, Nc)] = v; else Cf[off] = v; }
                    if (Cb) Cb[off] = f2bf(v);
                } else if (EPI == 1) {
                    v += bias[c];
                    float cdf = 0.5f * (1.0f + erff(v * 0.70710678118654752f));
                    Cb[off] = f2bf(v * cdf);
                    aux[off] = f2bf(cdf + v * 0.39894228040143267f * expf(-0.5f * v * v));
                } else {
                    Cb[off] = f2bf(v * bf2f(aux[(size_t)(rg & (BS_ - 1)) * Nc + c]));
                }
            }
        }
    }
}

// ---------------- MFMA QK^T: single-shot BK=64 (K=HD), XOR-swizzled ----------------
template <bool TAN>
__global__ __launch_bounds__(256) void attn_qk_mfma(const ushort* __restrict__ qkvb,
                                                    const ushort* __restrict__ dqkvp,
                                                    ushort* __restrict__ sc) {
    int work = xcd_swz(blockIdx.x, gridDim.x);
    constexpr int NT = S_ / 128;  // 4
    int mz = work / (BH_ * NT * NT);
    int rem = work % (BH_ * NT * NT);
    int bh = rem / (NT * NT);
    int r2 = rem % (NT * NT);
    int q0 = (r2 / NT) * 128, kc0 = (r2 % NT) * 128;
    int b = bh / H_, hh = bh - b * H_;
    const size_t qoff = (size_t)b * S_ * 3 * D_ + hh * HD_;
    const int ld = 3 * D_;
    const ushort* dqkv = TAN ? dqkvp + (size_t)mz * BS3D_ : nullptr;
    __shared__ ushort As[128 * 64];
    __shared__ ushort Bs[128 * 64];
    __shared__ ushort dAs[TAN ? 128 * 64 : 1];
    __shared__ ushort dBs[TAN ? 128 * 64 : 1];
    int tid = threadIdx.x;
    int wave = tid >> 6, lane = tid & 63;
    int wr = wave >> 1, wc = wave & 1;

    int srow = lane >> 3;
    int skel = ((lane & 7) ^ (lane >> 3)) * 8;
    const ushort* Ag0 = qkvb + qoff + (size_t)(q0 + srow) * ld + skel;
    const ushort* Bg0 = qkvb + qoff + D_ + (size_t)(kc0 + srow) * ld + skel;

#pragma unroll
    for (int cc = 0; cc < 4; cc++) {
        int c = wave * 4 + cc;
        gll16(Ag0 + (size_t)(c * 8) * ld, As + c * 512);
        gll16(Bg0 + (size_t)(c * 8) * ld, Bs + c * 512);
        if (TAN) {
            gll16(dqkv + qoff + (size_t)(q0 + c * 8 + srow) * ld + skel, dAs + c * 512);
            gll16(dqkv + qoff + D_ + (size_t)(kc0 + c * 8 + srow) * ld + skel, dBs + c * 512);
        }
    }
    __syncthreads();

    int frow = lane & 15, fkb = (lane >> 4) * 8;
    f32x4 acc[4][4] = {};
#pragma unroll
    for (int ks = 0; ks < 2; ks++) {
        int sw = (fkb + ks * 32) ^ ((frow & 7) * 8);
        bf16x8 af[4], bfv[4];
#pragma unroll
        for (int i = 0; i < 4; i++) af[i] = *(const bf16x8*)(As + (wr * 64 + i * 16 + frow) * 64 + sw);
#pragma unroll
        for (int j = 0; j < 4; j++) bfv[j] = *(const bf16x8*)(Bs + (wc * 64 + j * 16 + frow) * 64 + sw);
        if (!TAN) {
#pragma unroll
            for (int i = 0; i < 4; i++)
#pragma unroll
                for (int j = 0; j < 4; j++)
                    acc[i][j] = __builtin_amdgcn_mfma_f32_16x16x32_bf16(af[i], bfv[j], acc[i][j], 0, 0, 0);
        } else {
            bf16x8 daf[4], dbf[4];
#pragma unroll
            for (int i = 0; i < 4; i++) daf[i] = *(const bf16x8*)(dAs + (wr * 64 + i * 16 + frow) * 64 + sw);
#pragma unroll
            for (int j = 0; j < 4; j++) dbf[j] = *(const bf16x8*)(dBs + (wc * 64 + j * 16 + frow) * 64 + sw);
#pragma unroll
            for (int i = 0; i < 4; i++)
#pragma unroll
                for (int j = 0; j < 4; j++) {
                    acc[i][j] = __builtin_amdgcn_mfma_f32_16x16x32_bf16(daf[i], bfv[j], acc[i][j], 0, 0, 0);
                    acc[i][j] = __builtin_amdgcn_mfma_f32_16x16x32_bf16(af[i], dbf[j], acc[i][j], 0, 0, 0);
                }
        }
    }

    ushort* scm = sc + (size_t)mz * ATT_;
#pragma unroll
    for (int i = 0; i < 4; i++) {
        int rbase = q0 + wr * 64 + i * 16 + (lane >> 4) * 4;
#pragma unroll
        for (int j = 0; j < 4; j++) {
            int c = kc0 + wc * 64 + j * 16 + (lane & 15);
#pragma unroll
            for (int r = 0; r < 4; r++)
                scm[((size_t)bh * S_ + rbase + r) * S_ + c] = f2bf(acc[i][j][r] * SCALE_);
        }
    }
}

// ---------------- primal P@V: BK=64, XOR-swizzled ----------------
__global__ __launch_bounds__(256) void attn_av_p(const ushort* __restrict__ Pb,
                                                 const ushort* __restrict__ Vt,
                                                 ushort* __restrict__ outp) {
    int work = xcd_swz(blockIdx.x, gridDim.x);
    constexpr int NT = S_ / 128;  // 4
    int bh = work / NT;
    int q0 = (work % NT) * 128;
    int b = bh / H_, hh = bh - b * H_;
    const ushort* Pg = Pb + (size_t)bh * S_ * S_;
    const ushort* Vg = Vt + (size_t)bh * HD_ * S_;
    __shared__ ushort As[128 * 64];
    __shared__ ushort Bs[64 * 64];
    int tid = threadIdx.x;
    int wave = tid >> 6, lane = tid & 63;
    int wr = wave >> 1, wc = wave & 1;
    int srow = lane >> 3;
    int skel = ((lane & 7) ^ (lane >> 3)) * 8;
    int frow = lane & 15, fkb = (lane >> 4) * 8;

    f32x4 acc[4][2] = {};
    for (int k0 = 0; k0 < S_; k0 += 64) {
#pragma unroll
        for (int cc = 0; cc < 4; cc++) {
            int c = wave * 4 + cc;
            gll16(Pg + (size_t)(q0 + c * 8 + srow) * S_ + k0 + skel, As + c * 512);
        }
#pragma unroll
        for (int cc = 0; cc < 2; cc++) {
            int c = wave * 2 + cc;
            gll16(Vg + (size_t)(c * 8 + srow) * S_ + k0 + skel, Bs + c * 512);
        }
        __syncthreads();
#pragma unroll
        for (int ks = 0; ks < 2; ks++) {
            int sw = (fkb + ks * 32) ^ ((frow & 7) * 8);
            bf16x8 af[4], bfv[2];
#pragma unroll
            for (int i = 0; i < 4; i++) af[i] = *(const bf16x8*)(As + (wr * 64 + i * 16 + frow) * 64 + sw);
#pragma unroll
            for (int j = 0; j < 2; j++) bfv[j] = *(const bf16x8*)(Bs + (wc * 32 + j * 16 + frow) * 64 + sw);
#pragma unroll
            for (int i = 0; i < 4; i++)
#pragma unroll
                for (int j = 0; j < 2; j++)
                    acc[i][j] = __builtin_amdgcn_mfma_f32_16x16x32_bf16(af[i], bfv[j], acc[i][j], 0, 0, 0);
        }
        __syncthreads();
    }

#pragma unroll
    for (int i = 0; i < 4; i++) {
        int rbase = q0 + wr * 64 + i * 16 + (lane >> 4) * 4;
#pragma unroll
        for (int j = 0; j < 2; j++) {
            int c = hh * HD_ + wc * 32 + j * 16 + (lane & 15);
#pragma unroll
            for (int r = 0; r < 4; r++)
                outp[(size_t)(b * S_ + rbase + r) * D_ + c] = f2bf(acc[i][j][r]);
        }
    }
}

// ---------------- FUSED tangent P@V (single pass, 128 q-rows): dO = (P.D)@V + P@dV - s*O ----
// 1D grid: work = mz*(BH*4) + bh*4 + qi
__global__ __launch_bounds__(256) void attn_av_tan(const ushort* __restrict__ Pb,
                                                   const ushort* __restrict__ dscp,
                                                   const ushort* __restrict__ Vt,
                                                   const ushort* __restrict__ dVtp,
                                                   const ushort* __restrict__ Ob,
                                                   ushort* __restrict__ outp) {
    int work = xcd_swz(blockIdx.x, gridDim.x);
    int mz = work / (BH_ * 4);
    int rem = work % (BH_ * 4);
    int bh = rem / 4;
    int q0 = (rem % 4) * 128;
    int b = bh / H_, hh = bh - b * H_;
    const ushort* Pg = Pb + (size_t)bh * S_ * S_;
    const ushort* Dg = dscp + (size_t)mz * ATT_ + (size_t)bh * S_ * S_;
    const ushort* Vg = Vt + (size_t)bh * HD_ * S_;
    const ushort* dVg = dVtp + (size_t)mz * BSD_ + (size_t)bh * HD_ * S_;
    ushort* outm = outp + (size_t)mz * BSD_;
    __shared__ ushort Ps[128 * 64], Ds[128 * 64], Vs[64 * 64], dVs[64 * 64];  // 48 KB
    int tid = threadIdx.x;
    int wave = tid >> 6, lane = tid & 63;
    int wr = wave >> 1, wc = wave & 1;
    int srow = lane >> 3;
    int skel = ((lane & 7) ^ (lane >> 3)) * 8;
    int frow = lane & 15, fkb = (lane >> 4) * 8;
    int aoff[2][4], boff[2][2];
#pragma unroll
    for (int ks = 0; ks < 2; ks++) {
        int sw = (fkb + ks * 32) ^ ((frow & 7) * 8);
#pragma unroll
        for (int i = 0; i < 4; i++) aoff[ks][i] = (wr * 64 + i * 16 + frow) * 64 + sw;
#pragma unroll
        for (int j = 0; j < 2; j++) boff[ks][j] = (wc * 32 + j * 16 + frow) * 64 + sw;
    }

    float s[4] = {0.f, 0.f, 0.f, 0.f};
    f32x4 acc[4][2] = {};

    for (int k0 = 0; k0 < S_; k0 += 64) {
#pragma unroll
        for (int cc = 0; cc < 4; cc++) {
            int c = wave * 4 + cc;
            gll16(Pg + (size_t)(q0 + c * 8 + srow) * S_ + k0 + skel, Ps + c * 512);
            gll16(Dg + (size_t)(q0 + c * 8 + srow) * S_ + k0 + skel, Ds + c * 512);
        }
#pragma unroll
        for (int cc = 0; cc < 2; cc++) {
            int c = wave * 2 + cc;
            gll16(Vg + (size_t)(c * 8 + srow) * S_ + k0 + skel, Vs + c * 512);
            gll16(dVg + (size_t)(c * 8 + srow) * S_ + k0 + skel, dVs + c * 512);
        }
        __syncthreads();
#pragma unroll
        for (int ks = 0; ks < 2; ks++) {
            bf16x8 p8[4], pq8[4], v8[2], dv8[2];
#pragma unroll
            for (int i = 0; i < 4; i++) {
                p8[i] = *(const bf16x8*)(Ps + aoff[ks][i]);
                bf16x8 d8 = *(const bf16x8*)(Ds + aoff[ks][i]);
#pragma unroll
                for (int e = 0; e < 8; e++) {
                    float pd = bf2f((ushort)p8[i][e]) * bf2f((ushort)d8[e]);
                    s[i] += pd;
                    pq8[i][e] = (short)f2bf(pd);
                }
            }
#pragma unroll
            for (int j = 0; j < 2; j++) {
                v8[j] = *(const bf16x8*)(Vs + boff[ks][j]);
                dv8[j] = *(const bf16x8*)(dVs + boff[ks][j]);
            }
#pragma unroll
            for (int i = 0; i < 4; i++)
#pragma unroll
                for (int j = 0; j < 2; j++) {
                    acc[i][j] = __builtin_amdgcn_mfma_f32_16x16x32_bf16(pq8[i], v8[j], acc[i][j], 0, 0, 0);
                    acc[i][j] = __builtin_amdgcn_mfma_f32_16x16x32_bf16(p8[i], dv8[j], acc[i][j], 0, 0, 0);
                }
        }
        __syncthreads();
    }

    // complete rowsums: lanes {l, l^16, l^32, l^48} hold the 4 k-slices of row (.. + frow)
#pragma unroll
    for (int i = 0; i < 4; i++) {
        s[i] += __shfl_xor(s[i], 16);
        s[i] += __shfl_xor(s[i], 32);
    }

    // epilogue: out = acc - s[row]*O[row][col]
#pragma unroll
    for (int i = 0; i < 4; i++) {
        int rbase = q0 + wr * 64 + i * 16 + (lane >> 4) * 4;
#pragma unroll
        for (int r = 0; r < 4; r++) {
            float sc = __shfl(s[i], ((lane >> 4) << 2) + r);
#pragma unroll
            for (int j = 0; j < 2; j++) {
                int c = hh * HD_ + wc * 32 + j * 16 + (lane & 15);
                float o = bf2f(Ob[(size_t)(b * S_ + rbase + r) * D_ + c]);
                outm[(size_t)(b * S_ + rbase + r) * D_ + c] = f2bf(acc[i][j][r] - sc * o);
            }
        }
    }
}

// ---------------- softmax: bf16 scores -> bf16 probs ----------------
__global__ __launch_bounds__(256) void softmax_rows(const ushort* __restrict__ sc,
                                                    ushort* __restrict__ scb) {
    size_t row = blockIdx.x;
    const ushort* p = sc + row * S_;
    int tid = threadIdx.x;
    ushort2 vu = *(const ushort2*)&p[tid * 2];
    float v0 = bf2f(vu.x), v1 = bf2f(vu.y);
    float mx = block_max(fmaxf(v0, v1));
    float e0 = expf(v0 - mx), e1 = expf(v1 - mx);
    float s = block_sum(e0 + e1);
    float inv = 1.0f / s;
    ushort2 ob; ob.x = f2bf(e0 * inv); ob.y = f2bf(e1 * inv);
    *(ushort2*)&scb[row * S_ + tid * 2] = ob;
}

// ---------------- host ----------------
extern "C" void kernel_launch(void* const* d_in, const int* in_sizes, int n_in,
                              void* d_out, int out_size, void* d_ws, size_t ws_size,
                              hipStream_t stream) {
    const float* x = (const float*)d_in[0];
    const float* xt = (const float*)d_in[1];
    const float* g1 = (const float*)d_in[2];
    const float* b1 = (const float*)d_in[3];
    const float* Wqkv = (const float*)d_in[4];
    const float* Wproj = (const float*)d_in[5];
    const float* bproj = (const float*)d_in[6];
    const float* g2 = (const float*)d_in[7];
    const float* b2 = (const float*)d_in[8];
    const float* W1 = (const float*)d_in[9];
    const float* bf1 = (const float*)d_in[10];
    const float* W2 = (const float*)d_in[11];
    const float* bf2 = (const float*)d_in[12];
    float* out = (float*)d_out;
    float* out_t = out + BSD_;   // [B,M,S,D]

    char* wp = (char*)d_ws;
    auto alloc = [&](size_t bytes) { void* p = wp; wp += (bytes + 255) & ~(size_t)255; return p; };
    ushort* xhat1 = (ushort*)alloc(BSD_ * 2);
    ushort* hb = (ushort*)alloc(BSD_ * 2);
    ushort* obb = (ushort*)alloc(BSD_ * 2);
    float* x2 = (float*)alloc(BSD_ * 4);
    ushort* xhat2 = (ushort*)alloc(BSD_ * 2);
    ushort* h2b = (ushort*)alloc(BSD_ * 2);
    ushort* dx2b = (ushort*)alloc(4 * BSD_ * 2);   // [4*BS][D] bf16
    ushort* qkvb = (ushort*)alloc(BS3D_ * 2);
    ushort* Vt = (ushort*)alloc(BSD_ * 2);
    ushort* dscb2 = (ushort*)alloc(2 * ATT_ * 2);  // [2][BH,S,S]
    ushort* attnb = (ushort*)alloc(ATT_ * 2);      // primal probs bf16
    ushort* gpb = (ushort*)alloc(BSF_ * 2);        // gelu'(u) bf16
    float* rstd1 = (float*)alloc(BS_ * 4);
    float* rstd2 = (float*)alloc(BS_ * 4);
    ushort* WqkvT = (ushort*)alloc((size_t)D_ * 3 * D_ * 2);
    ushort* WprojT = (ushort*)alloc((size_t)D_ * D_ * 2);
    ushort* W1T = (ushort*)alloc((size_t)DFF_ * D_ * 2);
    ushort* W2T = (ushort*)alloc((size_t)D_ * DFF_ * 2);
    // Region A (50.3 MB): phase1 {dqkvb4 + dVt4}, phase2 {da4}
    char* regA = (char*)alloc(4 * BSF_ * 2);
    ushort* dqkvb4 = (ushort*)regA;
    ushort* dVt4 = (ushort*)(regA + 4 * BS3D_ * 2);
    ushort* da4 = (ushort*)regA;
    // Region B (12.6 MB): {ab} -> {dh4} -> {dob4} -> {dh2_4}
    char* regB = (char*)alloc(4 * BSD_ * 2);
    ushort* ab = (ushort*)regB;
    ushort* dh4 = (ushort*)regB;
    ushort* dob4 = (ushort*)regB;
    ushort* dh2_4 = (ushort*)regB;

    // ---- weights -> bf16 transposed [N][K] ----
    transpose_f2b<<<dim3(3 * D_ / 32, D_ / 32), 256, 0, stream>>>(Wqkv, WqkvT, D_, 3 * D_);
    transpose_f2b<<<dim3(D_ / 32, D_ / 32), 256, 0, stream>>>(Wproj, WprojT, D_, D_);
    transpose_f2b<<<dim3(DFF_ / 32, D_ / 32), 256, 0, stream>>>(W1, W1T, D_, DFF_);
    transpose_f2b<<<dim3(D_ / 32, DFF_ / 32), 256, 0, stream>>>(W2, W2T, DFF_, D_);

    // ---- primal ----
    ln_fwd<<<BS_, 256, 0, stream>>>(x, g1, b1, xhat1, hb, rstd1);
    gemm_mfma<64, 128, 0, false, false><<<dim3(3 * D_ / 128, BS_ / 64), 256, 0, stream>>>(
        hb, WqkvT, nullptr, nullptr, nullptr, nullptr, qkvb, nullptr, 3 * D_, D_);
    transpose_v<<<dim3(S_ / 32, HD_ / 32, BH_), 256, 0, stream>>>(qkvb, Vt);
    attn_qk_mfma<false><<<(S_ / 128) * (S_ / 128) * BH_, 256, 0, stream>>>(qkvb, nullptr, dscb2);
    softmax_rows<<<BH_ * S_, 256, 0, stream>>>(dscb2, attnb);
    attn_av_p<<<(S_ / 128) * BH_, 256, 0, stream>>>(attnb, Vt, obb);
    gemm_mfma<64, 64, 0, false, false><<<dim3(D_ / 64, BS_ / 64), 256, 0, stream>>>(
        obb, WprojT, bproj, x, nullptr, x2, nullptr, nullptr, D_, D_);
    ln_fwd<<<BS_, 256, 0, stream>>>(x2, g2, b2, xhat2, h2b, rstd2);
    gemm_mfma<128, 128, 1, false, false><<<dim3(DFF_ / 128, BS_ / 128), 256, 0, stream>>>(
        h2b, W1T, bf1, nullptr, nullptr, nullptr, ab, gpb, DFF_, D_);
    gemm_mfma<64, 64, 0, false, false><<<dim3(D_ / 64, BS_ / 64), 256, 0, stream>>>(
        ab, W2T, bf2, x2, nullptr, out, nullptr, nullptr, D_, DFF_);

    // ---- tangents: batched linear stages (M = 8192), pair-batched fused attention ----
    ln_jvp<<<4 * BS_, 256, 0, stream>>>(xt, nullptr, 0, xhat1, rstd1, g1, dh4);
    gemm_mfma<128, 128, 0, false, false><<<dim3(3 * D_ / 128, 4 * BS_ / 128), 256, 0, stream>>>(
        dh4, WqkvT, nullptr, nullptr, nullptr, nullptr, dqkvb4, nullptr, 3 * D_, D_);
    transpose_v<<<dim3(S_ / 32, HD_ / 32, 4 * BH_), 256, 0, stream>>>(dqkvb4, dVt4);
    for (int p = 0; p < 2; p++) {
        attn_qk_mfma<true><<<2 * (S_ / 128) * (S_ / 128) * BH_, 256, 0, stream>>>(
            qkvb, dqkvb4 + (size_t)p * 2 * BS3D_, dscb2);
        attn_av_tan<<<2 * 4 * BH_, 256, 0, stream>>>(
            attnb, dscb2, Vt, dVt4 + (size_t)p * 2 * BSD_, obb, dob4 + (size_t)p * 2 * BSD_);
    }
    gemm_mfma<128, 64, 0, true, false><<<dim3(D_ / 64, 4 * BS_ / 128), 256, 0, stream>>>(
        dob4, WprojT, nullptr, xt, nullptr, nullptr, dx2b, nullptr, D_, D_);
    ln_jvp<<<4 * BS_, 256, 0, stream>>>(nullptr, dx2b, 1, xhat2, rstd2, g2, dh2_4);
    gemm_mfma<128, 128, 2, false, false><<<dim3(DFF_ / 128, 4 * BS_ / 128), 256, 0, stream>>>(
        dh2_4, W1T, nullptr, nullptr, nullptr, nullptr, da4, gpb, DFF_, D_);
    gemm_mfma<128, 64, 0, false, true><<<dim3(D_ / 64, 4 * BS_ / 128), 256, 0, stream>>>(
        da4, W2T, nullptr, nullptr, dx2b, out_t, nullptr, nullptr, D_, DFF_);
}

// Round 16
// 443.799 us; speedup vs baseline: 1.1552x; 1.0186x over previous
//
#include <hip/hip_runtime.h>
#include <math.h>

constexpr int B_ = 4, S_ = 512, D_ = 768, H_ = 12, M_ = 4, DFF_ = 3072, HD_ = 64;
constexpr float EPS_ = 1e-6f;
constexpr float SCALE_ = 0.125f;  // HD^-0.5
constexpr int BS_ = B_ * S_;
constexpr int BH_ = B_ * H_;
constexpr long long BSD_ = (long long)BS_ * D_;
constexpr long long BS3D_ = (long long)BS_ * 3 * D_;
constexpr long long ATT_ = (long long)BH_ * S_ * S_;
constexpr long long BSF_ = (long long)BS_ * DFF_;

typedef __attribute__((ext_vector_type(8))) short bf16x8;
typedef __attribute__((ext_vector_type(4))) float f32x4;

__device__ __forceinline__ ushort f2bf(float f) {
    uint32_t u = __float_as_uint(f);
    u += 0x7FFF + ((u >> 16) & 1);
    return (ushort)(u >> 16);
}
__device__ __forceinline__ float bf2f(ushort u) {
    return __uint_as_float((uint32_t)u << 16);
}

__device__ __forceinline__ void gll16(const ushort* g, ushort* l) {
    __builtin_amdgcn_global_load_lds((const __attribute__((address_space(1))) void*)g,
                                     (__attribute__((address_space(3))) void*)l, 16, 0, 0);
}

// counted vmcnt wait (literal required in asm)
template <int N> __device__ __forceinline__ void waitcnt_vm() {
    if constexpr (N == 0) asm volatile("s_waitcnt vmcnt(0)" ::: "memory");
    else if constexpr (N == 4) asm volatile("s_waitcnt vmcnt(4)" ::: "memory");
    else if constexpr (N == 6) asm volatile("s_waitcnt vmcnt(6)" ::: "memory");
    else if constexpr (N == 8) asm volatile("s_waitcnt vmcnt(8)" ::: "memory");
    else static_assert(N == 0 || N == 4 || N == 6 || N == 8, "add literal");
}

__device__ __forceinline__ void waitcnt_lgkm0() {
    asm volatile("s_waitcnt lgkmcnt(0)" ::: "memory");
    __builtin_amdgcn_sched_barrier(0);  // rule 18: fence MFMA/reg-op hoisting
}

// XCD-chunked bijective block remap (m204)
__device__ __forceinline__ int xcd_swz(int flat, int nwg) {
    int q = nwg >> 3, r = nwg & 7;
    int x = flat & 7, pos = flat >> 3;
    int base = (x < r) ? x * (q + 1) : r * (q + 1) + (x - r) * q;
    return base + pos;
}

// batched-row (rg in [0,8192)) -> [B,M,S,Nc] offset
__device__ __forceinline__ size_t stroff(int rg, int c, int Nc) {
    int m = rg >> 11;
    int b = (rg >> 9) & (B_ - 1);
    int s = rg & (S_ - 1);
    return ((size_t)((b * M_ + m) * S_ + s)) * Nc + c;
}

// ---------------- block reductions (256 threads = 4 waves) ----------------
__device__ __forceinline__ float block_sum(float v) {
    __shared__ float red[4];
    int tid = threadIdx.x;
#pragma unroll
    for (int off = 32; off > 0; off >>= 1) v += __shfl_down(v, off, 64);
    __syncthreads();
    if ((tid & 63) == 0) red[tid >> 6] = v;
    __syncthreads();
    return red[0] + red[1] + red[2] + red[3];
}

__device__ __forceinline__ float block_max(float v) {
    __shared__ float red[4];
    int tid = threadIdx.x;
#pragma unroll
    for (int off = 32; off > 0; off >>= 1) v = fmaxf(v, __shfl_down(v, off, 64));
    __syncthreads();
    if ((tid & 63) == 0) red[tid >> 6] = v;
    __syncthreads();
    return fmaxf(fmaxf(red[0], red[1]), fmaxf(red[2], red[3]));
}

// ---------------- weight transpose+convert: W[K][N] f32 -> WT[N][K] bf16 ----------------
__global__ __launch_bounds__(256) void transpose_f2b(const float* __restrict__ W,
                                                     ushort* __restrict__ WT,
                                                     int K, int N) {
    __shared__ float t[32][33];
    int n0 = blockIdx.x * 32, k0 = blockIdx.y * 32;
    int tx = threadIdx.x & 31, ty = threadIdx.x >> 5;
#pragma unroll
    for (int i = 0; i < 4; i++)
        t[ty + i * 8][tx] = W[(size_t)(k0 + ty + i * 8) * N + n0 + tx];
    __syncthreads();
#pragma unroll
    for (int i = 0; i < 4; i++)
        WT[(size_t)(n0 + ty + i * 8) * K + k0 + tx] = f2bf(t[tx][ty + i * 8]);
}

// ---------------- V transpose: qkv5[5][B,S,3D] bf16 -> m=0: Vt[bh][HD][S]; m>=1: dVt4[m-1] ----
__global__ __launch_bounds__(256) void transpose_v(const ushort* __restrict__ src0,
                                                   ushort* __restrict__ Vt0,
                                                   ushort* __restrict__ dVt4) {
    int z = blockIdx.z;
    int m = z / BH_, bh = z % BH_;
    const ushort* qkvb = src0 + (size_t)m * BS3D_;
    ushort* Vt = (m == 0) ? Vt0 : dVt4 + (size_t)(m - 1) * BSD_;
    int b = bh / H_, hh = bh - b * H_;
    int s0 = blockIdx.x * 32, d0 = blockIdx.y * 32;
    __shared__ ushort t[32][33];
    int tx = threadIdx.x & 31, ty = threadIdx.x >> 5;
#pragma unroll
    for (int i = 0; i < 4; i++)
        t[ty + i * 8][tx] = qkvb[(size_t)(b * S_ + s0 + ty + i * 8) * 3 * D_ + 2 * D_ + hh * HD_ + d0 + tx];
    __syncthreads();
#pragma unroll
    for (int i = 0; i < 4; i++)
        Vt[(size_t)bh * HD_ * S_ + (size_t)(d0 + ty + i * 8) * S_ + s0 + tx] = t[tx][ty + i * 8];
}

// ---------------- LayerNorm forward: xhat bf16, h bf16 ----------------
__global__ __launch_bounds__(256) void ln_fwd(const float* __restrict__ x,
                                              const float* __restrict__ g,
                                              const float* __restrict__ bta,
                                              ushort* __restrict__ xhat,
                                              ushort* __restrict__ h,
                                              float* __restrict__ rstd) {
    int row = blockIdx.x;
    const float* xr = x + (size_t)row * D_;
    int tid = threadIdx.x;
    float v[3];
    float s = 0.f;
#pragma unroll
    for (int i = 0; i < 3; i++) { v[i] = xr[tid + i * 256]; s += v[i]; }
    s = block_sum(s);
    float mu = s * (1.0f / D_);
    float vs = 0.f;
#pragma unroll
    for (int i = 0; i < 3; i++) { float c = v[i] - mu; vs += c * c; }
    vs = block_sum(vs);
    float rs = rsqrtf(vs * (1.0f / D_) + EPS_);
#pragma unroll
    for (int i = 0; i < 3; i++) {
        int c = tid + i * 256;
        float xh = (v[i] - mu) * rs;
        xhat[(size_t)row * D_ + c] = f2bf(xh);
        h[(size_t)row * D_ + c] = f2bf(xh * g[c] + bta[c]);
    }
    if (tid == 0) rstd[row] = rs;
}

// ---------------- batched LayerNorm JVP: grid 4*BS_ rows ----------------
// mode 0: tf strided [B,M,S,D] f32 (also emits xtb bf16 compact copy); mode 1: tb bf16 compact
__global__ __launch_bounds__(256) void ln_jvp(const float* __restrict__ tf,
                                              const ushort* __restrict__ tb, int mode,
                                              const ushort* __restrict__ xhat,
                                              const float* __restrict__ rstd,
                                              const float* __restrict__ g,
                                              ushort* __restrict__ dh,
                                              ushort* __restrict__ xtb) {
    int rg = blockIdx.x;
    int r = rg & (BS_ - 1);
    size_t pbase = (size_t)r * D_;
    int tid = threadIdx.x;
    float tv[3], xh[3];
    float s1 = 0.f, s2 = 0.f;
    size_t tbase;
    if (mode == 0) {
        int m = rg >> 11;
        int b = r >> 9, s = r & (S_ - 1);
        tbase = ((size_t)((b * M_ + m) * S_ + s)) * D_;
    } else {
        tbase = (size_t)rg * D_;
    }
#pragma unroll
    for (int i = 0; i < 3; i++) {
        int c = tid + i * 256;
        tv[i] = (mode == 0) ? tf[tbase + c] : bf2f(tb[tbase + c]);
        xh[i] = bf2f(xhat[pbase + c]);
        s1 += tv[i];
        s2 += tv[i] * xh[i];
    }
    s1 = block_sum(s1);
    s2 = block_sum(s2);
    float mt = s1 * (1.0f / D_);
    float mx = s2 * (1.0f / D_);
    float rs = rstd[r];
#pragma unroll
    for (int i = 0; i < 3; i++) {
        int c = tid + i * 256;
        dh[(size_t)rg * D_ + c] = f2bf(g[c] * rs * (tv[i] - mt - xh[i] * mx));
        if (mode == 0 && xtb) xtb[(size_t)rg * D_ + c] = f2bf(tv[i]);
    }
}

// ---------------- bf16 MFMA GEMM <BM,BN>, BK=64, 2-deep pipeline, stage-early ----------------
template <int BM, int BN, int EPI, bool RS, bool OS>
__global__ __launch_bounds__(256) void gemm_mfma(const ushort* __restrict__ A,
                                                 const ushort* __restrict__ BT,
                                                 const float* __restrict__ bias,
                                                 const float* __restrict__ resf,
                                                 const ushort* __restrict__ resb,
                                                 float* __restrict__ Cf,
                                                 ushort* __restrict__ Cb,
                                                 ushort* __restrict__ aux,
                                                 int Nc, int Kd) {
    constexpr int FI = BM / 32, FJ = BN / 32;
    constexpr int LA = BM / 32, LB = BN / 32, L = LA + LB;
    __shared__ ushort As[2][BM * 64];
    __shared__ ushort Bs[2][BN * 64];
    int tid = threadIdx.x;
    int wave = tid >> 6, lane = tid & 63;
    int wr = wave >> 1, wc = wave & 1;
    int gx = gridDim.x, nwg = gx * gridDim.y;
    int work = xcd_swz(blockIdx.x + blockIdx.y * gx, nwg);
    // band remap: 8 row-panels per band, col-major inside (L2 anti-thrash); gy%8==0 required
    int band = work / (8 * gx);
    int wi = work - band * (8 * gx);
    int row0 = (band * 8 + (wi & 7)) * BM;
    int col0 = (wi >> 3) * BN;

    int srow = lane >> 3;
    int skel = ((lane & 7) ^ (lane >> 3)) * 8;
    const ushort* Ag0 = A + (size_t)(row0 + srow) * Kd + skel;
    const ushort* Bg0 = BT + (size_t)(col0 + srow) * Kd + skel;

    auto stage = [&](int bufi, int k0) {
#pragma unroll
        for (int cc = 0; cc < LA; cc++) {
            int c = wave * LA + cc;
            gll16(Ag0 + (size_t)(c * 8) * Kd + k0, As[bufi] + c * 512);
        }
#pragma unroll
        for (int cc = 0; cc < LB; cc++) {
            int c = wave * LB + cc;
            gll16(Bg0 + (size_t)(c * 8) * Kd + k0, Bs[bufi] + c * 512);
        }
    };

    int frow = lane & 15, fkb = (lane >> 4) * 8;
    int aoff[2][FI], boff[2][FJ];
#pragma unroll
    for (int ks = 0; ks < 2; ks++) {
        int sw = (fkb + ks * 32) ^ ((frow & 7) * 8);
#pragma unroll
        for (int i = 0; i < FI; i++) aoff[ks][i] = (wr * (BM / 2) + i * 16 + frow) * 64 + sw;
#pragma unroll
        for (int j = 0; j < FJ; j++) boff[ks][j] = (wc * (BN / 2) + j * 16 + frow) * 64 + sw;
    }

    f32x4 acc[FI][FJ] = {};

    int nt = Kd >> 6;
    stage(0, 0);
    if (nt > 1) { stage(1, 64); waitcnt_vm<L>(); }
    else        { waitcnt_vm<0>(); }
    __builtin_amdgcn_s_barrier();
    __builtin_amdgcn_sched_barrier(0);

    int cur = 0;
    for (int t = 0; t < nt; t++) {
        bf16x8 af[2][FI], bfv[2][FJ];
        const ushort* Ab = As[cur];
        const ushort* Bb = Bs[cur];
#pragma unroll
        for (int ks = 0; ks < 2; ks++) {
#pragma unroll
            for (int i = 0; i < FI; i++) af[ks][i] = *(const bf16x8*)(Ab + aoff[ks][i]);
#pragma unroll
            for (int j = 0; j < FJ; j++) bfv[ks][j] = *(const bf16x8*)(Bb + boff[ks][j]);
        }
        waitcnt_lgkm0();                 // reads retired before others' stages can overwrite
        __builtin_amdgcn_s_barrier();    // all waves done reading buf[cur]
        if (t + 2 < nt) {
            stage(cur, (t + 2) << 6);    // issue early: overlaps with MFMA below
            __builtin_amdgcn_sched_barrier(0);
        }
#pragma unroll
        for (int ks = 0; ks < 2; ks++)
#pragma unroll
            for (int i = 0; i < FI; i++)
#pragma unroll
                for (int j = 0; j < FJ; j++)
                    acc[i][j] = __builtin_amdgcn_mfma_f32_16x16x32_bf16(af[ks][i], bfv[ks][j], acc[i][j], 0, 0, 0);
        __builtin_amdgcn_sched_barrier(0);
        if (t + 2 < nt) waitcnt_vm<L>();        // t+1 complete, t+2 in flight
        else if (t + 1 < nt) waitcnt_vm<0>();   // last prefetched tile complete
        __builtin_amdgcn_s_barrier();
        __builtin_amdgcn_sched_barrier(0);
        cur ^= 1;
    }

    // C/D layout: col = lane&15, row = (lane>>4)*4 + reg
#pragma unroll
    for (int i = 0; i < FI; i++) {
        int rbase = row0 + wr * (BM / 2) + i * 16 + (lane >> 4) * 4;
#pragma unroll
        for (int j = 0; j < FJ; j++) {
            int c = col0 + wc * (BN / 2) + j * 16 + (lane & 15);
#pragma unroll
            for (int r = 0; r < 4; r++) {
                int rg = rbase + r;
                size_t off = (size_t)rg * Nc + c;
                float v = acc[i][j][r];
                if (EPI == 0) {
                    if (bias) v += bias[c];
                    if (resf) v += resf[RS ? stroff(rg, c, Nc) : off];
                    if (resb) v += bf2f(resb[off]);
                    if (Cf) { if (OS) Cf[stroff(rg, c, Nc)] = v; else Cf[off] = v; }
                    if (Cb) Cb[off] = f2bf(v);
                } else if (EPI == 1) {
                    v += bias[c];
                    float cdf = 0.5f * (1.0f + erff(v * 0.70710678118654752f));
                    Cb[off] = f2bf(v * cdf);
                    aux[off] = f2bf(cdf + v * 0.39894228040143267f * expf(-0.5f * v * v));
                } else {
                    Cb[off] = f2bf(v * bf2f(aux[(size_t)(rg & (BS_ - 1)) * Nc + c]));
                }
            }
        }
    }
}

// ---------------- MFMA QK^T: single-shot BK=64 (K=HD), XOR-swizzled ----------------
template <bool TAN>
__global__ __launch_bounds__(256) void attn_qk_mfma(const ushort* __restrict__ qkvb,
                                                    const ushort* __restrict__ dqkvp,
                                                    ushort* __restrict__ sc) {
    int work = xcd_swz(blockIdx.x, gridDim.x);
    constexpr int NT = S_ / 128;  // 4
    int mz = work / (BH_ * NT * NT);
    int rem = work % (BH_ * NT * NT);
    int bh = rem / (NT * NT);
    int r2 = rem % (NT * NT);
    int q0 = (r2 / NT) * 128, kc0 = (r2 % NT) * 128;
    int b = bh / H_, hh = bh - b * H_;
    const size_t qoff = (size_t)b * S_ * 3 * D_ + hh * HD_;
    const int ld = 3 * D_;
    const ushort* dqkv = TAN ? dqkvp + (size_t)mz * BS3D_ : nullptr;
    __shared__ ushort As[128 * 64];
    __shared__ ushort Bs[128 * 64];
    __shared__ ushort dAs[TAN ? 128 * 64 : 1];
    __shared__ ushort dBs[TAN ? 128 * 64 : 1];
    int tid = threadIdx.x;
    int wave = tid >> 6, lane = tid & 63;
    int wr = wave >> 1, wc = wave & 1;

    int srow = lane >> 3;
    int skel = ((lane & 7) ^ (lane >> 3)) * 8;
    const ushort* Ag0 = qkvb + qoff + (size_t)(q0 + srow) * ld + skel;
    const ushort* Bg0 = qkvb + qoff + D_ + (size_t)(kc0 + srow) * ld + skel;

#pragma unroll
    for (int cc = 0; cc < 4; cc++) {
        int c = wave * 4 + cc;
        gll16(Ag0 + (size_t)(c * 8) * ld, As + c * 512);
        gll16(Bg0 + (size_t)(c * 8) * ld, Bs + c * 512);
        if (TAN) {
            gll16(dqkv + qoff + (size_t)(q0 + c * 8 + srow) * ld + skel, dAs + c * 512);
            gll16(dqkv + qoff + D_ + (size_t)(kc0 + c * 8 + srow) * ld + skel, dBs + c * 512);
        }
    }
    __syncthreads();

    int frow = lane & 15, fkb = (lane >> 4) * 8;
    f32x4 acc[4][4] = {};
#pragma unroll
    for (int ks = 0; ks < 2; ks++) {
        int sw = (fkb + ks * 32) ^ ((frow & 7) * 8);
        bf16x8 af[4], bfv[4];
#pragma unroll
        for (int i = 0; i < 4; i++) af[i] = *(const bf16x8*)(As + (wr * 64 + i * 16 + frow) * 64 + sw);
#pragma unroll
        for (int j = 0; j < 4; j++) bfv[j] = *(const bf16x8*)(Bs + (wc * 64 + j * 16 + frow) * 64 + sw);
        if (!TAN) {
#pragma unroll
            for (int i = 0; i < 4; i++)
#pragma unroll
                for (int j = 0; j < 4; j++)
                    acc[i][j] = __builtin_amdgcn_mfma_f32_16x16x32_bf16(af[i], bfv[j], acc[i][j], 0, 0, 0);
        } else {
            bf16x8 daf[4], dbf[4];
#pragma unroll
            for (int i = 0; i < 4; i++) daf[i] = *(const bf16x8*)(dAs + (wr * 64 + i * 16 + frow) * 64 + sw);
#pragma unroll
            for (int j = 0; j < 4; j++) dbf[j] = *(const bf16x8*)(dBs + (wc * 64 + j * 16 + frow) * 64 + sw);
#pragma unroll
            for (int i = 0; i < 4; i++)
#pragma unroll
                for (int j = 0; j < 4; j++) {
                    acc[i][j] = __builtin_amdgcn_mfma_f32_16x16x32_bf16(daf[i], bfv[j], acc[i][j], 0, 0, 0);
                    acc[i][j] = __builtin_amdgcn_mfma_f32_16x16x32_bf16(af[i], dbf[j], acc[i][j], 0, 0, 0);
                }
        }
    }

    ushort* scm = sc + (size_t)mz * ATT_;
#pragma unroll
    for (int i = 0; i < 4; i++) {
        int rbase = q0 + wr * 64 + i * 16 + (lane >> 4) * 4;
#pragma unroll
        for (int j = 0; j < 4; j++) {
            int c = kc0 + wc * 64 + j * 16 + (lane & 15);
#pragma unroll
            for (int r = 0; r < 4; r++)
                scm[((size_t)bh * S_ + rbase + r) * S_ + c] = f2bf(acc[i][j][r] * SCALE_);
        }
    }
}

// ---------------- primal P@V: BK=64, XOR-swizzled ----------------
__global__ __launch_bounds__(256) void attn_av_p(const ushort* __restrict__ Pb,
                                                 const ushort* __restrict__ Vt,
                                                 ushort* __restrict__ outp) {
    int work = xcd_swz(blockIdx.x, gridDim.x);
    constexpr int NT = S_ / 128;  // 4
    int bh = work / NT;
    int q0 = (work % NT) * 128;
    int b = bh / H_, hh = bh - b * H_;
    const ushort* Pg = Pb + (size_t)bh * S_ * S_;
    const ushort* Vg = Vt + (size_t)bh * HD_ * S_;
    __shared__ ushort As[128 * 64];
    __shared__ ushort Bs[64 * 64];
    int tid = threadIdx.x;
    int wave = tid >> 6, lane = tid & 63;
    int wr = wave >> 1, wc = wave & 1;
    int srow = lane >> 3;
    int skel = ((lane & 7) ^ (lane >> 3)) * 8;
    int frow = lane & 15, fkb = (lane >> 4) * 8;

    f32x4 acc[4][2] = {};
    for (int k0 = 0; k0 < S_; k0 += 64) {
#pragma unroll
        for (int cc = 0; cc < 4; cc++) {
            int c = wave * 4 + cc;
            gll16(Pg + (size_t)(q0 + c * 8 + srow) * S_ + k0 + skel, As + c * 512);
        }
#pragma unroll
        for (int cc = 0; cc < 2; cc++) {
            int c = wave * 2 + cc;
            gll16(Vg + (size_t)(c * 8 + srow) * S_ + k0 + skel, Bs + c * 512);
        }
        __syncthreads();
#pragma unroll
        for (int ks = 0; ks < 2; ks++) {
            int sw = (fkb + ks * 32) ^ ((frow & 7) * 8);
            bf16x8 af[4], bfv[2];
#pragma unroll
            for (int i = 0; i < 4; i++) af[i] = *(const bf16x8*)(As + (wr * 64 + i * 16 + frow) * 64 + sw);
#pragma unroll
            for (int j = 0; j < 2; j++) bfv[j] = *(const bf16x8*)(Bs + (wc * 32 + j * 16 + frow) * 64 + sw);
#pragma unroll
            for (int i = 0; i < 4; i++)
#pragma unroll
                for (int j = 0; j < 2; j++)
                    acc[i][j] = __builtin_amdgcn_mfma_f32_16x16x32_bf16(af[i], bfv[j], acc[i][j], 0, 0, 0);
        }
        __syncthreads();
    }

#pragma unroll
    for (int i = 0; i < 4; i++) {
        int rbase = q0 + wr * 64 + i * 16 + (lane >> 4) * 4;
#pragma unroll
        for (int j = 0; j < 2; j++) {
            int c = hh * HD_ + wc * 32 + j * 16 + (lane & 15);
#pragma unroll
            for (int r = 0; r < 4; r++)
                outp[(size_t)(b * S_ + rbase + r) * D_ + c] = f2bf(acc[i][j][r]);
        }
    }
}

// ---------------- FUSED tangent P@V (single pass, 128 q-rows): dO = (P.D)@V + P@dV - s*O ----
__global__ __launch_bounds__(256) void attn_av_tan(const ushort* __restrict__ Pb,
                                                   const ushort* __restrict__ dscp,
                                                   const ushort* __restrict__ Vt,
                                                   const ushort* __restrict__ dVtp,
                                                   const ushort* __restrict__ Ob,
                                                   ushort* __restrict__ outp) {
    int work = xcd_swz(blockIdx.x, gridDim.x);
    int mz = work / (BH_ * 4);
    int rem = work % (BH_ * 4);
    int bh = rem / 4;
    int q0 = (rem % 4) * 128;
    int b = bh / H_, hh = bh - b * H_;
    const ushort* Pg = Pb + (size_t)bh * S_ * S_;
    const ushort* Dg = dscp + (size_t)mz * ATT_ + (size_t)bh * S_ * S_;
    const ushort* Vg = Vt + (size_t)bh * HD_ * S_;
    const ushort* dVg = dVtp + (size_t)mz * BSD_ + (size_t)bh * HD_ * S_;
    ushort* outm = outp + (size_t)mz * BSD_;
    __shared__ ushort Ps[128 * 64], Ds[128 * 64], Vs[64 * 64], dVs[64 * 64];  // 48 KB
    int tid = threadIdx.x;
    int wave = tid >> 6, lane = tid & 63;
    int wr = wave >> 1, wc = wave & 1;
    int srow = lane >> 3;
    int skel = ((lane & 7) ^ (lane >> 3)) * 8;
    int frow = lane & 15, fkb = (lane >> 4) * 8;
    int aoff[2][4], boff[2][2];
#pragma unroll
    for (int ks = 0; ks < 2; ks++) {
        int sw = (fkb + ks * 32) ^ ((frow & 7) * 8);
#pragma unroll
        for (int i = 0; i < 4; i++) aoff[ks][i] = (wr * 64 + i * 16 + frow) * 64 + sw;
#pragma unroll
        for (int j = 0; j < 2; j++) boff[ks][j] = (wc * 32 + j * 16 + frow) * 64 + sw;
    }

    float s[4] = {0.f, 0.f, 0.f, 0.f};
    f32x4 acc[4][2] = {};

    for (int k0 = 0; k0 < S_; k0 += 64) {
#pragma unroll
        for (int cc = 0; cc < 4; cc++) {
            int c = wave * 4 + cc;
            gll16(Pg + (size_t)(q0 + c * 8 + srow) * S_ + k0 + skel, Ps + c * 512);
            gll16(Dg + (size_t)(q0 + c * 8 + srow) * S_ + k0 + skel, Ds + c * 512);
        }
#pragma unroll
        for (int cc = 0; cc < 2; cc++) {
            int c = wave * 2 + cc;
            gll16(Vg + (size_t)(c * 8 + srow) * S_ + k0 + skel, Vs + c * 512);
            gll16(dVg + (size_t)(c * 8 + srow) * S_ + k0 + skel, dVs + c * 512);
        }
        __syncthreads();
#pragma unroll
        for (int ks = 0; ks < 2; ks++) {
            bf16x8 p8[4], pq8[4], v8[2], dv8[2];
#pragma unroll
            for (int i = 0; i < 4; i++) {
                p8[i] = *(const bf16x8*)(Ps + aoff[ks][i]);
                bf16x8 d8 = *(const bf16x8*)(Ds + aoff[ks][i]);
#pragma unroll
                for (int e = 0; e < 8; e++) {
                    float pd = bf2f((ushort)p8[i][e]) * bf2f((ushort)d8[e]);
                    s[i] += pd;
                    pq8[i][e] = (short)f2bf(pd);
                }
            }
#pragma unroll
            for (int j = 0; j < 2; j++) {
                v8[j] = *(const bf16x8*)(Vs + boff[ks][j]);
                dv8[j] = *(const bf16x8*)(dVs + boff[ks][j]);
            }
#pragma unroll
            for (int i = 0; i < 4; i++)
#pragma unroll
                for (int j = 0; j < 2; j++) {
                    acc[i][j] = __builtin_amdgcn_mfma_f32_16x16x32_bf16(pq8[i], v8[j], acc[i][j], 0, 0, 0);
                    acc[i][j] = __builtin_amdgcn_mfma_f32_16x16x32_bf16(p8[i], dv8[j], acc[i][j], 0, 0, 0);
                }
        }
        __syncthreads();
    }

    // complete rowsums: lanes {l, l^16, l^32, l^48} hold the 4 k-slices of row (.. + frow)
#pragma unroll
    for (int i = 0; i < 4; i++) {
        s[i] += __shfl_xor(s[i], 16);
        s[i] += __shfl_xor(s[i], 32);
    }

    // epilogue: out = acc - s[row]*O[row][col]
#pragma unroll
    for (int i = 0; i < 4; i++) {
        int rbase = q0 + wr * 64 + i * 16 + (lane >> 4) * 4;
#pragma unroll
        for (int r = 0; r < 4; r++) {
            float sc = __shfl(s[i], ((lane >> 4) << 2) + r);
#pragma unroll
            for (int j = 0; j < 2; j++) {
                int c = hh * HD_ + wc * 32 + j * 16 + (lane & 15);
                float o = bf2f(Ob[(size_t)(b * S_ + rbase + r) * D_ + c]);
                outm[(size_t)(b * S_ + rbase + r) * D_ + c] = f2bf(acc[i][j][r] - sc * o);
            }
        }
    }
}

// ---------------- softmax: bf16 scores -> bf16 probs ----------------
__global__ __launch_bounds__(256) void softmax_rows(const ushort* __restrict__ sc,
                                                    ushort* __restrict__ scb) {
    size_t row = blockIdx.x;
    const ushort* p = sc + row * S_;
    int tid = threadIdx.x;
    ushort2 vu = *(const ushort2*)&p[tid * 2];
    float v0 = bf2f(vu.x), v1 = bf2f(vu.y);
    float mx = block_max(fmaxf(v0, v1));
    float e0 = expf(v0 - mx), e1 = expf(v1 - mx);
    float s = block_sum(e0 + e1);
    float inv = 1.0f / s;
    ushort2 ob; ob.x = f2bf(e0 * inv); ob.y = f2bf(e1 * inv);
    *(ushort2*)&scb[row * S_ + tid * 2] = ob;
}

// ---------------- host ----------------
extern "C" void kernel_launch(void* const* d_in, const int* in_sizes, int n_in,
                              void* d_out, int out_size, void* d_ws, size_t ws_size,
                              hipStream_t stream) {
    const float* x = (const float*)d_in[0];
    const float* xt = (const float*)d_in[1];
    const float* g1 = (const float*)d_in[2];
    const float* b1 = (const float*)d_in[3];
    const float* Wqkv = (const float*)d_in[4];
    const float* Wproj = (const float*)d_in[5];
    const float* bproj = (const float*)d_in[6];
    const float* g2 = (const float*)d_in[7];
    const float* b2 = (const float*)d_in[8];
    const float* W1 = (const float*)d_in[9];
    const float* bf1 = (const float*)d_in[10];
    const float* W2 = (const float*)d_in[11];
    const float* bf2 = (const float*)d_in[12];
    float* out = (float*)d_out;
    float* out_t = out + BSD_;   // [B,M,S,D]

    char* wp = (char*)d_ws;
    auto alloc = [&](size_t bytes) { void* p = wp; wp += (bytes + 255) & ~(size_t)255; return p; };
    ushort* xhat1 = (ushort*)alloc(BSD_ * 2);
    ushort* hb5 = (ushort*)alloc(5 * BSD_ * 2);    // [5*BS][D]: slice0 = h, slices1-4 = dh
    ushort* obb = (ushort*)alloc(BSD_ * 2);
    float* x2 = (float*)alloc(BSD_ * 4);
    ushort* xhat2 = (ushort*)alloc(BSD_ * 2);
    ushort* h2b = (ushort*)alloc(BSD_ * 2);
    ushort* dx2b = (ushort*)alloc(4 * BSD_ * 2);   // [4*BS][D] bf16
    ushort* xt_b = (ushort*)alloc(4 * BSD_ * 2);   // compact bf16 copy of x_tangent
    ushort* Vt = (ushort*)alloc(BSD_ * 2);
    ushort* dscb2 = (ushort*)alloc(2 * ATT_ * 2);  // [2][BH,S,S]
    ushort* attnb = (ushort*)alloc(ATT_ * 2);      // primal probs bf16
    ushort* gpb = (ushort*)alloc(BSF_ * 2);        // gelu'(u) bf16
    float* rstd1 = (float*)alloc(BS_ * 4);
    float* rstd2 = (float*)alloc(BS_ * 4);
    ushort* WqkvT = (ushort*)alloc((size_t)D_ * 3 * D_ * 2);
    ushort* WprojT = (ushort*)alloc((size_t)D_ * D_ * 2);
    ushort* W1T = (ushort*)alloc((size_t)DFF_ * D_ * 2);
    ushort* W2T = (ushort*)alloc((size_t)D_ * DFF_ * 2);
    // Region A (50.3 MB): phase1 {qkv5 = [5][B,S,3D] 47.2 MB}, phase2 {da4 50.3 MB}
    char* regA = (char*)alloc(4 * BSF_ * 2);
    ushort* qkv5 = (ushort*)regA;
    ushort* da4 = (ushort*)regA;
    ushort* dVt4 = (ushort*)alloc(4 * BSD_ * 2);   // [4][bh][HD][S]
    // Region B (12.6 MB): {ab} -> {dob4} -> {dh2_4}
    char* regB = (char*)alloc(4 * BSD_ * 2);
    ushort* ab = (ushort*)regB;
    ushort* dob4 = (ushort*)regB;
    ushort* dh2_4 = (ushort*)regB;

    // ---- weights -> bf16 transposed [N][K] ----
    transpose_f2b<<<dim3(3 * D_ / 32, D_ / 32), 256, 0, stream>>>(Wqkv, WqkvT, D_, 3 * D_);
    transpose_f2b<<<dim3(D_ / 32, D_ / 32), 256, 0, stream>>>(Wproj, WprojT, D_, D_);
    transpose_f2b<<<dim3(DFF_ / 32, D_ / 32), 256, 0, stream>>>(W1, W1T, D_, DFF_);
    transpose_f2b<<<dim3(D_ / 32, DFF_ / 32), 256, 0, stream>>>(W2, W2T, DFF_, D_);

    // ---- LN fwd + batched LN-JVP, then ONE merged qkv GEMM over [h; dh x4] (M=10240) ----
    ln_fwd<<<BS_, 256, 0, stream>>>(x, g1, b1, xhat1, hb5, rstd1);
    ln_jvp<<<4 * BS_, 256, 0, stream>>>(xt, nullptr, 0, xhat1, rstd1, g1, hb5 + BSD_, xt_b);
    gemm_mfma<128, 128, 0, false, false><<<dim3(3 * D_ / 128, 5 * BS_ / 128), 256, 0, stream>>>(
        hb5, WqkvT, nullptr, nullptr, nullptr, nullptr, qkv5, nullptr, 3 * D_, D_);
    transpose_v<<<dim3(S_ / 32, HD_ / 32, 5 * BH_), 256, 0, stream>>>(qkv5, Vt, dVt4);

    // ---- primal attention + MLP ----
    attn_qk_mfma<false><<<(S_ / 128) * (S_ / 128) * BH_, 256, 0, stream>>>(qkv5, nullptr, dscb2);
    softmax_rows<<<BH_ * S_, 256, 0, stream>>>(dscb2, attnb);
    attn_av_p<<<(S_ / 128) * BH_, 256, 0, stream>>>(attnb, Vt, obb);
    gemm_mfma<64, 64, 0, false, false><<<dim3(D_ / 64, BS_ / 64), 256, 0, stream>>>(
        obb, WprojT, bproj, x, nullptr, x2, nullptr, nullptr, D_, D_);
    ln_fwd<<<BS_, 256, 0, stream>>>(x2, g2, b2, xhat2, h2b, rstd2);
    gemm_mfma<128, 128, 1, false, false><<<dim3(DFF_ / 128, BS_ / 128), 256, 0, stream>>>(
        h2b, W1T, bf1, nullptr, nullptr, nullptr, ab, gpb, DFF_, D_);
    gemm_mfma<64, 64, 0, false, false><<<dim3(D_ / 64, BS_ / 64), 256, 0, stream>>>(
        ab, W2T, bf2, x2, nullptr, out, nullptr, nullptr, D_, DFF_);

    // ---- tangent attention (pair-batched) + linear stages ----
    const ushort* dqkv4 = qkv5 + BS3D_;  // slices 1-4
    for (int p = 0; p < 2; p++) {
        attn_qk_mfma<true><<<2 * (S_ / 128) * (S_ / 128) * BH_, 256, 0, stream>>>(
            qkv5, dqkv4 + (size_t)p * 2 * BS3D_, dscb2);
        attn_av_tan<<<2 * 4 * BH_, 256, 0, stream>>>(
            attnb, dscb2, Vt, dVt4 + (size_t)p * 2 * BSD_, obb, dob4 + (size_t)p * 2 * BSD_);
    }
    gemm_mfma<128, 64, 0, false, false><<<dim3(D_ / 64, 4 * BS_ / 128), 256, 0, stream>>>(
        dob4, WprojT, nullptr, nullptr, xt_b, nullptr, dx2b, nullptr, D_, D_);
    ln_jvp<<<4 * BS_, 256, 0, stream>>>(nullptr, dx2b, 1, xhat2, rstd2, g2, dh2_4, nullptr);
    gemm_mfma<128, 128, 2, false, false><<<dim3(DFF_ / 128, 4 * BS_ / 128), 256, 0, stream>>>(
        dh2_4, W1T, nullptr, nullptr, nullptr, nullptr, da4, gpb, DFF_, D_);
    gemm_mfma<128, 64, 0, false, true><<<dim3(D_ / 64, 4 * BS_ / 128), 256, 0, stream>>>(
        da4, W2T, nullptr, nullptr, dx2b, out_t, nullptr, nullptr, D_, DFF_);
}

// Round 17
// 435.453 us; speedup vs baseline: 1.1773x; 1.0192x over previous
//
#include <hip/hip_runtime.h>
#include <math.h>

constexpr int B_ = 4, S_ = 512, D_ = 768, H_ = 12, M_ = 4, DFF_ = 3072, HD_ = 64;
constexpr float EPS_ = 1e-6f;
constexpr float SCALE_ = 0.125f;  // HD^-0.5
constexpr int BS_ = B_ * S_;
constexpr int BH_ = B_ * H_;
constexpr long long BSD_ = (long long)BS_ * D_;
constexpr long long BS3D_ = (long long)BS_ * 3 * D_;
constexpr long long ATT_ = (long long)BH_ * S_ * S_;
constexpr long long BSF_ = (long long)BS_ * DFF_;

typedef __attribute__((ext_vector_type(8))) short bf16x8;
typedef __attribute__((ext_vector_type(4))) float f32x4;

__device__ __forceinline__ ushort f2bf(float f) {
    uint32_t u = __float_as_uint(f);
    u += 0x7FFF + ((u >> 16) & 1);
    return (ushort)(u >> 16);
}
__device__ __forceinline__ float bf2f(ushort u) {
    return __uint_as_float((uint32_t)u << 16);
}

__device__ __forceinline__ void gll16(const ushort* g, ushort* l) {
    __builtin_amdgcn_global_load_lds((const __attribute__((address_space(1))) void*)g,
                                     (__attribute__((address_space(3))) void*)l, 16, 0, 0);
}

// counted vmcnt wait (literal required in asm)
template <int N> __device__ __forceinline__ void waitcnt_vm() {
    if constexpr (N == 0) asm volatile("s_waitcnt vmcnt(0)" ::: "memory");
    else if constexpr (N == 4) asm volatile("s_waitcnt vmcnt(4)" ::: "memory");
    else if constexpr (N == 6) asm volatile("s_waitcnt vmcnt(6)" ::: "memory");
    else if constexpr (N == 8) asm volatile("s_waitcnt vmcnt(8)" ::: "memory");
    else static_assert(N == 0 || N == 4 || N == 6 || N == 8, "add literal");
}

__device__ __forceinline__ void waitcnt_lgkm0() {
    asm volatile("s_waitcnt lgkmcnt(0)" ::: "memory");
    __builtin_amdgcn_sched_barrier(0);  // rule 18: fence MFMA/reg-op hoisting
}

// XCD-chunked bijective block remap (m204)
__device__ __forceinline__ int xcd_swz(int flat, int nwg) {
    int q = nwg >> 3, r = nwg & 7;
    int x = flat & 7, pos = flat >> 3;
    int base = (x < r) ? x * (q + 1) : r * (q + 1) + (x - r) * q;
    return base + pos;
}

// batched-row (rg in [0,8192)) -> [B,M,S,Nc] offset
__device__ __forceinline__ size_t stroff(int rg, int c, int Nc) {
    int m = rg >> 11;
    int b = (rg >> 9) & (B_ - 1);
    int s = rg & (S_ - 1);
    return ((size_t)((b * M_ + m) * S_ + s)) * Nc + c;
}

// ---------------- block reductions (256 threads = 4 waves) ----------------
__device__ __forceinline__ float block_sum(float v) {
    __shared__ float red[4];
    int tid = threadIdx.x;
#pragma unroll
    for (int off = 32; off > 0; off >>= 1) v += __shfl_down(v, off, 64);
    __syncthreads();
    if ((tid & 63) == 0) red[tid >> 6] = v;
    __syncthreads();
    return red[0] + red[1] + red[2] + red[3];
}

__device__ __forceinline__ float block_max(float v) {
    __shared__ float red[4];
    int tid = threadIdx.x;
#pragma unroll
    for (int off = 32; off > 0; off >>= 1) v = fmaxf(v, __shfl_down(v, off, 64));
    __syncthreads();
    if ((tid & 63) == 0) red[tid >> 6] = v;
    __syncthreads();
    return fmaxf(fmaxf(red[0], red[1]), fmaxf(red[2], red[3]));
}

// ---------------- weight transpose+convert: W[K][N] f32 -> WT[N][K] bf16 ----------------
__global__ __launch_bounds__(256) void transpose_f2b(const float* __restrict__ W,
                                                     ushort* __restrict__ WT,
                                                     int K, int N) {
    __shared__ float t[32][33];
    int n0 = blockIdx.x * 32, k0 = blockIdx.y * 32;
    int tx = threadIdx.x & 31, ty = threadIdx.x >> 5;
#pragma unroll
    for (int i = 0; i < 4; i++)
        t[ty + i * 8][tx] = W[(size_t)(k0 + ty + i * 8) * N + n0 + tx];
    __syncthreads();
#pragma unroll
    for (int i = 0; i < 4; i++)
        WT[(size_t)(n0 + ty + i * 8) * K + k0 + tx] = f2bf(t[tx][ty + i * 8]);
}

// ---------------- V transpose: qkv5[5][B,S,3D] bf16 -> m=0: Vt[bh][HD][S]; m>=1: dVt4[m-1] ----
__global__ __launch_bounds__(256) void transpose_v(const ushort* __restrict__ src0,
                                                   ushort* __restrict__ Vt0,
                                                   ushort* __restrict__ dVt4) {
    int z = blockIdx.z;
    int m = z / BH_, bh = z % BH_;
    const ushort* qkvb = src0 + (size_t)m * BS3D_;
    ushort* Vt = (m == 0) ? Vt0 : dVt4 + (size_t)(m - 1) * BSD_;
    int b = bh / H_, hh = bh - b * H_;
    int s0 = blockIdx.x * 32, d0 = blockIdx.y * 32;
    __shared__ ushort t[32][33];
    int tx = threadIdx.x & 31, ty = threadIdx.x >> 5;
#pragma unroll
    for (int i = 0; i < 4; i++)
        t[ty + i * 8][tx] = qkvb[(size_t)(b * S_ + s0 + ty + i * 8) * 3 * D_ + 2 * D_ + hh * HD_ + d0 + tx];
    __syncthreads();
#pragma unroll
    for (int i = 0; i < 4; i++)
        Vt[(size_t)bh * HD_ * S_ + (size_t)(d0 + ty + i * 8) * S_ + s0 + tx] = t[tx][ty + i * 8];
}

// ---------------- LayerNorm forward: input f32 (xf) or bf16 (xb); out xhat bf16, h bf16 ----
__global__ __launch_bounds__(256) void ln_fwd(const float* __restrict__ xf,
                                              const ushort* __restrict__ xb,
                                              const float* __restrict__ g,
                                              const float* __restrict__ bta,
                                              ushort* __restrict__ xhat,
                                              ushort* __restrict__ h,
                                              float* __restrict__ rstd) {
    int row = blockIdx.x;
    size_t base = (size_t)row * D_;
    int tid = threadIdx.x;
    float v[3];
    float s = 0.f;
#pragma unroll
    for (int i = 0; i < 3; i++) {
        int c = tid + i * 256;
        v[i] = xf ? xf[base + c] : bf2f(xb[base + c]);
        s += v[i];
    }
    s = block_sum(s);
    float mu = s * (1.0f / D_);
    float vs = 0.f;
#pragma unroll
    for (int i = 0; i < 3; i++) { float c = v[i] - mu; vs += c * c; }
    vs = block_sum(vs);
    float rs = rsqrtf(vs * (1.0f / D_) + EPS_);
#pragma unroll
    for (int i = 0; i < 3; i++) {
        int c = tid + i * 256;
        float xh = (v[i] - mu) * rs;
        xhat[base + c] = f2bf(xh);
        h[base + c] = f2bf(xh * g[c] + bta[c]);
    }
    if (tid == 0) rstd[row] = rs;
}

// ---------------- batched LayerNorm JVP: grid 4*BS_ rows ----------------
// mode 0: tf strided [B,M,S,D] f32 (also emits xtb bf16 compact copy); mode 1: tb bf16 compact
__global__ __launch_bounds__(256) void ln_jvp(const float* __restrict__ tf,
                                              const ushort* __restrict__ tb, int mode,
                                              const ushort* __restrict__ xhat,
                                              const float* __restrict__ rstd,
                                              const float* __restrict__ g,
                                              ushort* __restrict__ dh,
                                              ushort* __restrict__ xtb) {
    int rg = blockIdx.x;
    int r = rg & (BS_ - 1);
    size_t pbase = (size_t)r * D_;
    int tid = threadIdx.x;
    float tv[3], xh[3];
    float s1 = 0.f, s2 = 0.f;
    size_t tbase;
    if (mode == 0) {
        int m = rg >> 11;
        int b = r >> 9, s = r & (S_ - 1);
        tbase = ((size_t)((b * M_ + m) * S_ + s)) * D_;
    } else {
        tbase = (size_t)rg * D_;
    }
#pragma unroll
    for (int i = 0; i < 3; i++) {
        int c = tid + i * 256;
        tv[i] = (mode == 0) ? tf[tbase + c] : bf2f(tb[tbase + c]);
        xh[i] = bf2f(xhat[pbase + c]);
        s1 += tv[i];
        s2 += tv[i] * xh[i];
    }
    s1 = block_sum(s1);
    s2 = block_sum(s2);
    float mt = s1 * (1.0f / D_);
    float mx = s2 * (1.0f / D_);
    float rs = rstd[r];
#pragma unroll
    for (int i = 0; i < 3; i++) {
        int c = tid + i * 256;
        dh[(size_t)rg * D_ + c] = f2bf(g[c] * rs * (tv[i] - mt - xh[i] * mx));
        if (mode == 0 && xtb) xtb[(size_t)rg * D_ + c] = f2bf(tv[i]);
    }
}

// ---------------- bf16 MFMA GEMM <BM,BN>, BK=64, 2-deep pipeline, stage-early ----------------
// EPI 0: Cb = bf16(acc)                       (merged qkv)
// EPI 1: u = acc + bias; Cb = bf16(gelu(u)); aux = bf16(gelu'(u))   (W1 primal)
// EPI 2: Cb = bf16(acc * bf2f(aux[rg mod BS]))                       (W1 tangent)
// EPI 4: merged W2: rg<BS: v+=bias+bf2f(resb); Cf[off]=v
//                   rg>=BS: v+=bf2f(resb2[rg2]); Cf2[stroff(rg2)]=v
// EPI 5: merged proj: rg<BS: v+=bias+resf[off]; Cb[off]=bf16(v)
//                     rg>=BS: v+=bf2f(resb[rg2]); aux[rg2]=bf16(v)
template <int BM, int BN, int EPI>
__global__ __launch_bounds__(256) void gemm_mfma(const ushort* __restrict__ A,
                                                 const ushort* __restrict__ BT,
                                                 const float* __restrict__ bias,
                                                 const float* __restrict__ resf,
                                                 const ushort* __restrict__ resb,
                                                 const ushort* __restrict__ resb2,
                                                 float* __restrict__ Cf,
                                                 float* __restrict__ Cf2,
                                                 ushort* __restrict__ Cb,
                                                 ushort* __restrict__ aux,
                                                 int Nc, int Kd) {
    constexpr int FI = BM / 32, FJ = BN / 32;
    constexpr int LA = BM / 32, LB = BN / 32, L = LA + LB;
    __shared__ ushort As[2][BM * 64];
    __shared__ ushort Bs[2][BN * 64];
    int tid = threadIdx.x;
    int wave = tid >> 6, lane = tid & 63;
    int wr = wave >> 1, wc = wave & 1;
    int gx = gridDim.x, nwg = gx * gridDim.y;
    int work = xcd_swz(blockIdx.x + blockIdx.y * gx, nwg);
    // band remap: 8 row-panels per band, col-major inside (L2 anti-thrash); gy%8==0 required
    int band = work / (8 * gx);
    int wi = work - band * (8 * gx);
    int row0 = (band * 8 + (wi & 7)) * BM;
    int col0 = (wi >> 3) * BN;

    int srow = lane >> 3;
    int skel = ((lane & 7) ^ (lane >> 3)) * 8;
    const ushort* Ag0 = A + (size_t)(row0 + srow) * Kd + skel;
    const ushort* Bg0 = BT + (size_t)(col0 + srow) * Kd + skel;

    auto stage = [&](int bufi, int k0) {
#pragma unroll
        for (int cc = 0; cc < LA; cc++) {
            int c = wave * LA + cc;
            gll16(Ag0 + (size_t)(c * 8) * Kd + k0, As[bufi] + c * 512);
        }
#pragma unroll
        for (int cc = 0; cc < LB; cc++) {
            int c = wave * LB + cc;
            gll16(Bg0 + (size_t)(c * 8) * Kd + k0, Bs[bufi] + c * 512);
        }
    };

    int frow = lane & 15, fkb = (lane >> 4) * 8;
    int aoff[2][FI], boff[2][FJ];
#pragma unroll
    for (int ks = 0; ks < 2; ks++) {
        int sw = (fkb + ks * 32) ^ ((frow & 7) * 8);
#pragma unroll
        for (int i = 0; i < FI; i++) aoff[ks][i] = (wr * (BM / 2) + i * 16 + frow) * 64 + sw;
#pragma unroll
        for (int j = 0; j < FJ; j++) boff[ks][j] = (wc * (BN / 2) + j * 16 + frow) * 64 + sw;
    }

    f32x4 acc[FI][FJ] = {};

    int nt = Kd >> 6;
    stage(0, 0);
    if (nt > 1) { stage(1, 64); waitcnt_vm<L>(); }
    else        { waitcnt_vm<0>(); }
    __builtin_amdgcn_s_barrier();
    __builtin_amdgcn_sched_barrier(0);

    int cur = 0;
    for (int t = 0; t < nt; t++) {
        bf16x8 af[2][FI], bfv[2][FJ];
        const ushort* Ab = As[cur];
        const ushort* Bb = Bs[cur];
#pragma unroll
        for (int ks = 0; ks < 2; ks++) {
#pragma unroll
            for (int i = 0; i < FI; i++) af[ks][i] = *(const bf16x8*)(Ab + aoff[ks][i]);
#pragma unroll
            for (int j = 0; j < FJ; j++) bfv[ks][j] = *(const bf16x8*)(Bb + boff[ks][j]);
        }
        waitcnt_lgkm0();                 // reads retired before others' stages can overwrite
        __builtin_amdgcn_s_barrier();    // all waves done reading buf[cur]
        if (t + 2 < nt) {
            stage(cur, (t + 2) << 6);    // issue early: overlaps with MFMA below
            __builtin_amdgcn_sched_barrier(0);
        }
#pragma unroll
        for (int ks = 0; ks < 2; ks++)
#pragma unroll
            for (int i = 0; i < FI; i++)
#pragma unroll
                for (int j = 0; j < FJ; j++)
                    acc[i][j] = __builtin_amdgcn_mfma_f32_16x16x32_bf16(af[ks][i], bfv[ks][j], acc[i][j], 0, 0, 0);
        __builtin_amdgcn_sched_barrier(0);
        if (t + 2 < nt) waitcnt_vm<L>();        // t+1 complete, t+2 in flight
        else if (t + 1 < nt) waitcnt_vm<0>();   // last prefetched tile complete
        __builtin_amdgcn_s_barrier();
        __builtin_amdgcn_sched_barrier(0);
        cur ^= 1;
    }

    // C/D layout: col = lane&15, row = (lane>>4)*4 + reg
#pragma unroll
    for (int i = 0; i < FI; i++) {
        int rbase = row0 + wr * (BM / 2) + i * 16 + (lane >> 4) * 4;
#pragma unroll
        for (int j = 0; j < FJ; j++) {
            int c = col0 + wc * (BN / 2) + j * 16 + (lane & 15);
#pragma unroll
            for (int r = 0; r < 4; r++) {
                int rg = rbase + r;
                size_t off = (size_t)rg * Nc + c;
                float v = acc[i][j][r];
                if (EPI == 0) {
                    Cb[off] = f2bf(v);
                } else if (EPI == 1) {
                    v += bias[c];
                    float cdf = 0.5f * (1.0f + erff(v * 0.70710678118654752f));
                    Cb[off] = f2bf(v * cdf);
                    aux[off] = f2bf(cdf + v * 0.39894228040143267f * expf(-0.5f * v * v));
                } else if (EPI == 2) {
                    Cb[off] = f2bf(v * bf2f(aux[(size_t)(rg & (BS_ - 1)) * Nc + c]));
                } else if (EPI == 4) {
                    if (rg < BS_) {
                        v += bias[c] + bf2f(resb[off]);
                        Cf[off] = v;
                    } else {
                        int rg2 = rg - BS_;
                        v += bf2f(resb2[(size_t)rg2 * Nc + c]);
                        Cf2[stroff(rg2, c, Nc)] = v;
                    }
                } else {  // EPI == 5
                    if (rg < BS_) {
                        v += bias[c] + resf[off];
                        Cb[off] = f2bf(v);
                    } else {
                        int rg2 = rg - BS_;
                        v += bf2f(resb[(size_t)rg2 * Nc + c]);
                        aux[(size_t)rg2 * Nc + c] = f2bf(v);
                    }
                }
            }
        }
    }
}

// ---------------- MFMA QK^T: single-shot BK=64 (K=HD), XOR-swizzled ----------------
template <bool TAN>
__global__ __launch_bounds__(256) void attn_qk_mfma(const ushort* __restrict__ qkvb,
                                                    const ushort* __restrict__ dqkvp,
                                                    ushort* __restrict__ sc) {
    int work = xcd_swz(blockIdx.x, gridDim.x);
    constexpr int NT = S_ / 128;  // 4
    int mz = work / (BH_ * NT * NT);
    int rem = work % (BH_ * NT * NT);
    int bh = rem / (NT * NT);
    int r2 = rem % (NT * NT);
    int q0 = (r2 / NT) * 128, kc0 = (r2 % NT) * 128;
    int b = bh / H_, hh = bh - b * H_;
    const size_t qoff = (size_t)b * S_ * 3 * D_ + hh * HD_;
    const int ld = 3 * D_;
    const ushort* dqkv = TAN ? dqkvp + (size_t)mz * BS3D_ : nullptr;
    __shared__ ushort As[128 * 64];
    __shared__ ushort Bs[128 * 64];
    __shared__ ushort dAs[TAN ? 128 * 64 : 1];
    __shared__ ushort dBs[TAN ? 128 * 64 : 1];
    int tid = threadIdx.x;
    int wave = tid >> 6, lane = tid & 63;
    int wr = wave >> 1, wc = wave & 1;

    int srow = lane >> 3;
    int skel = ((lane & 7) ^ (lane >> 3)) * 8;
    const ushort* Ag0 = qkvb + qoff + (size_t)(q0 + srow) * ld + skel;
    const ushort* Bg0 = qkvb + qoff + D_ + (size_t)(kc0 + srow) * ld + skel;

#pragma unroll
    for (int cc = 0; cc < 4; cc++) {
        int c = wave * 4 + cc;
        gll16(Ag0 + (size_t)(c * 8) * ld, As + c * 512);
        gll16(Bg0 + (size_t)(c * 8) * ld, Bs + c * 512);
        if (TAN) {
            gll16(dqkv + qoff + (size_t)(q0 + c * 8 + srow) * ld + skel, dAs + c * 512);
            gll16(dqkv + qoff + D_ + (size_t)(kc0 + c * 8 + srow) * ld + skel, dBs + c * 512);
        }
    }
    __syncthreads();

    int frow = lane & 15, fkb = (lane >> 4) * 8;
    f32x4 acc[4][4] = {};
#pragma unroll
    for (int ks = 0; ks < 2; ks++) {
        int sw = (fkb + ks * 32) ^ ((frow & 7) * 8);
        bf16x8 af[4], bfv[4];
#pragma unroll
        for (int i = 0; i < 4; i++) af[i] = *(const bf16x8*)(As + (wr * 64 + i * 16 + frow) * 64 + sw);
#pragma unroll
        for (int j = 0; j < 4; j++) bfv[j] = *(const bf16x8*)(Bs + (wc * 64 + j * 16 + frow) * 64 + sw);
        if (!TAN) {
#pragma unroll
            for (int i = 0; i < 4; i++)
#pragma unroll
                for (int j = 0; j < 4; j++)
                    acc[i][j] = __builtin_amdgcn_mfma_f32_16x16x32_bf16(af[i], bfv[j], acc[i][j], 0, 0, 0);
        } else {
            bf16x8 daf[4], dbf[4];
#pragma unroll
            for (int i = 0; i < 4; i++) daf[i] = *(const bf16x8*)(dAs + (wr * 64 + i * 16 + frow) * 64 + sw);
#pragma unroll
            for (int j = 0; j < 4; j++) dbf[j] = *(const bf16x8*)(dBs + (wc * 64 + j * 16 + frow) * 64 + sw);
#pragma unroll
            for (int i = 0; i < 4; i++)
#pragma unroll
                for (int j = 0; j < 4; j++) {
                    acc[i][j] = __builtin_amdgcn_mfma_f32_16x16x32_bf16(daf[i], bfv[j], acc[i][j], 0, 0, 0);
                    acc[i][j] = __builtin_amdgcn_mfma_f32_16x16x32_bf16(af[i], dbf[j], acc[i][j], 0, 0, 0);
                }
        }
    }

    ushort* scm = sc + (size_t)mz * ATT_;
#pragma unroll
    for (int i = 0; i < 4; i++) {
        int rbase = q0 + wr * 64 + i * 16 + (lane >> 4) * 4;
#pragma unroll
        for (int j = 0; j < 4; j++) {
            int c = kc0 + wc * 64 + j * 16 + (lane & 15);
#pragma unroll
            for (int r = 0; r < 4; r++)
                scm[((size_t)bh * S_ + rbase + r) * S_ + c] = f2bf(acc[i][j][r] * SCALE_);
        }
    }
}

// ---------------- primal P@V: BK=64, XOR-swizzled ----------------
__global__ __launch_bounds__(256) void attn_av_p(const ushort* __restrict__ Pb,
                                                 const ushort* __restrict__ Vt,
                                                 ushort* __restrict__ outp) {
    int work = xcd_swz(blockIdx.x, gridDim.x);
    constexpr int NT = S_ / 128;  // 4
    int bh = work / NT;
    int q0 = (work % NT) * 128;
    int b = bh / H_, hh = bh - b * H_;
    const ushort* Pg = Pb + (size_t)bh * S_ * S_;
    const ushort* Vg = Vt + (size_t)bh * HD_ * S_;
    __shared__ ushort As[128 * 64];
    __shared__ ushort Bs[64 * 64];
    int tid = threadIdx.x;
    int wave = tid >> 6, lane = tid & 63;
    int wr = wave >> 1, wc = wave & 1;
    int srow = lane >> 3;
    int skel = ((lane & 7) ^ (lane >> 3)) * 8;
    int frow = lane & 15, fkb = (lane >> 4) * 8;

    f32x4 acc[4][2] = {};
    for (int k0 = 0; k0 < S_; k0 += 64) {
#pragma unroll
        for (int cc = 0; cc < 4; cc++) {
            int c = wave * 4 + cc;
            gll16(Pg + (size_t)(q0 + c * 8 + srow) * S_ + k0 + skel, As + c * 512);
        }
#pragma unroll
        for (int cc = 0; cc < 2; cc++) {
            int c = wave * 2 + cc;
            gll16(Vg + (size_t)(c * 8 + srow) * S_ + k0 + skel, Bs + c * 512);
        }
        __syncthreads();
#pragma unroll
        for (int ks = 0; ks < 2; ks++) {
            int sw = (fkb + ks * 32) ^ ((frow & 7) * 8);
            bf16x8 af[4], bfv[2];
#pragma unroll
            for (int i = 0; i < 4; i++) af[i] = *(const bf16x8*)(As + (wr * 64 + i * 16 + frow) * 64 + sw);
#pragma unroll
            for (int j = 0; j < 2; j++) bfv[j] = *(const bf16x8*)(Bs + (wc * 32 + j * 16 + frow) * 64 + sw);
#pragma unroll
            for (int i = 0; i < 4; i++)
#pragma unroll
                for (int j = 0; j < 2; j++)
                    acc[i][j] = __builtin_amdgcn_mfma_f32_16x16x32_bf16(af[i], bfv[j], acc[i][j], 0, 0, 0);
        }
        __syncthreads();
    }

#pragma unroll
    for (int i = 0; i < 4; i++) {
        int rbase = q0 + wr * 64 + i * 16 + (lane >> 4) * 4;
#pragma unroll
        for (int j = 0; j < 2; j++) {
            int c = hh * HD_ + wc * 32 + j * 16 + (lane & 15);
#pragma unroll
            for (int r = 0; r < 4; r++)
                outp[(size_t)(b * S_ + rbase + r) * D_ + c] = f2bf(acc[i][j][r]);
        }
    }
}

// ---------------- FUSED tangent P@V (single pass, 128 q-rows): dO = (P.D)@V + P@dV - s*O ----
__global__ __launch_bounds__(256) void attn_av_tan(const ushort* __restrict__ Pb,
                                                   const ushort* __restrict__ dscp,
                                                   const ushort* __restrict__ Vt,
                                                   const ushort* __restrict__ dVtp,
                                                   const ushort* __restrict__ Ob,
                                                   ushort* __restrict__ outp) {
    int work = xcd_swz(blockIdx.x, gridDim.x);
    int mz = work / (BH_ * 4);
    int rem = work % (BH_ * 4);
    int bh = rem / 4;
    int q0 = (rem % 4) * 128;
    int b = bh / H_, hh = bh - b * H_;
    const ushort* Pg = Pb + (size_t)bh * S_ * S_;
    const ushort* Dg = dscp + (size_t)mz * ATT_ + (size_t)bh * S_ * S_;
    const ushort* Vg = Vt + (size_t)bh * HD_ * S_;
    const ushort* dVg = dVtp + (size_t)mz * BSD_ + (size_t)bh * HD_ * S_;
    ushort* outm = outp + (size_t)mz * BSD_;
    __shared__ ushort Ps[128 * 64], Ds[128 * 64], Vs[64 * 64], dVs[64 * 64];  // 48 KB
    int tid = threadIdx.x;
    int wave = tid >> 6, lane = tid & 63;
    int wr = wave >> 1, wc = wave & 1;
    int srow = lane >> 3;
    int skel = ((lane & 7) ^ (lane >> 3)) * 8;
    int frow = lane & 15, fkb = (lane >> 4) * 8;
    int aoff[2][4], boff[2][2];
#pragma unroll
    for (int ks = 0; ks < 2; ks++) {
        int sw = (fkb + ks * 32) ^ ((frow & 7) * 8);
#pragma unroll
        for (int i = 0; i < 4; i++) aoff[ks][i] = (wr * 64 + i * 16 + frow) * 64 + sw;
#pragma unroll
        for (int j = 0; j < 2; j++) boff[ks][j] = (wc * 32 + j * 16 + frow) * 64 + sw;
    }

    float s[4] = {0.f, 0.f, 0.f, 0.f};
    f32x4 acc[4][2] = {};

    for (int k0 = 0; k0 < S_; k0 += 64) {
#pragma unroll
        for (int cc = 0; cc < 4; cc++) {
            int c = wave * 4 + cc;
            gll16(Pg + (size_t)(q0 + c * 8 + srow) * S_ + k0 + skel, Ps + c * 512);
            gll16(Dg + (size_t)(q0 + c * 8 + srow) * S_ + k0 + skel, Ds + c * 512);
        }
#pragma unroll
        for (int cc = 0; cc < 2; cc++) {
            int c = wave * 2 + cc;
            gll16(Vg + (size_t)(c * 8 + srow) * S_ + k0 + skel, Vs + c * 512);
            gll16(dVg + (size_t)(c * 8 + srow) * S_ + k0 + skel, dVs + c * 512);
        }
        __syncthreads();
#pragma unroll
        for (int ks = 0; ks < 2; ks++) {
            bf16x8 p8[4], pq8[4], v8[2], dv8[2];
#pragma unroll
            for (int i = 0; i < 4; i++) {
                p8[i] = *(const bf16x8*)(Ps + aoff[ks][i]);
                bf16x8 d8 = *(const bf16x8*)(Ds + aoff[ks][i]);
#pragma unroll
                for (int e = 0; e < 8; e++) {
                    float pd = bf2f((ushort)p8[i][e]) * bf2f((ushort)d8[e]);
                    s[i] += pd;
                    pq8[i][e] = (short)f2bf(pd);
                }
            }
#pragma unroll
            for (int j = 0; j < 2; j++) {
                v8[j] = *(const bf16x8*)(Vs + boff[ks][j]);
                dv8[j] = *(const bf16x8*)(dVs + boff[ks][j]);
            }
#pragma unroll
            for (int i = 0; i < 4; i++)
#pragma unroll
                for (int j = 0; j < 2; j++) {
                    acc[i][j] = __builtin_amdgcn_mfma_f32_16x16x32_bf16(pq8[i], v8[j], acc[i][j], 0, 0, 0);
                    acc[i][j] = __builtin_amdgcn_mfma_f32_16x16x32_bf16(p8[i], dv8[j], acc[i][j], 0, 0, 0);
                }
        }
        __syncthreads();
    }

    // complete rowsums: lanes {l, l^16, l^32, l^48} hold the 4 k-slices of row (.. + frow)
#pragma unroll
    for (int i = 0; i < 4; i++) {
        s[i] += __shfl_xor(s[i], 16);
        s[i] += __shfl_xor(s[i], 32);
    }

    // epilogue: out = acc - s[row]*O[row][col]
#pragma unroll
    for (int i = 0; i < 4; i++) {
        int rbase = q0 + wr * 64 + i * 16 + (lane >> 4) * 4;
#pragma unroll
        for (int r = 0; r < 4; r++) {
            float sc = __shfl(s[i], ((lane >> 4) << 2) + r);
#pragma unroll
            for (int j = 0; j < 2; j++) {
                int c = hh * HD_ + wc * 32 + j * 16 + (lane & 15);
                float o = bf2f(Ob[(size_t)(b * S_ + rbase + r) * D_ + c]);
                outm[(size_t)(b * S_ + rbase + r) * D_ + c] = f2bf(acc[i][j][r] - sc * o);
            }
        }
    }
}

// ---------------- softmax: bf16 scores -> bf16 probs ----------------
__global__ __launch_bounds__(256) void softmax_rows(const ushort* __restrict__ sc,
                                                    ushort* __restrict__ scb) {
    size_t row = blockIdx.x;
    const ushort* p = sc + row * S_;
    int tid = threadIdx.x;
    ushort2 vu = *(const ushort2*)&p[tid * 2];
    float v0 = bf2f(vu.x), v1 = bf2f(vu.y);
    float mx = block_max(fmaxf(v0, v1));
    float e0 = expf(v0 - mx), e1 = expf(v1 - mx);
    float s = block_sum(e0 + e1);
    float inv = 1.0f / s;
    ushort2 ob; ob.x = f2bf(e0 * inv); ob.y = f2bf(e1 * inv);
    *(ushort2*)&scb[row * S_ + tid * 2] = ob;
}

// ---------------- host ----------------
extern "C" void kernel_launch(void* const* d_in, const int* in_sizes, int n_in,
                              void* d_out, int out_size, void* d_ws, size_t ws_size,
                              hipStream_t stream) {
    const float* x = (const float*)d_in[0];
    const float* xt = (const float*)d_in[1];
    const float* g1 = (const float*)d_in[2];
    const float* b1 = (const float*)d_in[3];
    const float* Wqkv = (const float*)d_in[4];
    const float* Wproj = (const float*)d_in[5];
    const float* bproj = (const float*)d_in[6];
    const float* g2 = (const float*)d_in[7];
    const float* b2 = (const float*)d_in[8];
    const float* W1 = (const float*)d_in[9];
    const float* bf1 = (const float*)d_in[10];
    const float* W2 = (const float*)d_in[11];
    const float* bf2 = (const float*)d_in[12];
    float* out = (float*)d_out;
    float* out_t = out + BSD_;   // [B,M,S,D]

    char* wp = (char*)d_ws;
    auto alloc = [&](size_t bytes) { void* p = wp; wp += (bytes + 255) & ~(size_t)255; return p; };
    // regBig: [hb5 | ob5 | qkv5] in phase 1; ab5 aliases from base in phase 2.
    // Lifetimes: hb5 dead after merged-qkv; ob5 dead after merged-proj; qkv5 dead after qk-tan.
    // ab5 (5*BSF) written at W1-primal / W1-tan, read by merged-W2 -- all after those deaths.
    char* regBig = (char*)alloc(25 * BSD_ * 2);    // 78.6 MB
    ushort* hb5 = (ushort*)regBig;                 // [5*BS][D]
    ushort* ob5 = (ushort*)(regBig + 5 * BSD_ * 2);  // [5][BS][D]
    ushort* qkv5 = (ushort*)(regBig + 10 * BSD_ * 2); // [5][B,S,3D]
    ushort* ab5 = (ushort*)regBig;                 // [5*BS][DFF] (phase 2)
    ushort* xhat1 = (ushort*)alloc(BSD_ * 2);      // dead after ln_jvp; then x2b alias
    ushort* x2b = xhat1;
    ushort* xhat2 = (ushort*)alloc(BSD_ * 2);
    ushort* h2b = (ushort*)alloc(BSD_ * 2);
    ushort* dx2b = (ushort*)alloc(4 * BSD_ * 2);   // [4*BS][D] bf16
    ushort* xt_b = (ushort*)alloc(4 * BSD_ * 2);   // compact bf16 copy of x_tangent
    ushort* Vt = (ushort*)alloc(BSD_ * 2);
    ushort* dscb2 = (ushort*)alloc(2 * ATT_ * 2);  // [2][BH,S,S]
    ushort* attnb = (ushort*)alloc(ATT_ * 2);      // primal probs bf16
    ushort* gpb = (ushort*)alloc(BSF_ * 2);        // gelu'(u) bf16
    ushort* dh2_4 = (ushort*)alloc(4 * BSD_ * 2);  // [4*BS][D]
    ushort* dVt4 = (ushort*)alloc(4 * BSD_ * 2);   // [4][bh][HD][S]
    float* rstd1 = (float*)alloc(BS_ * 4);
    float* rstd2 = (float*)alloc(BS_ * 4);
    ushort* WqkvT = (ushort*)alloc((size_t)D_ * 3 * D_ * 2);
    ushort* WprojT = (ushort*)alloc((size_t)D_ * D_ * 2);
    ushort* W1T = (ushort*)alloc((size_t)DFF_ * D_ * 2);
    ushort* W2T = (ushort*)alloc((size_t)D_ * DFF_ * 2);

    // ---- weights -> bf16 transposed [N][K] ----
    transpose_f2b<<<dim3(3 * D_ / 32, D_ / 32), 256, 0, stream>>>(Wqkv, WqkvT, D_, 3 * D_);
    transpose_f2b<<<dim3(D_ / 32, D_ / 32), 256, 0, stream>>>(Wproj, WprojT, D_, D_);
    transpose_f2b<<<dim3(DFF_ / 32, D_ / 32), 256, 0, stream>>>(W1, W1T, D_, DFF_);
    transpose_f2b<<<dim3(D_ / 32, DFF_ / 32), 256, 0, stream>>>(W2, W2T, DFF_, D_);

    // ---- LN fwd + batched LN-JVP, then ONE merged qkv GEMM over [h; dh x4] (M=10240) ----
    ln_fwd<<<BS_, 256, 0, stream>>>(x, nullptr, g1, b1, xhat1, hb5, rstd1);
    ln_jvp<<<4 * BS_, 256, 0, stream>>>(xt, nullptr, 0, xhat1, rstd1, g1, hb5 + BSD_, xt_b);
    gemm_mfma<128, 128, 0><<<dim3(3 * D_ / 128, 5 * BS_ / 128), 256, 0, stream>>>(
        hb5, WqkvT, nullptr, nullptr, nullptr, nullptr, nullptr, nullptr, qkv5, nullptr, 3 * D_, D_);
    transpose_v<<<dim3(S_ / 32, HD_ / 32, 5 * BH_), 256, 0, stream>>>(qkv5, Vt, dVt4);

    // ---- primal attention ----
    attn_qk_mfma<false><<<(S_ / 128) * (S_ / 128) * BH_, 256, 0, stream>>>(qkv5, nullptr, dscb2);
    softmax_rows<<<BH_ * S_, 256, 0, stream>>>(dscb2, attnb);
    attn_av_p<<<(S_ / 128) * BH_, 256, 0, stream>>>(attnb, Vt, ob5);

    // ---- tangent attention (pair-batched) -> ob5 slices 1-4 ----
    const ushort* dqkv4 = qkv5 + BS3D_;  // slices 1-4
    for (int p = 0; p < 2; p++) {
        attn_qk_mfma<true><<<2 * (S_ / 128) * (S_ / 128) * BH_, 256, 0, stream>>>(
            qkv5, dqkv4 + (size_t)p * 2 * BS3D_, dscb2);
        attn_av_tan<<<2 * 4 * BH_, 256, 0, stream>>>(
            attnb, dscb2, Vt, dVt4 + (size_t)p * 2 * BSD_, ob5, ob5 + BSD_ + (size_t)p * 2 * BSD_);
    }

    // ---- merged proj (M=10240): slice0 -> x2b (bias+x res), slices1-4 -> dx2b (xt_b res) ----
    gemm_mfma<128, 64, 5><<<dim3(D_ / 64, 5 * BS_ / 128), 256, 0, stream>>>(
        ob5, WprojT, bproj, x, xt_b, nullptr, nullptr, nullptr, x2b, dx2b, D_, D_);

    // ---- MLP ----
    ln_fwd<<<BS_, 256, 0, stream>>>(nullptr, x2b, g2, b2, xhat2, h2b, rstd2);
    gemm_mfma<128, 128, 1><<<dim3(DFF_ / 128, BS_ / 128), 256, 0, stream>>>(
        h2b, W1T, bf1, nullptr, nullptr, nullptr, nullptr, nullptr, ab5, gpb, DFF_, D_);
    ln_jvp<<<4 * BS_, 256, 0, stream>>>(nullptr, dx2b, 1, xhat2, rstd2, g2, dh2_4, nullptr);
    gemm_mfma<128, 128, 2><<<dim3(DFF_ / 128, 4 * BS_ / 128), 256, 0, stream>>>(
        dh2_4, W1T, nullptr, nullptr, nullptr, nullptr, nullptr, nullptr, ab5 + BSF_, gpb, DFF_, D_);
    // ---- merged W2 (M=10240): slice0 -> out (bias+x2b), slices1-4 -> out_t (dx2b res) ----
    gemm_mfma<128, 64, 4><<<dim3(D_ / 64, 5 * BS_ / 128), 256, 0, stream>>>(
        ab5, W2T, bf2, nullptr, x2b, dx2b, out, out_t, nullptr, nullptr, D_, DFF_);
}

// Round 18
// 428.454 us; speedup vs baseline: 1.1965x; 1.0163x over previous
//
#include <hip/hip_runtime.h>
#include <math.h>

constexpr int B_ = 4, S_ = 512, D_ = 768, H_ = 12, M_ = 4, DFF_ = 3072, HD_ = 64;
constexpr float EPS_ = 1e-6f;
constexpr float SCALE_ = 0.125f;  // HD^-0.5
constexpr int BS_ = B_ * S_;
constexpr int BH_ = B_ * H_;
constexpr long long BSD_ = (long long)BS_ * D_;
constexpr long long BS3D_ = (long long)BS_ * 3 * D_;
constexpr long long ATT_ = (long long)BH_ * S_ * S_;
constexpr long long BSF_ = (long long)BS_ * DFF_;

typedef __attribute__((ext_vector_type(8))) short bf16x8;
typedef __attribute__((ext_vector_type(4))) float f32x4;

__device__ __forceinline__ ushort f2bf(float f) {
    uint32_t u = __float_as_uint(f);
    u += 0x7FFF + ((u >> 16) & 1);
    return (ushort)(u >> 16);
}
__device__ __forceinline__ float bf2f(ushort u) {
    return __uint_as_float((uint32_t)u << 16);
}

__device__ __forceinline__ void gll16(const ushort* g, ushort* l) {
    __builtin_amdgcn_global_load_lds((const __attribute__((address_space(1))) void*)g,
                                     (__attribute__((address_space(3))) void*)l, 16, 0, 0);
}

// counted vmcnt wait (literal required in asm)
template <int N> __device__ __forceinline__ void waitcnt_vm() {
    if constexpr (N == 0) asm volatile("s_waitcnt vmcnt(0)" ::: "memory");
    else if constexpr (N == 4) asm volatile("s_waitcnt vmcnt(4)" ::: "memory");
    else if constexpr (N == 6) asm volatile("s_waitcnt vmcnt(6)" ::: "memory");
    else if constexpr (N == 8) asm volatile("s_waitcnt vmcnt(8)" ::: "memory");
    else static_assert(N == 0 || N == 4 || N == 6 || N == 8, "add literal");
}

__device__ __forceinline__ void waitcnt_lgkm0() {
    asm volatile("s_waitcnt lgkmcnt(0)" ::: "memory");
    __builtin_amdgcn_sched_barrier(0);  // rule 18: fence MFMA/reg-op hoisting
}

// XCD-chunked bijective block remap (m204)
__device__ __forceinline__ int xcd_swz(int flat, int nwg) {
    int q = nwg >> 3, r = nwg & 7;
    int x = flat & 7, pos = flat >> 3;
    int base = (x < r) ? x * (q + 1) : r * (q + 1) + (x - r) * q;
    return base + pos;
}

// batched-row (rg in [0,8192)) -> [B,M,S,Nc] offset
__device__ __forceinline__ size_t stroff(int rg, int c, int Nc) {
    int m = rg >> 11;
    int b = (rg >> 9) & (B_ - 1);
    int s = rg & (S_ - 1);
    return ((size_t)((b * M_ + m) * S_ + s)) * Nc + c;
}

// ---------------- block reductions (256 threads = 4 waves) ----------------
__device__ __forceinline__ float block_sum(float v) {
    __shared__ float red[4];
    int tid = threadIdx.x;
#pragma unroll
    for (int off = 32; off > 0; off >>= 1) v += __shfl_down(v, off, 64);
    __syncthreads();
    if ((tid & 63) == 0) red[tid >> 6] = v;
    __syncthreads();
    return red[0] + red[1] + red[2] + red[3];
}

__device__ __forceinline__ float block_max(float v) {
    __shared__ float red[4];
    int tid = threadIdx.x;
#pragma unroll
    for (int off = 32; off > 0; off >>= 1) v = fmaxf(v, __shfl_down(v, off, 64));
    __syncthreads();
    if ((tid & 63) == 0) red[tid >> 6] = v;
    __syncthreads();
    return fmaxf(fmaxf(red[0], red[1]), fmaxf(red[2], red[3]));
}

// ---------------- weight transpose+convert: W[K][N] f32 -> WT[N][K] bf16 ----------------
__global__ __launch_bounds__(256) void transpose_f2b(const float* __restrict__ W,
                                                     ushort* __restrict__ WT,
                                                     int K, int N) {
    __shared__ float t[32][33];
    int n0 = blockIdx.x * 32, k0 = blockIdx.y * 32;
    int tx = threadIdx.x & 31, ty = threadIdx.x >> 5;
#pragma unroll
    for (int i = 0; i < 4; i++)
        t[ty + i * 8][tx] = W[(size_t)(k0 + ty + i * 8) * N + n0 + tx];
    __syncthreads();
#pragma unroll
    for (int i = 0; i < 4; i++)
        WT[(size_t)(n0 + ty + i * 8) * K + k0 + tx] = f2bf(t[tx][ty + i * 8]);
}

// ---------------- V transpose: qkv5[5][B,S,3D] bf16 -> m=0: Vt[bh][HD][S]; m>=1: dVt4[m-1] ----
__global__ __launch_bounds__(256) void transpose_v(const ushort* __restrict__ src0,
                                                   ushort* __restrict__ Vt0,
                                                   ushort* __restrict__ dVt4) {
    int z = blockIdx.z;
    int m = z / BH_, bh = z % BH_;
    const ushort* qkvb = src0 + (size_t)m * BS3D_;
    ushort* Vt = (m == 0) ? Vt0 : dVt4 + (size_t)(m - 1) * BSD_;
    int b = bh / H_, hh = bh - b * H_;
    int s0 = blockIdx.x * 32, d0 = blockIdx.y * 32;
    __shared__ ushort t[32][33];
    int tx = threadIdx.x & 31, ty = threadIdx.x >> 5;
#pragma unroll
    for (int i = 0; i < 4; i++)
        t[ty + i * 8][tx] = qkvb[(size_t)(b * S_ + s0 + ty + i * 8) * 3 * D_ + 2 * D_ + hh * HD_ + d0 + tx];
    __syncthreads();
#pragma unroll
    for (int i = 0; i < 4; i++)
        Vt[(size_t)bh * HD_ * S_ + (size_t)(d0 + ty + i * 8) * S_ + s0 + tx] = t[tx][ty + i * 8];
}

// ---------------- LayerNorm forward: input f32 (xf) or bf16 (xb); out xhat bf16, h bf16 ----
__global__ __launch_bounds__(256) void ln_fwd(const float* __restrict__ xf,
                                              const ushort* __restrict__ xb,
                                              const float* __restrict__ g,
                                              const float* __restrict__ bta,
                                              ushort* __restrict__ xhat,
                                              ushort* __restrict__ h,
                                              float* __restrict__ rstd) {
    int row = blockIdx.x;
    size_t base = (size_t)row * D_;
    int tid = threadIdx.x;
    float v[3];
    float s = 0.f;
#pragma unroll
    for (int i = 0; i < 3; i++) {
        int c = tid + i * 256;
        v[i] = xf ? xf[base + c] : bf2f(xb[base + c]);
        s += v[i];
    }
    s = block_sum(s);
    float mu = s * (1.0f / D_);
    float vs = 0.f;
#pragma unroll
    for (int i = 0; i < 3; i++) { float c = v[i] - mu; vs += c * c; }
    vs = block_sum(vs);
    float rs = rsqrtf(vs * (1.0f / D_) + EPS_);
#pragma unroll
    for (int i = 0; i < 3; i++) {
        int c = tid + i * 256;
        float xh = (v[i] - mu) * rs;
        xhat[base + c] = f2bf(xh);
        h[base + c] = f2bf(xh * g[c] + bta[c]);
    }
    if (tid == 0) rstd[row] = rs;
}

// ---------------- batched LayerNorm JVP: grid 4*BS_ rows ----------------
// mode 0: tf strided [B,M,S,D] f32 (also emits xtb bf16 compact copy); mode 1: tb bf16 compact
__global__ __launch_bounds__(256) void ln_jvp(const float* __restrict__ tf,
                                              const ushort* __restrict__ tb, int mode,
                                              const ushort* __restrict__ xhat,
                                              const float* __restrict__ rstd,
                                              const float* __restrict__ g,
                                              ushort* __restrict__ dh,
                                              ushort* __restrict__ xtb) {
    int rg = blockIdx.x;
    int r = rg & (BS_ - 1);
    size_t pbase = (size_t)r * D_;
    int tid = threadIdx.x;
    float tv[3], xh[3];
    float s1 = 0.f, s2 = 0.f;
    size_t tbase;
    if (mode == 0) {
        int m = rg >> 11;
        int b = r >> 9, s = r & (S_ - 1);
        tbase = ((size_t)((b * M_ + m) * S_ + s)) * D_;
    } else {
        tbase = (size_t)rg * D_;
    }
#pragma unroll
    for (int i = 0; i < 3; i++) {
        int c = tid + i * 256;
        tv[i] = (mode == 0) ? tf[tbase + c] : bf2f(tb[tbase + c]);
        xh[i] = bf2f(xhat[pbase + c]);
        s1 += tv[i];
        s2 += tv[i] * xh[i];
    }
    s1 = block_sum(s1);
    s2 = block_sum(s2);
    float mt = s1 * (1.0f / D_);
    float mx = s2 * (1.0f / D_);
    float rs = rstd[r];
#pragma unroll
    for (int i = 0; i < 3; i++) {
        int c = tid + i * 256;
        dh[(size_t)rg * D_ + c] = f2bf(g[c] * rs * (tv[i] - mt - xh[i] * mx));
        if (mode == 0 && xtb) xtb[(size_t)rg * D_ + c] = f2bf(tv[i]);
    }
}

// ---------------- bf16 MFMA GEMM <BM,BN>, BK=64, 2-deep pipeline, stage-early ----------------
// EPI 0: Cb = bf16(acc)                       (merged qkv)
// EPI 1: u = acc + bias; Cb = bf16(gelu(u)); aux = bf16(gelu'(u))   (W1 primal)
// EPI 2: Cb = bf16(acc * bf2f(aux[rg mod BS]))                       (W1 tangent)
// EPI 4: primal W2: v += bias + bf2f(resb);  Cf[off] = v             (M = BS)
// EPI 5: merged proj: rg<BS: v+=bias+resf[off]; Cb[off]=bf16(v)
//                     rg>=BS: v+=bf2f(resb[rg2]); aux[rg2]=bf16(v)
// EPI 6: W2 tangent: v += bf2f(resb2[rg]); Cf2[stroff(rg)] = v       (M = 4*BS)
template <int BM, int BN, int EPI>
__global__ __launch_bounds__(256) void gemm_mfma(const ushort* __restrict__ A,
                                                 const ushort* __restrict__ BT,
                                                 const float* __restrict__ bias,
                                                 const float* __restrict__ resf,
                                                 const ushort* __restrict__ resb,
                                                 const ushort* __restrict__ resb2,
                                                 float* __restrict__ Cf,
                                                 float* __restrict__ Cf2,
                                                 ushort* __restrict__ Cb,
                                                 ushort* __restrict__ aux,
                                                 int Nc, int Kd) {
    constexpr int FI = BM / 32, FJ = BN / 32;
    constexpr int LA = BM / 32, LB = BN / 32, L = LA + LB;
    __shared__ ushort As[2][BM * 64];
    __shared__ ushort Bs[2][BN * 64];
    int tid = threadIdx.x;
    int wave = tid >> 6, lane = tid & 63;
    int wr = wave >> 1, wc = wave & 1;
    int gx = gridDim.x, nwg = gx * gridDim.y;
    int work = xcd_swz(blockIdx.x + blockIdx.y * gx, nwg);
    // band remap: 8 row-panels per band, col-major inside (L2 anti-thrash); gy%8==0 required
    int band = work / (8 * gx);
    int wi = work - band * (8 * gx);
    int row0 = (band * 8 + (wi & 7)) * BM;
    int col0 = (wi >> 3) * BN;

    int srow = lane >> 3;
    int skel = ((lane & 7) ^ (lane >> 3)) * 8;
    const ushort* Ag0 = A + (size_t)(row0 + srow) * Kd + skel;
    const ushort* Bg0 = BT + (size_t)(col0 + srow) * Kd + skel;

    auto stage = [&](int bufi, int k0) {
#pragma unroll
        for (int cc = 0; cc < LA; cc++) {
            int c = wave * LA + cc;
            gll16(Ag0 + (size_t)(c * 8) * Kd + k0, As[bufi] + c * 512);
        }
#pragma unroll
        for (int cc = 0; cc < LB; cc++) {
            int c = wave * LB + cc;
            gll16(Bg0 + (size_t)(c * 8) * Kd + k0, Bs[bufi] + c * 512);
        }
    };

    int frow = lane & 15, fkb = (lane >> 4) * 8;
    int aoff[2][FI], boff[2][FJ];
#pragma unroll
    for (int ks = 0; ks < 2; ks++) {
        int sw = (fkb + ks * 32) ^ ((frow & 7) * 8);
#pragma unroll
        for (int i = 0; i < FI; i++) aoff[ks][i] = (wr * (BM / 2) + i * 16 + frow) * 64 + sw;
#pragma unroll
        for (int j = 0; j < FJ; j++) boff[ks][j] = (wc * (BN / 2) + j * 16 + frow) * 64 + sw;
    }

    f32x4 acc[FI][FJ] = {};

    int nt = Kd >> 6;
    stage(0, 0);
    if (nt > 1) { stage(1, 64); waitcnt_vm<L>(); }
    else        { waitcnt_vm<0>(); }
    __builtin_amdgcn_s_barrier();
    __builtin_amdgcn_sched_barrier(0);

    int cur = 0;
    for (int t = 0; t < nt; t++) {
        bf16x8 af[2][FI], bfv[2][FJ];
        const ushort* Ab = As[cur];
        const ushort* Bb = Bs[cur];
#pragma unroll
        for (int ks = 0; ks < 2; ks++) {
#pragma unroll
            for (int i = 0; i < FI; i++) af[ks][i] = *(const bf16x8*)(Ab + aoff[ks][i]);
#pragma unroll
            for (int j = 0; j < FJ; j++) bfv[ks][j] = *(const bf16x8*)(Bb + boff[ks][j]);
        }
        waitcnt_lgkm0();                 // reads retired before others' stages can overwrite
        __builtin_amdgcn_s_barrier();    // all waves done reading buf[cur]
        if (t + 2 < nt) {
            stage(cur, (t + 2) << 6);    // issue early: overlaps with MFMA below
            __builtin_amdgcn_sched_barrier(0);
        }
#pragma unroll
        for (int ks = 0; ks < 2; ks++)
#pragma unroll
            for (int i = 0; i < FI; i++)
#pragma unroll
                for (int j = 0; j < FJ; j++)
                    acc[i][j] = __builtin_amdgcn_mfma_f32_16x16x32_bf16(af[ks][i], bfv[ks][j], acc[i][j], 0, 0, 0);
        __builtin_amdgcn_sched_barrier(0);
        if (t + 2 < nt) waitcnt_vm<L>();        // t+1 complete, t+2 in flight
        else if (t + 1 < nt) waitcnt_vm<0>();   // last prefetched tile complete
        __builtin_amdgcn_s_barrier();
        __builtin_amdgcn_sched_barrier(0);
        cur ^= 1;
    }

    // C/D layout: col = lane&15, row = (lane>>4)*4 + reg
#pragma unroll
    for (int i = 0; i < FI; i++) {
        int rbase = row0 + wr * (BM / 2) + i * 16 + (lane >> 4) * 4;
#pragma unroll
        for (int j = 0; j < FJ; j++) {
            int c = col0 + wc * (BN / 2) + j * 16 + (lane & 15);
#pragma unroll
            for (int r = 0; r < 4; r++) {
                int rg = rbase + r;
                size_t off = (size_t)rg * Nc + c;
                float v = acc[i][j][r];
                if (EPI == 0) {
                    Cb[off] = f2bf(v);
                } else if (EPI == 1) {
                    v += bias[c];
                    float cdf = 0.5f * (1.0f + erff(v * 0.70710678118654752f));
                    Cb[off] = f2bf(v * cdf);
                    aux[off] = f2bf(cdf + v * 0.39894228040143267f * expf(-0.5f * v * v));
                } else if (EPI == 2) {
                    Cb[off] = f2bf(v * bf2f(aux[(size_t)(rg & (BS_ - 1)) * Nc + c]));
                } else if (EPI == 4) {
                    v += bias[c] + bf2f(resb[off]);
                    Cf[off] = v;
                } else if (EPI == 5) {
                    if (rg < BS_) {
                        v += bias[c] + resf[off];
                        Cb[off] = f2bf(v);
                    } else {
                        int rg2 = rg - BS_;
                        v += bf2f(resb[(size_t)rg2 * Nc + c]);
                        aux[(size_t)rg2 * Nc + c] = f2bf(v);
                    }
                } else {  // EPI == 6
                    v += bf2f(resb2[(size_t)rg * Nc + c]);
                    Cf2[stroff(rg, c, Nc)] = v;
                }
            }
        }
    }
}

// ---------------- MFMA QK^T: single-shot BK=64 (K=HD), XOR-swizzled ----------------
template <bool TAN>
__global__ __launch_bounds__(256) void attn_qk_mfma(const ushort* __restrict__ qkvb,
                                                    const ushort* __restrict__ dqkvp,
                                                    ushort* __restrict__ sc) {
    int work = xcd_swz(blockIdx.x, gridDim.x);
    constexpr int NT = S_ / 128;  // 4
    int mz = work / (BH_ * NT * NT);
    int rem = work % (BH_ * NT * NT);
    int bh = rem / (NT * NT);
    int r2 = rem % (NT * NT);
    int q0 = (r2 / NT) * 128, kc0 = (r2 % NT) * 128;
    int b = bh / H_, hh = bh - b * H_;
    const size_t qoff = (size_t)b * S_ * 3 * D_ + hh * HD_;
    const int ld = 3 * D_;
    const ushort* dqkv = TAN ? dqkvp + (size_t)mz * BS3D_ : nullptr;
    __shared__ ushort As[128 * 64];
    __shared__ ushort Bs[128 * 64];
    __shared__ ushort dAs[TAN ? 128 * 64 : 1];
    __shared__ ushort dBs[TAN ? 128 * 64 : 1];
    int tid = threadIdx.x;
    int wave = tid >> 6, lane = tid & 63;
    int wr = wave >> 1, wc = wave & 1;

    int srow = lane >> 3;
    int skel = ((lane & 7) ^ (lane >> 3)) * 8;
    const ushort* Ag0 = qkvb + qoff + (size_t)(q0 + srow) * ld + skel;
    const ushort* Bg0 = qkvb + qoff + D_ + (size_t)(kc0 + srow) * ld + skel;

#pragma unroll
    for (int cc = 0; cc < 4; cc++) {
        int c = wave * 4 + cc;
        gll16(Ag0 + (size_t)(c * 8) * ld, As + c * 512);
        gll16(Bg0 + (size_t)(c * 8) * ld, Bs + c * 512);
        if (TAN) {
            gll16(dqkv + qoff + (size_t)(q0 + c * 8 + srow) * ld + skel, dAs + c * 512);
            gll16(dqkv + qoff + D_ + (size_t)(kc0 + c * 8 + srow) * ld + skel, dBs + c * 512);
        }
    }
    __syncthreads();

    int frow = lane & 15, fkb = (lane >> 4) * 8;
    f32x4 acc[4][4] = {};
#pragma unroll
    for (int ks = 0; ks < 2; ks++) {
        int sw = (fkb + ks * 32) ^ ((frow & 7) * 8);
        bf16x8 af[4], bfv[4];
#pragma unroll
        for (int i = 0; i < 4; i++) af[i] = *(const bf16x8*)(As + (wr * 64 + i * 16 + frow) * 64 + sw);
#pragma unroll
        for (int j = 0; j < 4; j++) bfv[j] = *(const bf16x8*)(Bs + (wc * 64 + j * 16 + frow) * 64 + sw);
        if (!TAN) {
#pragma unroll
            for (int i = 0; i < 4; i++)
#pragma unroll
                for (int j = 0; j < 4; j++)
                    acc[i][j] = __builtin_amdgcn_mfma_f32_16x16x32_bf16(af[i], bfv[j], acc[i][j], 0, 0, 0);
        } else {
            bf16x8 daf[4], dbf[4];
#pragma unroll
            for (int i = 0; i < 4; i++) daf[i] = *(const bf16x8*)(dAs + (wr * 64 + i * 16 + frow) * 64 + sw);
#pragma unroll
            for (int j = 0; j < 4; j++) dbf[j] = *(const bf16x8*)(dBs + (wc * 64 + j * 16 + frow) * 64 + sw);
#pragma unroll
            for (int i = 0; i < 4; i++)
#pragma unroll
                for (int j = 0; j < 4; j++) {
                    acc[i][j] = __builtin_amdgcn_mfma_f32_16x16x32_bf16(daf[i], bfv[j], acc[i][j], 0, 0, 0);
                    acc[i][j] = __builtin_amdgcn_mfma_f32_16x16x32_bf16(af[i], dbf[j], acc[i][j], 0, 0, 0);
                }
        }
    }

    ushort* scm = sc + (size_t)mz * ATT_;
#pragma unroll
    for (int i = 0; i < 4; i++) {
        int rbase = q0 + wr * 64 + i * 16 + (lane >> 4) * 4;
#pragma unroll
        for (int j = 0; j < 4; j++) {
            int c = kc0 + wc * 64 + j * 16 + (lane & 15);
#pragma unroll
            for (int r = 0; r < 4; r++)
                scm[((size_t)bh * S_ + rbase + r) * S_ + c] = f2bf(acc[i][j][r] * SCALE_);
        }
    }
}

// ---------------- primal P@V: BK=64, XOR-swizzled ----------------
__global__ __launch_bounds__(256) void attn_av_p(const ushort* __restrict__ Pb,
                                                 const ushort* __restrict__ Vt,
                                                 ushort* __restrict__ outp) {
    int work = xcd_swz(blockIdx.x, gridDim.x);
    constexpr int NT = S_ / 128;  // 4
    int bh = work / NT;
    int q0 = (work % NT) * 128;
    int b = bh / H_, hh = bh - b * H_;
    const ushort* Pg = Pb + (size_t)bh * S_ * S_;
    const ushort* Vg = Vt + (size_t)bh * HD_ * S_;
    __shared__ ushort As[128 * 64];
    __shared__ ushort Bs[64 * 64];
    int tid = threadIdx.x;
    int wave = tid >> 6, lane = tid & 63;
    int wr = wave >> 1, wc = wave & 1;
    int srow = lane >> 3;
    int skel = ((lane & 7) ^ (lane >> 3)) * 8;
    int frow = lane & 15, fkb = (lane >> 4) * 8;

    f32x4 acc[4][2] = {};
    for (int k0 = 0; k0 < S_; k0 += 64) {
#pragma unroll
        for (int cc = 0; cc < 4; cc++) {
            int c = wave * 4 + cc;
            gll16(Pg + (size_t)(q0 + c * 8 + srow) * S_ + k0 + skel, As + c * 512);
        }
#pragma unroll
        for (int cc = 0; cc < 2; cc++) {
            int c = wave * 2 + cc;
            gll16(Vg + (size_t)(c * 8 + srow) * S_ + k0 + skel, Bs + c * 512);
        }
        __syncthreads();
#pragma unroll
        for (int ks = 0; ks < 2; ks++) {
            int sw = (fkb + ks * 32) ^ ((frow & 7) * 8);
            bf16x8 af[4], bfv[2];
#pragma unroll
            for (int i = 0; i < 4; i++) af[i] = *(const bf16x8*)(As + (wr * 64 + i * 16 + frow) * 64 + sw);
#pragma unroll
            for (int j = 0; j < 2; j++) bfv[j] = *(const bf16x8*)(Bs + (wc * 32 + j * 16 + frow) * 64 + sw);
#pragma unroll
            for (int i = 0; i < 4; i++)
#pragma unroll
                for (int j = 0; j < 2; j++)
                    acc[i][j] = __builtin_amdgcn_mfma_f32_16x16x32_bf16(af[i], bfv[j], acc[i][j], 0, 0, 0);
        }
        __syncthreads();
    }

#pragma unroll
    for (int i = 0; i < 4; i++) {
        int rbase = q0 + wr * 64 + i * 16 + (lane >> 4) * 4;
#pragma unroll
        for (int j = 0; j < 2; j++) {
            int c = hh * HD_ + wc * 32 + j * 16 + (lane & 15);
#pragma unroll
            for (int r = 0; r < 4; r++)
                outp[(size_t)(b * S_ + rbase + r) * D_ + c] = f2bf(acc[i][j][r]);
        }
    }
}

// ---------------- FUSED tangent P@V (single pass, 128 q-rows): dO = (P.D)@V + P@dV - s*O ----
__global__ __launch_bounds__(256) void attn_av_tan(const ushort* __restrict__ Pb,
                                                   const ushort* __restrict__ dscp,
                                                   const ushort* __restrict__ Vt,
                                                   const ushort* __restrict__ dVtp,
                                                   const ushort* __restrict__ Ob,
                                                   ushort* __restrict__ outp) {
    int work = xcd_swz(blockIdx.x, gridDim.x);
    int mz = work / (BH_ * 4);
    int rem = work % (BH_ * 4);
    int bh = rem / 4;
    int q0 = (rem % 4) * 128;
    int b = bh / H_, hh = bh - b * H_;
    const ushort* Pg = Pb + (size_t)bh * S_ * S_;
    const ushort* Dg = dscp + (size_t)mz * ATT_ + (size_t)bh * S_ * S_;
    const ushort* Vg = Vt + (size_t)bh * HD_ * S_;
    const ushort* dVg = dVtp + (size_t)mz * BSD_ + (size_t)bh * HD_ * S_;
    ushort* outm = outp + (size_t)mz * BSD_;
    __shared__ ushort Ps[128 * 64], Ds[128 * 64], Vs[64 * 64], dVs[64 * 64];  // 48 KB
    int tid = threadIdx.x;
    int wave = tid >> 6, lane = tid & 63;
    int wr = wave >> 1, wc = wave & 1;
    int srow = lane >> 3;
    int skel = ((lane & 7) ^ (lane >> 3)) * 8;
    int frow = lane & 15, fkb = (lane >> 4) * 8;
    int aoff[2][4], boff[2][2];
#pragma unroll
    for (int ks = 0; ks < 2; ks++) {
        int sw = (fkb + ks * 32) ^ ((frow & 7) * 8);
#pragma unroll
        for (int i = 0; i < 4; i++) aoff[ks][i] = (wr * 64 + i * 16 + frow) * 64 + sw;
#pragma unroll
        for (int j = 0; j < 2; j++) boff[ks][j] = (wc * 32 + j * 16 + frow) * 64 + sw;
    }

    float s[4] = {0.f, 0.f, 0.f, 0.f};
    f32x4 acc[4][2] = {};

    for (int k0 = 0; k0 < S_; k0 += 64) {
#pragma unroll
        for (int cc = 0; cc < 4; cc++) {
            int c = wave * 4 + cc;
            gll16(Pg + (size_t)(q0 + c * 8 + srow) * S_ + k0 + skel, Ps + c * 512);
            gll16(Dg + (size_t)(q0 + c * 8 + srow) * S_ + k0 + skel, Ds + c * 512);
        }
#pragma unroll
        for (int cc = 0; cc < 2; cc++) {
            int c = wave * 2 + cc;
            gll16(Vg + (size_t)(c * 8 + srow) * S_ + k0 + skel, Vs + c * 512);
            gll16(dVg + (size_t)(c * 8 + srow) * S_ + k0 + skel, dVs + c * 512);
        }
        __syncthreads();
#pragma unroll
        for (int ks = 0; ks < 2; ks++) {
            bf16x8 p8[4], pq8[4], v8[2], dv8[2];
#pragma unroll
            for (int i = 0; i < 4; i++) {
                p8[i] = *(const bf16x8*)(Ps + aoff[ks][i]);
                bf16x8 d8 = *(const bf16x8*)(Ds + aoff[ks][i]);
#pragma unroll
                for (int e = 0; e < 8; e++) {
                    float pd = bf2f((ushort)p8[i][e]) * bf2f((ushort)d8[e]);
                    s[i] += pd;
                    pq8[i][e] = (short)f2bf(pd);
                }
            }
#pragma unroll
            for (int j = 0; j < 2; j++) {
                v8[j] = *(const bf16x8*)(Vs + boff[ks][j]);
                dv8[j] = *(const bf16x8*)(dVs + boff[ks][j]);
            }
#pragma unroll
            for (int i = 0; i < 4; i++)
#pragma unroll
                for (int j = 0; j < 2; j++) {
                    acc[i][j] = __builtin_amdgcn_mfma_f32_16x16x32_bf16(pq8[i], v8[j], acc[i][j], 0, 0, 0);
                    acc[i][j] = __builtin_amdgcn_mfma_f32_16x16x32_bf16(p8[i], dv8[j], acc[i][j], 0, 0, 0);
                }
        }
        __syncthreads();
    }

    // complete rowsums: lanes {l, l^16, l^32, l^48} hold the 4 k-slices of row (.. + frow)
#pragma unroll
    for (int i = 0; i < 4; i++) {
        s[i] += __shfl_xor(s[i], 16);
        s[i] += __shfl_xor(s[i], 32);
    }

    // epilogue: out = acc - s[row]*O[row][col]
#pragma unroll
    for (int i = 0; i < 4; i++) {
        int rbase = q0 + wr * 64 + i * 16 + (lane >> 4) * 4;
#pragma unroll
        for (int r = 0; r < 4; r++) {
            float sc = __shfl(s[i], ((lane >> 4) << 2) + r);
#pragma unroll
            for (int j = 0; j < 2; j++) {
                int c = hh * HD_ + wc * 32 + j * 16 + (lane & 15);
                float o = bf2f(Ob[(size_t)(b * S_ + rbase + r) * D_ + c]);
                outm[(size_t)(b * S_ + rbase + r) * D_ + c] = f2bf(acc[i][j][r] - sc * o);
            }
        }
    }
}

// ---------------- softmax: bf16 scores -> bf16 probs ----------------
__global__ __launch_bounds__(256) void softmax_rows(const ushort* __restrict__ sc,
                                                    ushort* __restrict__ scb) {
    size_t row = blockIdx.x;
    const ushort* p = sc + row * S_;
    int tid = threadIdx.x;
    ushort2 vu = *(const ushort2*)&p[tid * 2];
    float v0 = bf2f(vu.x), v1 = bf2f(vu.y);
    float mx = block_max(fmaxf(v0, v1));
    float e0 = expf(v0 - mx), e1 = expf(v1 - mx);
    float s = block_sum(e0 + e1);
    float inv = 1.0f / s;
    ushort2 ob; ob.x = f2bf(e0 * inv); ob.y = f2bf(e1 * inv);
    *(ushort2*)&scb[row * S_ + tid * 2] = ob;
}

// ---------------- host ----------------
extern "C" void kernel_launch(void* const* d_in, const int* in_sizes, int n_in,
                              void* d_out, int out_size, void* d_ws, size_t ws_size,
                              hipStream_t stream) {
    const float* x = (const float*)d_in[0];
    const float* xt = (const float*)d_in[1];
    const float* g1 = (const float*)d_in[2];
    const float* b1 = (const float*)d_in[3];
    const float* Wqkv = (const float*)d_in[4];
    const float* Wproj = (const float*)d_in[5];
    const float* bproj = (const float*)d_in[6];
    const float* g2 = (const float*)d_in[7];
    const float* b2 = (const float*)d_in[8];
    const float* W1 = (const float*)d_in[9];
    const float* bf1 = (const float*)d_in[10];
    const float* W2 = (const float*)d_in[11];
    const float* bf2 = (const float*)d_in[12];
    float* out = (float*)d_out;
    float* out_t = out + BSD_;   // [B,M,S,D]

    char* wp = (char*)d_ws;
    auto alloc = [&](size_t bytes) { void* p = wp; wp += (bytes + 255) & ~(size_t)255; return p; };
    // regBig: [hb5 | ob5 | qkv5] in phase 1; ab5 aliases from base in phase 2.
    // Lifetimes: hb5 dead after merged-qkv; ob5 dead after merged-proj; qkv5 dead after qk-tan.
    char* regBig = (char*)alloc(25 * BSD_ * 2);    // 78.6 MB
    ushort* hb5 = (ushort*)regBig;                 // [5*BS][D]
    ushort* ob5 = (ushort*)(regBig + 5 * BSD_ * 2);  // [5][BS][D]
    ushort* qkv5 = (ushort*)(regBig + 10 * BSD_ * 2); // [5][B,S,3D]
    ushort* ab5 = (ushort*)regBig;                 // [5*BS][DFF] (phase 2)
    ushort* xhat1 = (ushort*)alloc(BSD_ * 2);      // dead after ln_jvp; then x2b alias
    ushort* x2b = xhat1;
    ushort* xhat2 = (ushort*)alloc(BSD_ * 2);
    ushort* h2b = (ushort*)alloc(BSD_ * 2);
    ushort* dx2b = (ushort*)alloc(4 * BSD_ * 2);   // [4*BS][D] bf16
    ushort* xt_b = (ushort*)alloc(4 * BSD_ * 2);   // compact bf16 copy of x_tangent
    ushort* Vt = (ushort*)alloc(BSD_ * 2);
    ushort* dscb2 = (ushort*)alloc(2 * ATT_ * 2);  // [2][BH,S,S]
    ushort* attnb = (ushort*)alloc(ATT_ * 2);      // primal probs bf16
    ushort* gpb = (ushort*)alloc(BSF_ * 2);        // gelu'(u) bf16
    ushort* dh2_4 = (ushort*)alloc(4 * BSD_ * 2);  // [4*BS][D]
    ushort* dVt4 = (ushort*)alloc(4 * BSD_ * 2);   // [4][bh][HD][S]
    float* rstd1 = (float*)alloc(BS_ * 4);
    float* rstd2 = (float*)alloc(BS_ * 4);
    ushort* WqkvT = (ushort*)alloc((size_t)D_ * 3 * D_ * 2);
    ushort* WprojT = (ushort*)alloc((size_t)D_ * D_ * 2);
    ushort* W1T = (ushort*)alloc((size_t)DFF_ * D_ * 2);
    ushort* W2T = (ushort*)alloc((size_t)D_ * DFF_ * 2);

    // ---- weights -> bf16 transposed [N][K] ----
    transpose_f2b<<<dim3(3 * D_ / 32, D_ / 32), 256, 0, stream>>>(Wqkv, WqkvT, D_, 3 * D_);
    transpose_f2b<<<dim3(D_ / 32, D_ / 32), 256, 0, stream>>>(Wproj, WprojT, D_, D_);
    transpose_f2b<<<dim3(DFF_ / 32, D_ / 32), 256, 0, stream>>>(W1, W1T, D_, DFF_);
    transpose_f2b<<<dim3(D_ / 32, DFF_ / 32), 256, 0, stream>>>(W2, W2T, DFF_, D_);

    // ---- LN fwd + batched LN-JVP, then ONE merged qkv GEMM over [h; dh x4] (M=10240) ----
    ln_fwd<<<BS_, 256, 0, stream>>>(x, nullptr, g1, b1, xhat1, hb5, rstd1);
    ln_jvp<<<4 * BS_, 256, 0, stream>>>(xt, nullptr, 0, xhat1, rstd1, g1, hb5 + BSD_, xt_b);
    gemm_mfma<128, 128, 0><<<dim3(3 * D_ / 128, 5 * BS_ / 128), 256, 0, stream>>>(
        hb5, WqkvT, nullptr, nullptr, nullptr, nullptr, nullptr, nullptr, qkv5, nullptr, 3 * D_, D_);
    transpose_v<<<dim3(S_ / 32, HD_ / 32, 5 * BH_), 256, 0, stream>>>(qkv5, Vt, dVt4);

    // ---- primal attention ----
    attn_qk_mfma<false><<<(S_ / 128) * (S_ / 128) * BH_, 256, 0, stream>>>(qkv5, nullptr, dscb2);
    softmax_rows<<<BH_ * S_, 256, 0, stream>>>(dscb2, attnb);
    attn_av_p<<<(S_ / 128) * BH_, 256, 0, stream>>>(attnb, Vt, ob5);

    // ---- tangent attention (pair-batched) -> ob5 slices 1-4 ----
    const ushort* dqkv4 = qkv5 + BS3D_;  // slices 1-4
    for (int p = 0; p < 2; p++) {
        attn_qk_mfma<true><<<2 * (S_ / 128) * (S_ / 128) * BH_, 256, 0, stream>>>(
            qkv5, dqkv4 + (size_t)p * 2 * BS3D_, dscb2);
        attn_av_tan<<<2 * 4 * BH_, 256, 0, stream>>>(
            attnb, dscb2, Vt, dVt4 + (size_t)p * 2 * BSD_, ob5, ob5 + BSD_ + (size_t)p * 2 * BSD_);
    }

    // ---- merged proj (M=10240): slice0 -> x2b (bias+x res), slices1-4 -> dx2b (xt_b res) ----
    gemm_mfma<128, 64, 5><<<dim3(D_ / 64, 5 * BS_ / 128), 256, 0, stream>>>(
        ob5, WprojT, bproj, x, xt_b, nullptr, nullptr, nullptr, x2b, dx2b, D_, D_);

    // ---- MLP ----
    ln_fwd<<<BS_, 256, 0, stream>>>(nullptr, x2b, g2, b2, xhat2, h2b, rstd2);
    gemm_mfma<128, 128, 1><<<dim3(DFF_ / 128, BS_ / 128), 256, 0, stream>>>(
        h2b, W1T, bf1, nullptr, nullptr, nullptr, nullptr, nullptr, ab5, gpb, DFF_, D_);
    ln_jvp<<<4 * BS_, 256, 0, stream>>>(nullptr, dx2b, 1, xhat2, rstd2, g2, dh2_4, nullptr);
    gemm_mfma<128, 128, 2><<<dim3(DFF_ / 128, 4 * BS_ / 128), 256, 0, stream>>>(
        dh2_4, W1T, nullptr, nullptr, nullptr, nullptr, nullptr, nullptr, ab5 + BSF_, gpb, DFF_, D_);

    // ---- W2: split (K=3072 bands thrash L2 when merged at M=10240) ----
    gemm_mfma<64, 64, 4><<<dim3(D_ / 64, BS_ / 64), 256, 0, stream>>>(
        ab5, W2T, bf2, nullptr, x2b, nullptr, out, nullptr, nullptr, nullptr, D_, DFF_);
    gemm_mfma<128, 64, 6><<<dim3(D_ / 64, 4 * BS_ / 128), 256, 0, stream>>>(
        ab5 + BSF_, W2T, nullptr, nullptr, nullptr, dx2b, nullptr, out_t, nullptr, nullptr, D_, DFF_);
}

// Round 19
// 392.112 us; speedup vs baseline: 1.3074x; 1.0927x over previous
//
#include <hip/hip_runtime.h>
#include <math.h>

constexpr int B_ = 4, S_ = 512, D_ = 768, H_ = 12, M_ = 4, DFF_ = 3072, HD_ = 64;
constexpr float EPS_ = 1e-6f;
constexpr float SCALE_ = 0.125f;  // HD^-0.5
constexpr int BS_ = B_ * S_;
constexpr int BH_ = B_ * H_;
constexpr long long BSD_ = (long long)BS_ * D_;
constexpr long long BS3D_ = (long long)BS_ * 3 * D_;
constexpr long long ATT_ = (long long)BH_ * S_ * S_;
constexpr long long BSF_ = (long long)BS_ * DFF_;

typedef __attribute__((ext_vector_type(8))) short bf16x8;
typedef __attribute__((ext_vector_type(4))) float f32x4;

__device__ __forceinline__ ushort f2bf(float f) {
    uint32_t u = __float_as_uint(f);
    u += 0x7FFF + ((u >> 16) & 1);
    return (ushort)(u >> 16);
}
__device__ __forceinline__ float bf2f(ushort u) {
    return __uint_as_float((uint32_t)u << 16);
}

__device__ __forceinline__ void gll16(const ushort* g, ushort* l) {
    __builtin_amdgcn_global_load_lds((const __attribute__((address_space(1))) void*)g,
                                     (__attribute__((address_space(3))) void*)l, 16, 0, 0);
}

// counted vmcnt wait (literal required in asm)
template <int N> __device__ __forceinline__ void waitcnt_vm() {
    if constexpr (N == 0) asm volatile("s_waitcnt vmcnt(0)" ::: "memory");
    else if constexpr (N == 4) asm volatile("s_waitcnt vmcnt(4)" ::: "memory");
    else if constexpr (N == 6) asm volatile("s_waitcnt vmcnt(6)" ::: "memory");
    else if constexpr (N == 8) asm volatile("s_waitcnt vmcnt(8)" ::: "memory");
    else static_assert(N == 0 || N == 4 || N == 6 || N == 8, "add literal");
}

__device__ __forceinline__ void waitcnt_lgkm0() {
    asm volatile("s_waitcnt lgkmcnt(0)" ::: "memory");
    __builtin_amdgcn_sched_barrier(0);  // rule 18: fence MFMA/reg-op hoisting
}

// XCD-chunked bijective block remap (m204)
__device__ __forceinline__ int xcd_swz(int flat, int nwg) {
    int q = nwg >> 3, r = nwg & 7;
    int x = flat & 7, pos = flat >> 3;
    int base = (x < r) ? x * (q + 1) : r * (q + 1) + (x - r) * q;
    return base + pos;
}

// batched-row (rg in [0,8192)) -> [B,M,S,Nc] offset
__device__ __forceinline__ size_t stroff(int rg, int c, int Nc) {
    int m = rg >> 11;
    int b = (rg >> 9) & (B_ - 1);
    int s = rg & (S_ - 1);
    return ((size_t)((b * M_ + m) * S_ + s)) * Nc + c;
}

// ---------------- block reductions (256 threads = 4 waves) ----------------
__device__ __forceinline__ float block_sum(float v) {
    __shared__ float red[4];
    int tid = threadIdx.x;
#pragma unroll
    for (int off = 32; off > 0; off >>= 1) v += __shfl_down(v, off, 64);
    __syncthreads();
    if ((tid & 63) == 0) red[tid >> 6] = v;
    __syncthreads();
    return red[0] + red[1] + red[2] + red[3];
}

__device__ __forceinline__ float block_max(float v) {
    __shared__ float red[4];
    int tid = threadIdx.x;
#pragma unroll
    for (int off = 32; off > 0; off >>= 1) v = fmaxf(v, __shfl_down(v, off, 64));
    __syncthreads();
    if ((tid & 63) == 0) red[tid >> 6] = v;
    __syncthreads();
    return fmaxf(fmaxf(red[0], red[1]), fmaxf(red[2], red[3]));
}

// ---------------- weight transpose+convert: W[K][N] f32 -> WT[N][K] bf16 ----------------
__global__ __launch_bounds__(256) void transpose_f2b(const float* __restrict__ W,
                                                     ushort* __restrict__ WT,
                                                     int K, int N) {
    __shared__ float t[32][33];
    int n0 = blockIdx.x * 32, k0 = blockIdx.y * 32;
    int tx = threadIdx.x & 31, ty = threadIdx.x >> 5;
#pragma unroll
    for (int i = 0; i < 4; i++)
        t[ty + i * 8][tx] = W[(size_t)(k0 + ty + i * 8) * N + n0 + tx];
    __syncthreads();
#pragma unroll
    for (int i = 0; i < 4; i++)
        WT[(size_t)(n0 + ty + i * 8) * K + k0 + tx] = f2bf(t[tx][ty + i * 8]);
}

// ---------------- V transpose: qkv5[5][B,S,3D] bf16 -> m=0: Vt[bh][HD][S]; m>=1: dVt4[m-1] ----
__global__ __launch_bounds__(256) void transpose_v(const ushort* __restrict__ src0,
                                                   ushort* __restrict__ Vt0,
                                                   ushort* __restrict__ dVt4) {
    int z = blockIdx.z;
    int m = z / BH_, bh = z % BH_;
    const ushort* qkvb = src0 + (size_t)m * BS3D_;
    ushort* Vt = (m == 0) ? Vt0 : dVt4 + (size_t)(m - 1) * BSD_;
    int b = bh / H_, hh = bh - b * H_;
    int s0 = blockIdx.x * 32, d0 = blockIdx.y * 32;
    __shared__ ushort t[32][33];
    int tx = threadIdx.x & 31, ty = threadIdx.x >> 5;
#pragma unroll
    for (int i = 0; i < 4; i++)
        t[ty + i * 8][tx] = qkvb[(size_t)(b * S_ + s0 + ty + i * 8) * 3 * D_ + 2 * D_ + hh * HD_ + d0 + tx];
    __syncthreads();
#pragma unroll
    for (int i = 0; i < 4; i++)
        Vt[(size_t)bh * HD_ * S_ + (size_t)(d0 + ty + i * 8) * S_ + s0 + tx] = t[tx][ty + i * 8];
}

// ---------------- LayerNorm forward: input f32 (xf) or bf16 (xb); out xhat bf16, h bf16 ----
__global__ __launch_bounds__(256) void ln_fwd(const float* __restrict__ xf,
                                              const ushort* __restrict__ xb,
                                              const float* __restrict__ g,
                                              const float* __restrict__ bta,
                                              ushort* __restrict__ xhat,
                                              ushort* __restrict__ h,
                                              float* __restrict__ rstd) {
    int row = blockIdx.x;
    size_t base = (size_t)row * D_;
    int tid = threadIdx.x;
    float v[3];
    float s = 0.f;
#pragma unroll
    for (int i = 0; i < 3; i++) {
        int c = tid + i * 256;
        v[i] = xf ? xf[base + c] : bf2f(xb[base + c]);
        s += v[i];
    }
    s = block_sum(s);
    float mu = s * (1.0f / D_);
    float vs = 0.f;
#pragma unroll
    for (int i = 0; i < 3; i++) { float c = v[i] - mu; vs += c * c; }
    vs = block_sum(vs);
    float rs = rsqrtf(vs * (1.0f / D_) + EPS_);
#pragma unroll
    for (int i = 0; i < 3; i++) {
        int c = tid + i * 256;
        float xh = (v[i] - mu) * rs;
        xhat[base + c] = f2bf(xh);
        h[base + c] = f2bf(xh * g[c] + bta[c]);
    }
    if (tid == 0) rstd[row] = rs;
}

// ---------------- batched LayerNorm JVP: grid 4*BS_ rows ----------------
__global__ __launch_bounds__(256) void ln_jvp(const float* __restrict__ tf,
                                              const ushort* __restrict__ tb, int mode,
                                              const ushort* __restrict__ xhat,
                                              const float* __restrict__ rstd,
                                              const float* __restrict__ g,
                                              ushort* __restrict__ dh,
                                              ushort* __restrict__ xtb) {
    int rg = blockIdx.x;
    int r = rg & (BS_ - 1);
    size_t pbase = (size_t)r * D_;
    int tid = threadIdx.x;
    float tv[3], xh[3];
    float s1 = 0.f, s2 = 0.f;
    size_t tbase;
    if (mode == 0) {
        int m = rg >> 11;
        int b = r >> 9, s = r & (S_ - 1);
        tbase = ((size_t)((b * M_ + m) * S_ + s)) * D_;
    } else {
        tbase = (size_t)rg * D_;
    }
#pragma unroll
    for (int i = 0; i < 3; i++) {
        int c = tid + i * 256;
        tv[i] = (mode == 0) ? tf[tbase + c] : bf2f(tb[tbase + c]);
        xh[i] = bf2f(xhat[pbase + c]);
        s1 += tv[i];
        s2 += tv[i] * xh[i];
    }
    s1 = block_sum(s1);
    s2 = block_sum(s2);
    float mt = s1 * (1.0f / D_);
    float mx = s2 * (1.0f / D_);
    float rs = rstd[r];
#pragma unroll
    for (int i = 0; i < 3; i++) {
        int c = tid + i * 256;
        dh[(size_t)rg * D_ + c] = f2bf(g[c] * rs * (tv[i] - mt - xh[i] * mx));
        if (mode == 0 && xtb) xtb[(size_t)rg * D_ + c] = f2bf(tv[i]);
    }
}

// ---------------- bf16 MFMA GEMM <BM,BN>, BK=64, 2-deep pipeline, stage-early ----------------
// EPI 0: Cb = bf16(acc)
// EPI 1: u = acc + bias; Cb = bf16(gelu(u)); aux = bf16(gelu'(u))
// EPI 2: Cb = bf16(acc * bf2f(aux[rg mod BS]))
// EPI 4: primal W2: v += bias + bf2f(resb);  Cf[off] = v             (M = BS)
// EPI 5: merged proj: rg<BS: v+=bias+resf[off]; Cb[off]=bf16(v)
//                     rg>=BS: v+=bf2f(resb[rg2]); aux[rg2]=bf16(v)
// EPI 6: W2 tangent: v += bf2f(resb2[rg]); Cf2[stroff(rg)] = v       (M = 4*BS)
template <int BM, int BN, int EPI>
__global__ __launch_bounds__(256) void gemm_mfma(const ushort* __restrict__ A,
                                                 const ushort* __restrict__ BT,
                                                 const float* __restrict__ bias,
                                                 const float* __restrict__ resf,
                                                 const ushort* __restrict__ resb,
                                                 const ushort* __restrict__ resb2,
                                                 float* __restrict__ Cf,
                                                 float* __restrict__ Cf2,
                                                 ushort* __restrict__ Cb,
                                                 ushort* __restrict__ aux,
                                                 int Nc, int Kd) {
    constexpr int FI = BM / 32, FJ = BN / 32;
    constexpr int LA = BM / 32, LB = BN / 32, L = LA + LB;
    __shared__ ushort As[2][BM * 64];
    __shared__ ushort Bs[2][BN * 64];
    int tid = threadIdx.x;
    int wave = tid >> 6, lane = tid & 63;
    int wr = wave >> 1, wc = wave & 1;
    int gx = gridDim.x, nwg = gx * gridDim.y;
    int work = xcd_swz(blockIdx.x + blockIdx.y * gx, nwg);
    int band = work / (8 * gx);
    int wi = work - band * (8 * gx);
    int row0 = (band * 8 + (wi & 7)) * BM;
    int col0 = (wi >> 3) * BN;

    int srow = lane >> 3;
    int skel = ((lane & 7) ^ (lane >> 3)) * 8;
    const ushort* Ag0 = A + (size_t)(row0 + srow) * Kd + skel;
    const ushort* Bg0 = BT + (size_t)(col0 + srow) * Kd + skel;

    auto stage = [&](int bufi, int k0) {
#pragma unroll
        for (int cc = 0; cc < LA; cc++) {
            int c = wave * LA + cc;
            gll16(Ag0 + (size_t)(c * 8) * Kd + k0, As[bufi] + c * 512);
        }
#pragma unroll
        for (int cc = 0; cc < LB; cc++) {
            int c = wave * LB + cc;
            gll16(Bg0 + (size_t)(c * 8) * Kd + k0, Bs[bufi] + c * 512);
        }
    };

    int frow = lane & 15, fkb = (lane >> 4) * 8;
    int aoff[2][FI], boff[2][FJ];
#pragma unroll
    for (int ks = 0; ks < 2; ks++) {
        int sw = (fkb + ks * 32) ^ ((frow & 7) * 8);
#pragma unroll
        for (int i = 0; i < FI; i++) aoff[ks][i] = (wr * (BM / 2) + i * 16 + frow) * 64 + sw;
#pragma unroll
        for (int j = 0; j < FJ; j++) boff[ks][j] = (wc * (BN / 2) + j * 16 + frow) * 64 + sw;
    }

    f32x4 acc[FI][FJ] = {};

    int nt = Kd >> 6;
    stage(0, 0);
    if (nt > 1) { stage(1, 64); waitcnt_vm<L>(); }
    else        { waitcnt_vm<0>(); }
    __builtin_amdgcn_s_barrier();
    __builtin_amdgcn_sched_barrier(0);

    int cur = 0;
    for (int t = 0; t < nt; t++) {
        bf16x8 af[2][FI], bfv[2][FJ];
        const ushort* Ab = As[cur];
        const ushort* Bb = Bs[cur];
#pragma unroll
        for (int ks = 0; ks < 2; ks++) {
#pragma unroll
            for (int i = 0; i < FI; i++) af[ks][i] = *(const bf16x8*)(Ab + aoff[ks][i]);
#pragma unroll
            for (int j = 0; j < FJ; j++) bfv[ks][j] = *(const bf16x8*)(Bb + boff[ks][j]);
        }
        waitcnt_lgkm0();
        __builtin_amdgcn_s_barrier();
        if (t + 2 < nt) {
            stage(cur, (t + 2) << 6);
            __builtin_amdgcn_sched_barrier(0);
        }
#pragma unroll
        for (int ks = 0; ks < 2; ks++)
#pragma unroll
            for (int i = 0; i < FI; i++)
#pragma unroll
                for (int j = 0; j < FJ; j++)
                    acc[i][j] = __builtin_amdgcn_mfma_f32_16x16x32_bf16(af[ks][i], bfv[ks][j], acc[i][j], 0, 0, 0);
        __builtin_amdgcn_sched_barrier(0);
        if (t + 2 < nt) waitcnt_vm<L>();
        else if (t + 1 < nt) waitcnt_vm<0>();
        __builtin_amdgcn_s_barrier();
        __builtin_amdgcn_sched_barrier(0);
        cur ^= 1;
    }

    // C/D layout: col = lane&15, row = (lane>>4)*4 + reg
#pragma unroll
    for (int i = 0; i < FI; i++) {
        int rbase = row0 + wr * (BM / 2) + i * 16 + (lane >> 4) * 4;
#pragma unroll
        for (int j = 0; j < FJ; j++) {
            int c = col0 + wc * (BN / 2) + j * 16 + (lane & 15);
#pragma unroll
            for (int r = 0; r < 4; r++) {
                int rg = rbase + r;
                size_t off = (size_t)rg * Nc + c;
                float v = acc[i][j][r];
                if (EPI == 0) {
                    Cb[off] = f2bf(v);
                } else if (EPI == 1) {
                    v += bias[c];
                    float cdf = 0.5f * (1.0f + erff(v * 0.70710678118654752f));
                    Cb[off] = f2bf(v * cdf);
                    aux[off] = f2bf(cdf + v * 0.39894228040143267f * expf(-0.5f * v * v));
                } else if (EPI == 2) {
                    Cb[off] = f2bf(v * bf2f(aux[(size_t)(rg & (BS_ - 1)) * Nc + c]));
                } else if (EPI == 4) {
                    v += bias[c] + bf2f(resb[off]);
                    Cf[off] = v;
                } else if (EPI == 5) {
                    if (rg < BS_) {
                        v += bias[c] + resf[off];
                        Cb[off] = f2bf(v);
                    } else {
                        int rg2 = rg - BS_;
                        v += bf2f(resb[(size_t)rg2 * Nc + c]);
                        aux[(size_t)rg2 * Nc + c] = f2bf(v);
                    }
                } else {  // EPI == 6
                    v += bf2f(resb2[(size_t)rg * Nc + c]);
                    Cf2[stroff(rg, c, Nc)] = v;
                }
            }
        }
    }
}

// ---------------- MFMA QK^T primal: single-shot BK=64 (K=HD), XOR-swizzled ----------------
__global__ __launch_bounds__(256) void attn_qk_mfma(const ushort* __restrict__ qkvb,
                                                    ushort* __restrict__ sc) {
    int work = xcd_swz(blockIdx.x, gridDim.x);
    constexpr int NT = S_ / 128;  // 4
    int bh = work / (NT * NT);
    int r2 = work % (NT * NT);
    int q0 = (r2 / NT) * 128, kc0 = (r2 % NT) * 128;
    int b = bh / H_, hh = bh - b * H_;
    const size_t qoff = (size_t)b * S_ * 3 * D_ + hh * HD_;
    const int ld = 3 * D_;
    __shared__ ushort As[128 * 64];
    __shared__ ushort Bs[128 * 64];
    int tid = threadIdx.x;
    int wave = tid >> 6, lane = tid & 63;
    int wr = wave >> 1, wc = wave & 1;

    int srow = lane >> 3;
    int skel = ((lane & 7) ^ (lane >> 3)) * 8;
    const ushort* Ag0 = qkvb + qoff + (size_t)(q0 + srow) * ld + skel;
    const ushort* Bg0 = qkvb + qoff + D_ + (size_t)(kc0 + srow) * ld + skel;

#pragma unroll
    for (int cc = 0; cc < 4; cc++) {
        int c = wave * 4 + cc;
        gll16(Ag0 + (size_t)(c * 8) * ld, As + c * 512);
        gll16(Bg0 + (size_t)(c * 8) * ld, Bs + c * 512);
    }
    __syncthreads();

    int frow = lane & 15, fkb = (lane >> 4) * 8;
    f32x4 acc[4][4] = {};
#pragma unroll
    for (int ks = 0; ks < 2; ks++) {
        int sw = (fkb + ks * 32) ^ ((frow & 7) * 8);
        bf16x8 af[4], bfv[4];
#pragma unroll
        for (int i = 0; i < 4; i++) af[i] = *(const bf16x8*)(As + (wr * 64 + i * 16 + frow) * 64 + sw);
#pragma unroll
        for (int j = 0; j < 4; j++) bfv[j] = *(const bf16x8*)(Bs + (wc * 64 + j * 16 + frow) * 64 + sw);
#pragma unroll
        for (int i = 0; i < 4; i++)
#pragma unroll
            for (int j = 0; j < 4; j++)
                acc[i][j] = __builtin_amdgcn_mfma_f32_16x16x32_bf16(af[i], bfv[j], acc[i][j], 0, 0, 0);
    }

#pragma unroll
    for (int i = 0; i < 4; i++) {
        int rbase = q0 + wr * 64 + i * 16 + (lane >> 4) * 4;
#pragma unroll
        for (int j = 0; j < 4; j++) {
            int c = kc0 + wc * 64 + j * 16 + (lane & 15);
#pragma unroll
            for (int r = 0; r < 4; r++)
                sc[((size_t)bh * S_ + rbase + r) * S_ + c] = f2bf(acc[i][j][r] * SCALE_);
        }
    }
}

// ---------------- primal P@V: BK=64, XOR-swizzled ----------------
__global__ __launch_bounds__(256) void attn_av_p(const ushort* __restrict__ Pb,
                                                 const ushort* __restrict__ Vt,
                                                 ushort* __restrict__ outp) {
    int work = xcd_swz(blockIdx.x, gridDim.x);
    constexpr int NT = S_ / 128;  // 4
    int bh = work / NT;
    int q0 = (work % NT) * 128;
    int b = bh / H_, hh = bh - b * H_;
    const ushort* Pg = Pb + (size_t)bh * S_ * S_;
    const ushort* Vg = Vt + (size_t)bh * HD_ * S_;
    __shared__ ushort As[128 * 64];
    __shared__ ushort Bs[64 * 64];
    int tid = threadIdx.x;
    int wave = tid >> 6, lane = tid & 63;
    int wr = wave >> 1, wc = wave & 1;
    int srow = lane >> 3;
    int skel = ((lane & 7) ^ (lane >> 3)) * 8;
    int frow = lane & 15, fkb = (lane >> 4) * 8;

    f32x4 acc[4][2] = {};
    for (int k0 = 0; k0 < S_; k0 += 64) {
#pragma unroll
        for (int cc = 0; cc < 4; cc++) {
            int c = wave * 4 + cc;
            gll16(Pg + (size_t)(q0 + c * 8 + srow) * S_ + k0 + skel, As + c * 512);
        }
#pragma unroll
        for (int cc = 0; cc < 2; cc++) {
            int c = wave * 2 + cc;
            gll16(Vg + (size_t)(c * 8 + srow) * S_ + k0 + skel, Bs + c * 512);
        }
        __syncthreads();
#pragma unroll
        for (int ks = 0; ks < 2; ks++) {
            int sw = (fkb + ks * 32) ^ ((frow & 7) * 8);
            bf16x8 af[4], bfv[2];
#pragma unroll
            for (int i = 0; i < 4; i++) af[i] = *(const bf16x8*)(As + (wr * 64 + i * 16 + frow) * 64 + sw);
#pragma unroll
            for (int j = 0; j < 2; j++) bfv[j] = *(const bf16x8*)(Bs + (wc * 32 + j * 16 + frow) * 64 + sw);
#pragma unroll
            for (int i = 0; i < 4; i++)
#pragma unroll
                for (int j = 0; j < 2; j++)
                    acc[i][j] = __builtin_amdgcn_mfma_f32_16x16x32_bf16(af[i], bfv[j], acc[i][j], 0, 0, 0);
        }
        __syncthreads();
    }

#pragma unroll
    for (int i = 0; i < 4; i++) {
        int rbase = q0 + wr * 64 + i * 16 + (lane >> 4) * 4;
#pragma unroll
        for (int j = 0; j < 2; j++) {
            int c = hh * HD_ + wc * 32 + j * 16 + (lane & 15);
#pragma unroll
            for (int r = 0; r < 4; r++)
                outp[(size_t)(b * S_ + rbase + r) * D_ + c] = f2bf(acc[i][j][r]);
        }
    }
}

// ---------------- FUSED tangent attention: dsc (in LDS) + dattn + PV, all 4 tangents ----
// Per block: 64 q-rows, one (mz,bh). Per 64-k tile:
//   dsc = SCALE*(dQ.K^T + Q.dK^T)  [MFMA, Q/dQ staged once]
//   -> bf16 to LDS Ds (swizzled)  -> P from attnb; s += rowsum(P.dsc)
//   acc += (P.dsc)@V + P@dV ; epilogue: out = acc - s*O
// 1D grid: work = mz*(BH*8) + bh*8 + qi
__global__ __launch_bounds__(256) void attn_tan_fused(const ushort* __restrict__ qkv5,
                                                      const ushort* __restrict__ Pb,
                                                      const ushort* __restrict__ Vt,
                                                      const ushort* __restrict__ dVt4,
                                                      const ushort* __restrict__ Ob,
                                                      ushort* __restrict__ outp) {
    int work = xcd_swz(blockIdx.x, gridDim.x);
    int mz = work / (BH_ * 8);
    int rem = work % (BH_ * 8);
    int bh = rem / 8;
    int q0 = (rem % 8) * 64;
    int b = bh / H_, hh = bh - b * H_;
    const int ld = 3 * D_;
    const size_t qoff = (size_t)b * S_ * 3 * D_ + hh * HD_;
    const ushort* Qg = qkv5 + qoff;
    const ushort* Kg = qkv5 + qoff + D_;
    const ushort* dQg = qkv5 + (size_t)(1 + mz) * BS3D_ + qoff;
    const ushort* dKg = dQg + D_;
    const ushort* Vg = Vt + (size_t)bh * HD_ * S_;
    const ushort* dVg = dVt4 + (size_t)mz * BSD_ + (size_t)bh * HD_ * S_;
    const ushort* Pg = Pb + (size_t)bh * S_ * S_;
    ushort* outm = outp + (size_t)mz * BSD_;

    __shared__ ushort Qs[64 * 64], dQs[64 * 64];          // staged once (16 KB)
    __shared__ ushort Ks[64 * 64], dKs[64 * 64];          // per k-tile
    __shared__ ushort Vs[64 * 64], dVs[64 * 64];
    __shared__ ushort Ps[64 * 64], Ds[64 * 64];           // total 64 KB

    int tid = threadIdx.x;
    int wave = tid >> 6, lane = tid & 63;
    int wr = wave >> 1, wc = wave & 1;
    int srow = lane >> 3;
    int skel = ((lane & 7) ^ (lane >> 3)) * 8;
    int frow = lane & 15, fkb = (lane >> 4) * 8;

    // fragment offsets within a 64x64 swizzled tile
    int aoff[2][2], boff[2][2];
#pragma unroll
    for (int ks = 0; ks < 2; ks++) {
        int sw = (fkb + ks * 32) ^ ((frow & 7) * 8);
#pragma unroll
        for (int i = 0; i < 2; i++) aoff[ks][i] = (wr * 32 + i * 16 + frow) * 64 + sw;
#pragma unroll
        for (int j = 0; j < 2; j++) boff[ks][j] = (wc * 32 + j * 16 + frow) * 64 + sw;
    }

    // stage Q, dQ once (8 chunks of 8 rows each)
#pragma unroll
    for (int cc = 0; cc < 2; cc++) {
        int c = wave * 2 + cc;
        gll16(Qg + (size_t)(q0 + c * 8 + srow) * ld + skel, Qs + c * 512);
        gll16(dQg + (size_t)(q0 + c * 8 + srow) * ld + skel, dQs + c * 512);
    }

    float s[2] = {0.f, 0.f};
    f32x4 acc[2][2] = {};

    for (int k0 = 0; k0 < S_; k0 += 64) {
#pragma unroll
        for (int cc = 0; cc < 2; cc++) {
            int c = wave * 2 + cc;
            gll16(Kg + (size_t)(k0 + c * 8 + srow) * ld + skel, Ks + c * 512);
            gll16(dKg + (size_t)(k0 + c * 8 + srow) * ld + skel, dKs + c * 512);
            gll16(Vg + (size_t)(c * 8 + srow) * S_ + k0 + skel, Vs + c * 512);
            gll16(dVg + (size_t)(c * 8 + srow) * S_ + k0 + skel, dVs + c * 512);
            gll16(Pg + (size_t)(q0 + c * 8 + srow) * S_ + k0 + skel, Ps + c * 512);
        }
        __syncthreads();

        // ---- dsc = SCALE*(dQ.K^T + Q.dK^T) for the wave's 32q x 32k quadrant ----
        f32x4 accd[2][2] = {};
#pragma unroll
        for (int ks = 0; ks < 2; ks++) {
            bf16x8 aq[2], adq[2], bk[2], bdk[2];
#pragma unroll
            for (int i = 0; i < 2; i++) {
                aq[i] = *(const bf16x8*)(Qs + aoff[ks][i]);
                adq[i] = *(const bf16x8*)(dQs + aoff[ks][i]);
            }
#pragma unroll
            for (int j = 0; j < 2; j++) {
                bk[j] = *(const bf16x8*)(Ks + boff[ks][j]);
                bdk[j] = *(const bf16x8*)(dKs + boff[ks][j]);
            }
#pragma unroll
            for (int i = 0; i < 2; i++)
#pragma unroll
                for (int j = 0; j < 2; j++) {
                    accd[i][j] = __builtin_amdgcn_mfma_f32_16x16x32_bf16(adq[i], bk[j], accd[i][j], 0, 0, 0);
                    accd[i][j] = __builtin_amdgcn_mfma_f32_16x16x32_bf16(aq[i], bdk[j], accd[i][j], 0, 0, 0);
                }
        }
        // write dsc tile to Ds (C-layout: q=(lane>>4)*4+r, k=lane&15), swizzled like reads
#pragma unroll
        for (int i = 0; i < 2; i++) {
#pragma unroll
            for (int j = 0; j < 2; j++) {
#pragma unroll
                for (int r = 0; r < 4; r++) {
                    int qq = wr * 32 + i * 16 + (lane >> 4) * 4 + r;
                    int kk = wc * 32 + j * 16 + (lane & 15);
                    int blk = ((kk >> 3) ^ (qq & 7));
                    Ds[qq * 64 + blk * 8 + (kk & 7)] = f2bf(accd[i][j][r] * SCALE_);
                }
            }
        }
        __syncthreads();

        // ---- PV: pd = P.dsc (accumulate s), acc += pd@V + P@dV ----
#pragma unroll
        for (int ks = 0; ks < 2; ks++) {
            bf16x8 p8[2], pq8[2], v8[2], dv8[2];
#pragma unroll
            for (int i = 0; i < 2; i++) {
                p8[i] = *(const bf16x8*)(Ps + aoff[ks][i]);
                bf16x8 d8 = *(const bf16x8*)(Ds + aoff[ks][i]);
#pragma unroll
                for (int e = 0; e < 8; e++) {
                    float pd = bf2f((ushort)p8[i][e]) * bf2f((ushort)d8[e]);
                    s[i] += pd;
                    pq8[i][e] = (short)f2bf(pd);
                }
            }
#pragma unroll
            for (int j = 0; j < 2; j++) {
                v8[j] = *(const bf16x8*)(Vs + boff[ks][j]);
                dv8[j] = *(const bf16x8*)(dVs + boff[ks][j]);
            }
#pragma unroll
            for (int i = 0; i < 2; i++)
#pragma unroll
                for (int j = 0; j < 2; j++) {
                    acc[i][j] = __builtin_amdgcn_mfma_f32_16x16x32_bf16(pq8[i], v8[j], acc[i][j], 0, 0, 0);
                    acc[i][j] = __builtin_amdgcn_mfma_f32_16x16x32_bf16(p8[i], dv8[j], acc[i][j], 0, 0, 0);
                }
        }
        __syncthreads();
    }

    // complete rowsums: lanes {l, l^16, l^32, l^48} hold the 4 k-slices of row (.. + frow)
#pragma unroll
    for (int i = 0; i < 2; i++) {
        s[i] += __shfl_xor(s[i], 16);
        s[i] += __shfl_xor(s[i], 32);
    }

    // epilogue: out = acc - s[row]*O[row][col]
#pragma unroll
    for (int i = 0; i < 2; i++) {
        int rbase = q0 + wr * 32 + i * 16 + (lane >> 4) * 4;
#pragma unroll
        for (int r = 0; r < 4; r++) {
            float sc = __shfl(s[i], ((lane >> 4) << 2) + r);
#pragma unroll
            for (int j = 0; j < 2; j++) {
                int c = hh * HD_ + wc * 32 + j * 16 + (lane & 15);
                float o = bf2f(Ob[(size_t)(b * S_ + rbase + r) * D_ + c]);
                outm[(size_t)(b * S_ + rbase + r) * D_ + c] = f2bf(acc[i][j][r] - sc * o);
            }
        }
    }
}

// ---------------- softmax: bf16 scores -> bf16 probs ----------------
__global__ __launch_bounds__(256) void softmax_rows(const ushort* __restrict__ sc,
                                                    ushort* __restrict__ scb) {
    size_t row = blockIdx.x;
    const ushort* p = sc + row * S_;
    int tid = threadIdx.x;
    ushort2 vu = *(const ushort2*)&p[tid * 2];
    float v0 = bf2f(vu.x), v1 = bf2f(vu.y);
    float mx = block_max(fmaxf(v0, v1));
    float e0 = expf(v0 - mx), e1 = expf(v1 - mx);
    float s = block_sum(e0 + e1);
    float inv = 1.0f / s;
    ushort2 ob; ob.x = f2bf(e0 * inv); ob.y = f2bf(e1 * inv);
    *(ushort2*)&scb[row * S_ + tid * 2] = ob;
}

// ---------------- host ----------------
extern "C" void kernel_launch(void* const* d_in, const int* in_sizes, int n_in,
                              void* d_out, int out_size, void* d_ws, size_t ws_size,
                              hipStream_t stream) {
    const float* x = (const float*)d_in[0];
    const float* xt = (const float*)d_in[1];
    const float* g1 = (const float*)d_in[2];
    const float* b1 = (const float*)d_in[3];
    const float* Wqkv = (const float*)d_in[4];
    const float* Wproj = (const float*)d_in[5];
    const float* bproj = (const float*)d_in[6];
    const float* g2 = (const float*)d_in[7];
    const float* b2 = (const float*)d_in[8];
    const float* W1 = (const float*)d_in[9];
    const float* bf1 = (const float*)d_in[10];
    const float* W2 = (const float*)d_in[11];
    const float* bf2 = (const float*)d_in[12];
    float* out = (float*)d_out;
    float* out_t = out + BSD_;   // [B,M,S,D]

    char* wp = (char*)d_ws;
    auto alloc = [&](size_t bytes) { void* p = wp; wp += (bytes + 255) & ~(size_t)255; return p; };
    // regBig: [hb5 | ob5 | qkv5] in phase 1; ab5 aliases from base in phase 2.
    char* regBig = (char*)alloc(25 * BSD_ * 2);    // 78.6 MB
    ushort* hb5 = (ushort*)regBig;                 // [5*BS][D]
    ushort* ob5 = (ushort*)(regBig + 5 * BSD_ * 2);  // [5][BS][D]
    ushort* qkv5 = (ushort*)(regBig + 10 * BSD_ * 2); // [5][B,S,3D]
    ushort* ab5 = (ushort*)regBig;                 // [5*BS][DFF] (phase 2)
    ushort* xhat1 = (ushort*)alloc(BSD_ * 2);      // dead after ln_jvp; then x2b alias
    ushort* x2b = xhat1;
    ushort* xhat2 = (ushort*)alloc(BSD_ * 2);
    ushort* h2b = (ushort*)alloc(BSD_ * 2);
    ushort* dx2b = (ushort*)alloc(4 * BSD_ * 2);   // [4*BS][D] bf16
    ushort* xt_b = (ushort*)alloc(4 * BSD_ * 2);   // compact bf16 copy of x_tangent
    ushort* Vt = (ushort*)alloc(BSD_ * 2);
    ushort* scb = (ushort*)alloc(ATT_ * 2);        // primal scores
    ushort* attnb = (ushort*)alloc(ATT_ * 2);      // primal probs bf16
    ushort* gpb = (ushort*)alloc(BSF_ * 2);        // gelu'(u) bf16
    ushort* dh2_4 = (ushort*)alloc(4 * BSD_ * 2);  // [4*BS][D]
    ushort* dVt4 = (ushort*)alloc(4 * BSD_ * 2);   // [4][bh][HD][S]
    float* rstd1 = (float*)alloc(BS_ * 4);
    float* rstd2 = (float*)alloc(BS_ * 4);
    ushort* WqkvT = (ushort*)alloc((size_t)D_ * 3 * D_ * 2);
    ushort* WprojT = (ushort*)alloc((size_t)D_ * D_ * 2);
    ushort* W1T = (ushort*)alloc((size_t)DFF_ * D_ * 2);
    ushort* W2T = (ushort*)alloc((size_t)D_ * DFF_ * 2);

    // ---- weights -> bf16 transposed [N][K] ----
    transpose_f2b<<<dim3(3 * D_ / 32, D_ / 32), 256, 0, stream>>>(Wqkv, WqkvT, D_, 3 * D_);
    transpose_f2b<<<dim3(D_ / 32, D_ / 32), 256, 0, stream>>>(Wproj, WprojT, D_, D_);
    transpose_f2b<<<dim3(DFF_ / 32, D_ / 32), 256, 0, stream>>>(W1, W1T, D_, DFF_);
    transpose_f2b<<<dim3(D_ / 32, DFF_ / 32), 256, 0, stream>>>(W2, W2T, DFF_, D_);

    // ---- LN fwd + batched LN-JVP, then ONE merged qkv GEMM over [h; dh x4] (M=10240) ----
    ln_fwd<<<BS_, 256, 0, stream>>>(x, nullptr, g1, b1, xhat1, hb5, rstd1);
    ln_jvp<<<4 * BS_, 256, 0, stream>>>(xt, nullptr, 0, xhat1, rstd1, g1, hb5 + BSD_, xt_b);
    gemm_mfma<128, 128, 0><<<dim3(3 * D_ / 128, 5 * BS_ / 128), 256, 0, stream>>>(
        hb5, WqkvT, nullptr, nullptr, nullptr, nullptr, nullptr, nullptr, qkv5, nullptr, 3 * D_, D_);
    transpose_v<<<dim3(S_ / 32, HD_ / 32, 5 * BH_), 256, 0, stream>>>(qkv5, Vt, dVt4);

    // ---- primal attention ----
    attn_qk_mfma<<<(S_ / 128) * (S_ / 128) * BH_, 256, 0, stream>>>(qkv5, scb);
    softmax_rows<<<BH_ * S_, 256, 0, stream>>>(scb, attnb);
    attn_av_p<<<(S_ / 128) * BH_, 256, 0, stream>>>(attnb, Vt, ob5);

    // ---- fused tangent attention (all 4 tangents, one dispatch) -> ob5 slices 1-4 ----
    attn_tan_fused<<<4 * 8 * BH_, 256, 0, stream>>>(qkv5, attnb, Vt, dVt4, ob5, ob5 + BSD_);

    // ---- merged proj (M=10240): slice0 -> x2b (bias+x res), slices1-4 -> dx2b (xt_b res) ----
    gemm_mfma<128, 64, 5><<<dim3(D_ / 64, 5 * BS_ / 128), 256, 0, stream>>>(
        ob5, WprojT, bproj, x, xt_b, nullptr, nullptr, nullptr, x2b, dx2b, D_, D_);

    // ---- MLP ----
    ln_fwd<<<BS_, 256, 0, stream>>>(nullptr, x2b, g2, b2, xhat2, h2b, rstd2);
    gemm_mfma<128, 128, 1><<<dim3(DFF_ / 128, BS_ / 128), 256, 0, stream>>>(
        h2b, W1T, bf1, nullptr, nullptr, nullptr, nullptr, nullptr, ab5, gpb, DFF_, D_);
    ln_jvp<<<4 * BS_, 256, 0, stream>>>(nullptr, dx2b, 1, xhat2, rstd2, g2, dh2_4, nullptr);
    gemm_mfma<128, 128, 2><<<dim3(DFF_ / 128, 4 * BS_ / 128), 256, 0, stream>>>(
        dh2_4, W1T, nullptr, nullptr, nullptr, nullptr, nullptr, nullptr, ab5 + BSF_, gpb, DFF_, D_);

    // ---- W2: split (K=3072 bands thrash L2 when merged at M=10240) ----
    gemm_mfma<64, 64, 4><<<dim3(D_ / 64, BS_ / 64), 256, 0, stream>>>(
        ab5, W2T, bf2, nullptr, x2b, nullptr, out, nullptr, nullptr, nullptr, D_, DFF_);
    gemm_mfma<128, 64, 6><<<dim3(D_ / 64, 4 * BS_ / 128), 256, 0, stream>>>(
        ab5 + BSF_, W2T, nullptr, nullptr, nullptr, dx2b, nullptr, out_t, nullptr, nullptr, D_, DFF_);
}